// Round 1
// baseline (1203.853 us; speedup 1.0000x reference)
//
#include <hip/hip_runtime.h>

typedef float f32x4 __attribute__((ext_vector_type(4)));
typedef short s16x8 __attribute__((ext_vector_type(8)));

#define LDA 136   // padded LDS row length (bf16 elems): 272B rows -> ~2-way bank aliasing (free)

static __device__ __forceinline__ unsigned short f2bf(float f){
  union { float f; unsigned int u; } v; v.f = f;
  unsigned int u = v.u;
  return (unsigned short)((u + 0x7fffu + ((u >> 16) & 1u)) >> 16);
}

static __device__ __forceinline__ float lrelu02(float x){ return x > 0.f ? x : 0.2f * x; }

// bijective XCD swizzle (m204)
static __device__ __forceinline__ int xcd_swz(int bid, int nwg){
  int q = nwg >> 3, r = nwg & 7, x = bid & 7, i = bid >> 3;
  return (x < r ? x * (q + 1) : r * (q + 1) + (x - r) * q) + i;
}

// ---------------- CSR build ----------------

__global__ void zero_u32(unsigned int* p, int n){
  int i = blockIdx.x * 256 + threadIdx.x;
  if (i < n) p[i] = 0u;
}

__global__ void hist_kernel(const int* __restrict__ dst, unsigned int* __restrict__ cnt, int E){
  int i = blockIdx.x * 256 + threadIdx.x;
  if (i < E) atomicAdd(&cnt[dst[i]], 1u);
}

__global__ void scan_kernel(const unsigned int* __restrict__ cnt, unsigned int* __restrict__ rp,
                            int n, int ch){
  __shared__ unsigned int sums[1024];
  int tid = threadIdx.x;
  int base = tid * ch;
  unsigned int s = 0;
  for (int j = 0; j < ch; ++j){ int k = base + j; if (k < n) s += cnt[k]; }
  sums[tid] = s; __syncthreads();
  for (int off = 1; off < 1024; off <<= 1){
    unsigned int v = (tid >= off) ? sums[tid - off] : 0u;
    __syncthreads();
    sums[tid] += v;
    __syncthreads();
  }
  unsigned int run = (tid > 0) ? sums[tid - 1] : 0u;
  for (int j = 0; j < ch; ++j){
    int k = base + j;
    if (k < n){ rp[k] = run; run += cnt[k]; }
  }
  if (tid == 1023) rp[n] = sums[1023];
}

__global__ void scatter_kernel(const int* __restrict__ src, const int* __restrict__ dst,
                               const unsigned int* __restrict__ rp, unsigned int* __restrict__ fill,
                               int* __restrict__ colA, int E){
  int i = blockIdx.x * 256 + threadIdx.x;
  if (i < E){
    int d = dst[i];
    unsigned int pos = rp[d] + atomicAdd(&fill[d], 1u);
    colA[pos] = src[i];
  }
}

__global__ void dinv_kernel(const unsigned int* __restrict__ cnt, float* __restrict__ dinv, int n){
  int i = blockIdx.x * 256 + threadIdx.x;
  if (i < n) dinv[i] = rsqrtf((float)cnt[i] + 1.0f);
}

// ---------------- weight transpose (f32 [128,128] row-major -> bf16 [col][k]) ----------------

struct WSrc { const float* p[18]; };

__global__ void wtrans_kernel(WSrc s, unsigned short* __restrict__ dstAll){
  const float* src = s.p[blockIdx.x];
  unsigned short* dst = dstAll + (size_t)blockIdx.x * 16384;
  __shared__ float st[64][129];
  int tid = threadIdx.x;
  for (int half = 0; half < 2; ++half){
    int kb = half * 64;
#pragma unroll
    for (int j = 0; j < 8; ++j){
      int e = tid + 256 * j;          // 0..2047
      int r = e >> 5, c4 = (e & 31) * 4;
      float4 v = *(const float4*)(src + (size_t)(kb + r) * 128 + c4);
      st[r][c4] = v.x; st[r][c4+1] = v.y; st[r][c4+2] = v.z; st[r][c4+3] = v.w;
    }
    __syncthreads();
#pragma unroll
    for (int j = 0; j < 8; ++j){
      int e = tid + 256 * j;          // 0..2047
      int c = e >> 4, k4 = (e & 15) * 4;
      ushort4 o;
      o.x = f2bf(st[k4+0][c]); o.y = f2bf(st[k4+1][c]);
      o.z = f2bf(st[k4+2][c]); o.w = f2bf(st[k4+3][c]);
      *(ushort4*)(dst + (size_t)c * 128 + kb + k4) = o;
    }
    __syncthreads();
  }
}

// ---------------- MFMA GEMM: C[nrows,128] = sum_p A_p[nrows,128] @ W_p[128,128] (+epilogue) ----------------
// W_p given pre-transposed bf16: Wt[col][k].
// EPI: 0 none, 1 +bias, 2 relu(+bias), 3 conv: relu((acc+bias)*bn_g*RSQ + bn_b) + resid

template<int EPI>
__launch_bounds__(256, 2)
__global__ void gemm_kernel(const float* __restrict__ A0, const float* __restrict__ A1, const float* __restrict__ A2,
                            const unsigned short* __restrict__ W0, const unsigned short* __restrict__ W1, const unsigned short* __restrict__ W2,
                            const float* __restrict__ bias, const float* __restrict__ bng, const float* __restrict__ bnb,
                            const float* __restrict__ resid, float* __restrict__ C, int nrows)
{
  __shared__ unsigned short As[64 * LDA];
  __shared__ unsigned short Wt[128 * LDA];
  const int tid = threadIdx.x;
  const int wave = tid >> 6, lane = tid & 63;
  const int row0 = blockIdx.x * 64;
  const float* Aps[3] = {A0, A1, A2};
  const unsigned short* Wps[3] = {W0, W1, W2};
  f32x4 acc[8];
#pragma unroll
  for (int i = 0; i < 8; ++i) acc[i] = (f32x4){0.f, 0.f, 0.f, 0.f};

  for (int p = 0; p < 3; ++p){
    const float* Ap = Aps[p];
    if (Ap == nullptr) break;
    const unsigned short* Wp = Wps[p];
    if (p) __syncthreads();            // LDS reuse guard
    // stage A tile (f32 -> bf16)
#pragma unroll
    for (int j = 0; j < 8; ++j){
      int e = tid + 256 * j;           // 0..2047 (64 rows x 32 float4)
      int r = e >> 5, k4 = (e & 31) * 4;
      int gr = row0 + r;
      float4 v = make_float4(0.f, 0.f, 0.f, 0.f);
      if (gr < nrows) v = *(const float4*)(Ap + (size_t)gr * 128 + k4);
      ushort4 o; o.x = f2bf(v.x); o.y = f2bf(v.y); o.z = f2bf(v.z); o.w = f2bf(v.w);
      *(ushort4*)(As + r * LDA + k4) = o;
    }
    // stage Wt tile (already bf16, transposed)
#pragma unroll
    for (int j = 0; j < 8; ++j){
      int e = tid + 256 * j;           // 0..2047 (128 cols x 16 chunks of 8)
      int colw = e >> 4, k8 = (e & 15) * 8;
      *(s16x8*)(Wt + colw * LDA + k8) = *(const s16x8*)(Wp + (size_t)colw * 128 + k8);
    }
    __syncthreads();
#pragma unroll
    for (int kc = 0; kc < 4; ++kc){
      int ko = kc * 32 + (lane >> 4) * 8;
      s16x8 av = *(const s16x8*)(As + (wave * 16 + (lane & 15)) * LDA + ko);
#pragma unroll
      for (int ct = 0; ct < 8; ++ct){
        s16x8 bv = *(const s16x8*)(Wt + (ct * 16 + (lane & 15)) * LDA + ko);
        acc[ct] = __builtin_amdgcn_mfma_f32_16x16x32_bf16(av, bv, acc[ct], 0, 0, 0);
      }
    }
  }
  const float RSQ = 0.99999500003749969f; // rsqrt(1 + 1e-5)
#pragma unroll
  for (int ct = 0; ct < 8; ++ct){
    int colg = ct * 16 + (lane & 15);
    float bv_ = (EPI >= 1) ? bias[colg] : 0.f;
    float sg = (EPI == 3) ? bng[colg] * RSQ : 0.f;
    float sb = (EPI == 3) ? bnb[colg] : 0.f;
#pragma unroll
    for (int r = 0; r < 4; ++r){
      int rowg = row0 + wave * 16 + (lane >> 4) * 4 + r;
      if (rowg < nrows){
        float v = acc[ct][r];
        if (EPI == 1) v += bv_;
        else if (EPI == 2) v = fmaxf(v + bv_, 0.f);
        else if (EPI == 3){
          v = (v + bv_) * sg + sb;
          v = fmaxf(v, 0.f) + resid[(size_t)rowg * 128 + colg];
        }
        C[(size_t)rowg * 128 + colg] = v;
      }
    }
  }
}

// ---------------- aggregation kernels (wave per node, float2 per lane) ----------------

__global__ void gin_agg_kernel(const float* __restrict__ x, const unsigned int* __restrict__ rp,
                               const int* __restrict__ col, float* __restrict__ xs, int n){
  int bid = xcd_swz(blockIdx.x, gridDim.x);
  int node = bid * 4 + (int)(threadIdx.x >> 6);
  if (node >= n) return;
  int lane = threadIdx.x & 63;
  const float2* xin = (const float2*)x;
  float2 acc = xin[(size_t)node * 64 + lane];   // (1+0)*x self term
  unsigned int rs = rp[node], re = rp[node + 1];
  for (unsigned int e = rs; e < re; ++e){
    int s = col[e];
    float2 v = xin[(size_t)s * 64 + lane];
    acc.x += v.x; acc.y += v.y;
  }
  ((float2*)xs)[(size_t)node * 64 + lane] = acc;
}

__global__ void gcn_agg_kernel(const float* __restrict__ h, const float* __restrict__ dinv,
                               const unsigned int* __restrict__ rp, const int* __restrict__ col,
                               const float* __restrict__ b, float* __restrict__ out, int n){
  int bid = xcd_swz(blockIdx.x, gridDim.x);
  int node = bid * 4 + (int)(threadIdx.x >> 6);
  if (node >= n) return;
  int lane = threadIdx.x & 63;
  const float2* hv = (const float2*)h;
  float di = dinv[node];
  float2 a0 = hv[(size_t)node * 64 + lane];
  float2 acc = make_float2(a0.x * di, a0.y * di);   // self loop: h[i]*dinv[i]
  unsigned int rs = rp[node], re = rp[node + 1];
  for (unsigned int e = rs; e < re; ++e){
    int s = col[e];
    float ds = dinv[s];
    float2 v = hv[(size_t)s * 64 + lane];
    acc.x += v.x * ds; acc.y += v.y * ds;
  }
  int f = lane * 2;
  out[(size_t)node * 128 + f]     = fmaxf(acc.x * di + b[f], 0.f);
  out[(size_t)node * 128 + f + 1] = fmaxf(acc.y * di + b[f + 1], 0.f);
}

__global__ void sum_agg_kernel(const float* __restrict__ x, const unsigned int* __restrict__ rp,
                               const int* __restrict__ col, float* __restrict__ out, int n){
  int bid = xcd_swz(blockIdx.x, gridDim.x);
  int node = bid * 4 + (int)(threadIdx.x >> 6);
  if (node >= n) return;
  int lane = threadIdx.x & 63;
  const float2* xin = (const float2*)x;
  float2 acc = make_float2(0.f, 0.f);
  unsigned int rs = rp[node], re = rp[node + 1];
  for (unsigned int e = rs; e < re; ++e){
    int s = col[e];
    float2 v = xin[(size_t)s * 64 + lane];
    acc.x += v.x; acc.y += v.y;
  }
  ((float2*)out)[(size_t)node * 64 + lane] = acc;
}

__global__ void gat_agg_kernel(const float* __restrict__ xp, const float* __restrict__ als,
                               const float* __restrict__ ald, const unsigned int* __restrict__ rp,
                               const int* __restrict__ col, const float* __restrict__ bgat,
                               float* __restrict__ out, int n){
  int bid = xcd_swz(blockIdx.x, gridDim.x);
  int node = bid * 4 + (int)(threadIdx.x >> 6);
  if (node >= n) return;
  int lane = threadIdx.x & 63;
  int h = lane >> 4;
  float ad = ald[(size_t)node * 4 + h];
  unsigned int rs = rp[node], re = rp[node + 1];
  float eself = lrelu02(als[(size_t)node * 4 + h] + ad);
  float m = eself;
  for (unsigned int e = rs; e < re; ++e){
    int s = col[e];
    m = fmaxf(m, lrelu02(als[(size_t)s * 4 + h] + ad));
  }
  const float2* xv = (const float2*)xp;
  float w = __expf(eself - m);
  float2 sv = xv[(size_t)node * 64 + lane];
  float2 acc = make_float2(sv.x * w, sv.y * w);
  float denom = w;
  for (unsigned int e = rs; e < re; ++e){
    int s = col[e];
    float we = __expf(lrelu02(als[(size_t)s * 4 + h] + ad) - m);
    float2 v = xv[(size_t)s * 64 + lane];
    acc.x += v.x * we; acc.y += v.y * we;
    denom += we;
  }
  float inv = 1.0f / denom;
  int f = lane * 2;
  out[(size_t)node * 128 + f]     = fmaxf(acc.x * inv + bgat[f], 0.f);
  out[(size_t)node * 128 + f + 1] = fmaxf(acc.y * inv + bgat[f + 1], 0.f);
}

// ---------------- small per-node kernels ----------------

__global__ void alpair_kernel(const float* __restrict__ xp, const float* __restrict__ a_src,
                              const float* __restrict__ a_dst, float* __restrict__ als,
                              float* __restrict__ ald, int n){
  int node = blockIdx.x * 4 + (int)(threadIdx.x >> 6);
  if (node >= n) return;
  int lane = threadIdx.x & 63;
  int f = lane * 2;
  float2 v = ((const float2*)xp)[(size_t)node * 64 + lane];
  float ps = v.x * a_src[f] + v.y * a_src[f + 1];
  float pd = v.x * a_dst[f] + v.y * a_dst[f + 1];
#pragma unroll
  for (int off = 1; off < 16; off <<= 1){
    ps += __shfl_xor(ps, off, 64);
    pd += __shfl_xor(pd, off, 64);
  }
  if ((lane & 15) == 0){
    int hh = lane >> 4;
    als[(size_t)node * 4 + hh] = ps;
    ald[(size_t)node * 4 + hh] = pd;
  }
}

__global__ void combine_kernel(const float* __restrict__ t, const float* __restrict__ W2,
                               const float* __restrict__ b2, const float* __restrict__ xg,
                               const float* __restrict__ xi, const float* __restrict__ xa,
                               const float* __restrict__ bn0g, const float* __restrict__ bn0b,
                               float* __restrict__ xx, int n){
  int node = blockIdx.x * 4 + (int)(threadIdx.x >> 6);
  if (node >= n) return;
  int lane = threadIdx.x & 63;
  int f = lane * 2;
  float2 tv = ((const float2*)t)[(size_t)node * 64 + lane];
  float p0 = tv.x * W2[f * 3 + 0] + tv.y * W2[(f + 1) * 3 + 0];
  float p1 = tv.x * W2[f * 3 + 1] + tv.y * W2[(f + 1) * 3 + 1];
  float p2 = tv.x * W2[f * 3 + 2] + tv.y * W2[(f + 1) * 3 + 2];
#pragma unroll
  for (int off = 1; off < 64; off <<= 1){
    p0 += __shfl_xor(p0, off, 64);
    p1 += __shfl_xor(p1, off, 64);
    p2 += __shfl_xor(p2, off, 64);
  }
  p0 += b2[0]; p1 += b2[1]; p2 += b2[2];
  float mm = fmaxf(p0, fmaxf(p1, p2));
  float e0 = __expf(p0 - mm), e1 = __expf(p1 - mm), e2 = __expf(p2 - mm);
  float inv = 1.0f / (e0 + e1 + e2);
  e0 *= inv; e1 *= inv; e2 *= inv;
  float2 a = ((const float2*)xg)[(size_t)node * 64 + lane];
  float2 b = ((const float2*)xi)[(size_t)node * 64 + lane];
  float2 c = ((const float2*)xa)[(size_t)node * 64 + lane];
  const float RSQ = 0.99999500003749969f;
  float o0 = fmaxf((e0 * a.x + e1 * b.x + e2 * c.x) * (bn0g[f] * RSQ) + bn0b[f], 0.f);
  float o1 = fmaxf((e0 * a.y + e1 * b.y + e2 * c.y) * (bn0g[f + 1] * RSQ) + bn0b[f + 1], 0.f);
  xx[(size_t)node * 128 + f] = o0;
  xx[(size_t)node * 128 + f + 1] = o1;
}

__global__ void alog_kernel(const float* __restrict__ t, const float* __restrict__ w,
                            const float* __restrict__ b, float* __restrict__ alog, int n){
  int node = blockIdx.x * 4 + (int)(threadIdx.x >> 6);
  if (node >= n) return;
  int lane = threadIdx.x & 63;
  int f = lane * 2;
  float2 tv = ((const float2*)t)[(size_t)node * 64 + lane];
  float p = tv.x * w[f] + tv.y * w[f + 1];
#pragma unroll
  for (int off = 1; off < 64; off <<= 1) p += __shfl_xor(p, off, 64);
  if (lane == 0) alog[node] = p + b[0];
}

// ---------------- pooling + head ----------------

__global__ void pool_kernel(const float* __restrict__ xx, const float* __restrict__ alog,
                            float* __restrict__ hg, int npg){
  __shared__ float red[256];
  __shared__ float wts[1008];
  int g = blockIdx.x, tid = threadIdx.x;
  size_t base = (size_t)g * npg;
  float m = -1e30f;
  for (int n2 = tid; n2 < npg; n2 += 256) m = fmaxf(m, alog[base + n2]);
  red[tid] = m; __syncthreads();
  for (int off = 128; off > 0; off >>= 1){ if (tid < off) red[tid] = fmaxf(red[tid], red[tid + off]); __syncthreads(); }
  float gm = red[0]; __syncthreads();
  float z = 0.f;
  for (int n2 = tid; n2 < npg; n2 += 256){ float w = __expf(alog[base + n2] - gm); wts[n2] = w; z += w; }
  red[tid] = z; __syncthreads();
  for (int off = 128; off > 0; off >>= 1){ if (tid < off) red[tid] += red[tid + off]; __syncthreads(); }
  float gz = red[0]; __syncthreads();
  int f = tid & 127, half = tid >> 7;
  float add = 0.f, mx = -1e30f, att = 0.f;
  for (int n2 = half; n2 < npg; n2 += 2){
    float v = xx[(base + n2) * 128 + f];
    add += v; mx = fmaxf(mx, v); att += v * wts[n2];
  }
  red[tid] = add; __syncthreads();
  if (half == 0) add += red[tid + 128];
  __syncthreads(); red[tid] = mx; __syncthreads();
  if (half == 0) mx = fmaxf(mx, red[tid + 128]);
  __syncthreads(); red[tid] = att; __syncthreads();
  if (half == 0) att += red[tid + 128];
  if (half == 0){
    float* o = hg + (size_t)g * 512;
    o[f] = add / (float)npg;    // mean
    o[128 + f] = mx;            // max
    o[256 + f] = add;           // add
    o[384 + f] = att / gz;      // att
  }
}

__global__ void head_kernel(const float* __restrict__ hg, const float* __restrict__ combW,
                            const float* __restrict__ combB, const float* __restrict__ c1W,
                            const float* __restrict__ c1B, const float* __restrict__ c2W,
                            const float* __restrict__ c2B, float* __restrict__ out){
  __shared__ float cat[512];
  __shared__ float h1[128];
  __shared__ float h2[64];
  int g = blockIdx.x, tid = threadIdx.x;   // block 128
#pragma unroll
  for (int j = 0; j < 4; ++j) cat[tid + 128 * j] = hg[(size_t)g * 512 + tid + 128 * j];
  __syncthreads();
  float a = combB[tid];
  for (int k = 0; k < 512; ++k) a += cat[k] * combW[(size_t)k * 128 + tid];
  h1[tid] = a; __syncthreads();
  if (tid < 64){
    float b = c1B[tid];
    for (int k = 0; k < 128; ++k) b += h1[k] * c1W[(size_t)k * 64 + tid];
    h2[tid] = fmaxf(b, 0.f);
  }
  __syncthreads();
  if (tid < 2){
    float o = c2B[tid];
    for (int k = 0; k < 64; ++k) o += h2[k] * c2W[(size_t)k * 2 + tid];
    out[(size_t)g * 2 + tid] = o;
  }
}

// ---------------- host ----------------

static void launch_gemm(int epi, dim3 grid, hipStream_t st,
                        const float* A0, const float* A1, const float* A2,
                        const unsigned short* W0, const unsigned short* W1, const unsigned short* W2,
                        const float* bias, const float* bng, const float* bnb,
                        const float* resid, float* C, int nrows){
  switch (epi){
    case 0: gemm_kernel<0><<<grid, 256, 0, st>>>(A0, A1, A2, W0, W1, W2, bias, bng, bnb, resid, C, nrows); break;
    case 1: gemm_kernel<1><<<grid, 256, 0, st>>>(A0, A1, A2, W0, W1, W2, bias, bng, bnb, resid, C, nrows); break;
    case 2: gemm_kernel<2><<<grid, 256, 0, st>>>(A0, A1, A2, W0, W1, W2, bias, bng, bnb, resid, C, nrows); break;
    default: gemm_kernel<3><<<grid, 256, 0, st>>>(A0, A1, A2, W0, W1, W2, bias, bng, bnb, resid, C, nrows); break;
  }
}

extern "C" void kernel_launch(void* const* d_in, const int* in_sizes, int n_in,
                              void* d_out, int out_size, void* d_ws, size_t ws_size,
                              hipStream_t stream){
  (void)n_in; (void)out_size; (void)ws_size;
  const int N = in_sizes[0] / 128;
  const int E = in_sizes[1] / 2;
  const int NG = 50;
  const int npg = N / NG;

  const float* x       = (const float*)d_in[0];
  const int*   ei      = (const int*)d_in[1];
  const int*   srcI    = ei;
  const int*   dstI    = ei + E;
  const float* W_gcn   = (const float*)d_in[3];
  const float* b_gcn   = (const float*)d_in[4];
  const float* gin_W1  = (const float*)d_in[5];
  const float* gin_b1  = (const float*)d_in[6];
  const float* gin_W2  = (const float*)d_in[7];
  const float* gin_b2  = (const float*)d_in[8];
  const float* W_gat   = (const float*)d_in[9];
  const float* b_gat   = (const float*)d_in[10];
  const float* a_src   = (const float*)d_in[11];
  const float* a_dst   = (const float*)d_in[12];
  const float* gproj_W = (const float*)d_in[13];
  const float* gproj_b = (const float*)d_in[14];
  const float* gate_W1 = (const float*)d_in[15];
  const float* gate_b1 = (const float*)d_in[16];
  const float* gate_W2 = (const float*)d_in[17];
  const float* gate_b2 = (const float*)d_in[18];
  const float* bn0_g   = (const float*)d_in[19];
  const float* bn0_b   = (const float*)d_in[20];
  const float* rel_W   = (const float*)d_in[21];
  const float* rel_b   = (const float*)d_in[22];
  const float* root_W  = (const float*)d_in[23];
  const float* bn_g    = (const float*)d_in[24];
  const float* bn_b    = (const float*)d_in[25];
  const float* jump_W  = (const float*)d_in[26];
  const float* jump_b  = (const float*)d_in[27];
  const float* att_W1  = (const float*)d_in[28];
  const float* att_b1  = (const float*)d_in[29];
  const float* att_W2  = (const float*)d_in[30];
  const float* att_b2  = (const float*)d_in[31];
  const float* comb_W  = (const float*)d_in[32];
  const float* comb_b  = (const float*)d_in[33];
  const float* cls_W1  = (const float*)d_in[34];
  const float* cls_b1  = (const float*)d_in[35];
  const float* cls_W2  = (const float*)d_in[36];
  const float* cls_b2  = (const float*)d_in[37];
  float* out = (float*)d_out;

  char* wp = (char*)d_ws;
  auto alloc = [&](size_t b) -> char* {
    char* p = wp; wp += (b + 511) & ~(size_t)511; return p;
  };
  unsigned int* cnt  = (unsigned int*)alloc((size_t)N * 4);
  unsigned int* fill = (unsigned int*)alloc((size_t)N * 4);
  unsigned int* rp   = (unsigned int*)alloc(((size_t)N + 1) * 4);
  int* colA          = (int*)alloc((size_t)E * 4);
  float* dinv        = (float*)alloc((size_t)N * 4);
  float* als         = (float*)alloc((size_t)N * 16);
  float* ald         = (float*)alloc((size_t)N * 16);
  float* alogv       = (float*)alloc((size_t)N * 4);
  unsigned short* WtAll = (unsigned short*)alloc((size_t)18 * 16384 * 2);
  float* hg          = (float*)alloc((size_t)NG * 512 * 4);
  float* S0 = (float*)alloc((size_t)N * 128 * 4);
  float* S1 = (float*)alloc((size_t)N * 128 * 4);
  float* S2 = (float*)alloc((size_t)N * 128 * 4);
  float* S3 = (float*)alloc((size_t)N * 128 * 4);
  float* S4 = (float*)alloc((size_t)N * 128 * 4);

  // --- CSR build ---
  int zn = (int)(((char*)rp - (char*)cnt) / 4);   // cnt + fill regions (contiguous)
  zero_u32<<<(zn + 255) / 256, 256, 0, stream>>>(cnt, zn);
  hist_kernel<<<(E + 255) / 256, 256, 0, stream>>>(dstI, cnt, E);
  int ch = (N + 1023) / 1024;
  scan_kernel<<<1, 1024, 0, stream>>>(cnt, rp, N, ch);
  scatter_kernel<<<(E + 255) / 256, 256, 0, stream>>>(srcI, dstI, rp, fill, colA, E);
  dinv_kernel<<<(N + 255) / 256, 256, 0, stream>>>(cnt, dinv, N);

  // --- weight transpose/cast ---
  WSrc wsrc;
  wsrc.p[0] = W_gcn;  wsrc.p[1] = W_gat;  wsrc.p[2] = gin_W1; wsrc.p[3] = gin_W2;
  wsrc.p[4] = gproj_W;
  wsrc.p[5] = gate_W1;      wsrc.p[6] = gate_W1 + 16384; wsrc.p[7] = gate_W1 + 32768;
  wsrc.p[8] = rel_W;        wsrc.p[9] = rel_W + 16384;   wsrc.p[10] = rel_W + 32768;
  wsrc.p[11] = root_W;      wsrc.p[12] = root_W + 16384; wsrc.p[13] = root_W + 32768;
  wsrc.p[14] = jump_W;      wsrc.p[15] = jump_W + 16384; wsrc.p[16] = jump_W + 32768;
  wsrc.p[17] = att_W1;
  wtrans_kernel<<<18, 256, 0, stream>>>(wsrc, WtAll);

  dim3 gg((N + 63) / 64);
  int nb4 = (N + 3) / 4;
  #define WT(i) (WtAll + (size_t)(i) * 16384)
  const unsigned short* Z = nullptr;
  const float* FZ = nullptr;

  // stems
  launch_gemm(0, gg, stream, x, FZ, FZ, WT(0), Z, Z, FZ, FZ, FZ, FZ, S0, N);   // h_gcn = x@W_gcn
  launch_gemm(0, gg, stream, x, FZ, FZ, WT(1), Z, Z, FZ, FZ, FZ, FZ, S1, N);   // xp = x@W_gat
  alpair_kernel<<<nb4, 256, 0, stream>>>(S1, a_src, a_dst, als, ald, N);
  gin_agg_kernel<<<nb4, 256, 0, stream>>>(x, rp, colA, S2, N);                 // xs = x + aggr
  launch_gemm(2, gg, stream, S2, FZ, FZ, WT(2), Z, Z, gin_b1, FZ, FZ, FZ, S3, N); // t_gin
  launch_gemm(2, gg, stream, S3, FZ, FZ, WT(3), Z, Z, gin_b2, FZ, FZ, FZ, S2, N); // x_gin
  gcn_agg_kernel<<<nb4, 256, 0, stream>>>(S0, dinv, rp, colA, b_gcn, S3, N);   // x_gcn
  gat_agg_kernel<<<nb4, 256, 0, stream>>>(S1, als, ald, rp, colA, b_gat, S0, N); // gat_pre
  launch_gemm(1, gg, stream, S0, FZ, FZ, WT(4), Z, Z, gproj_b, FZ, FZ, FZ, S1, N); // x_gat

  // gated fusion
  launch_gemm(2, gg, stream, S3, S2, S1, WT(5), WT(6), WT(7), gate_b1, FZ, FZ, FZ, S4, N); // t_gate
  combine_kernel<<<nb4, 256, 0, stream>>>(S4, gate_W2, gate_b2, S3, S2, S1, bn0_g, bn0_b, S0, N); // xx

  // GraphConv stack
  sum_agg_kernel<<<nb4, 256, 0, stream>>>(S0, rp, colA, S1, N);
  launch_gemm(3, gg, stream, S1, S0, FZ, WT(8), WT(11), Z, rel_b, bn_g, bn_b, S0, S2, N);          // reps0
  sum_agg_kernel<<<nb4, 256, 0, stream>>>(S2, rp, colA, S1, N);
  launch_gemm(3, gg, stream, S1, S2, FZ, WT(9), WT(12), Z, rel_b + 128, bn_g + 128, bn_b + 128, S2, S3, N); // reps1
  sum_agg_kernel<<<nb4, 256, 0, stream>>>(S3, rp, colA, S1, N);
  launch_gemm(3, gg, stream, S1, S3, FZ, WT(10), WT(13), Z, rel_b + 256, bn_g + 256, bn_b + 256, S3, S4, N); // reps2

  // JK cat + attention logits
  launch_gemm(1, gg, stream, S2, S3, S4, WT(14), WT(15), WT(16), jump_b, FZ, FZ, FZ, S0, N); // xx2
  launch_gemm(2, gg, stream, S0, FZ, FZ, WT(17), Z, Z, att_b1, FZ, FZ, FZ, S1, N);           // t_att
  alog_kernel<<<nb4, 256, 0, stream>>>(S1, att_W2, att_b2, alogv, N);

  // pooling + head
  pool_kernel<<<NG, 256, 0, stream>>>(S0, alogv, hg, npg);
  head_kernel<<<NG, 128, 0, stream>>>(hg, comb_W, comb_b, cls_W1, cls_b1, cls_W2, cls_b2, out);
}

// Round 2
// 999.920 us; speedup vs baseline: 1.2039x; 1.2039x over previous
//
#include <hip/hip_runtime.h>

typedef float f32x4 __attribute__((ext_vector_type(4)));
typedef short s16x8 __attribute__((ext_vector_type(8)));

#define LDA 136   // padded LDS row length (bf16 elems): 272B rows -> ~2-way bank aliasing (free)

static __device__ __forceinline__ unsigned short f2bf(float f){
  union { float f; unsigned int u; } v; v.f = f;
  unsigned int u = v.u;
  return (unsigned short)((u + 0x7fffu + ((u >> 16) & 1u)) >> 16);
}

static __device__ __forceinline__ float lrelu02(float x){ return x > 0.f ? x : 0.2f * x; }

// bijective XCD swizzle (m204)
static __device__ __forceinline__ int xcd_swz(int bid, int nwg){
  int q = nwg >> 3, r = nwg & 7, x = bid & 7, i = bid >> 3;
  return (x < r ? x * (q + 1) : r * (q + 1) + (x - r) * q) + i;
}

// ---------------- CSR build ----------------

__global__ void zero_u32(unsigned int* p, int n){
  int i = blockIdx.x * 256 + threadIdx.x;
  if (i < n) p[i] = 0u;
}

__global__ void hist_kernel(const int* __restrict__ dst, unsigned int* __restrict__ cnt, int E){
  int i = blockIdx.x * 256 + threadIdx.x;
  if (i < E) atomicAdd(&cnt[dst[i]], 1u);
}

// 3-kernel exclusive scan of cnt[0..n) -> rp, plus rp[n] = E
__global__ void scan1_kernel(const unsigned int* __restrict__ cnt, unsigned int* __restrict__ rp,
                             unsigned int* __restrict__ bsum, int n){
  __shared__ unsigned int s[1024];
  int b = blockIdx.x, tid = threadIdx.x, i = b * 1024 + tid;
  unsigned int v = (i < n) ? cnt[i] : 0u;
  s[tid] = v; __syncthreads();
  for (int off = 1; off < 1024; off <<= 1){
    unsigned int t = (tid >= off) ? s[tid - off] : 0u;
    __syncthreads();
    s[tid] += t;
    __syncthreads();
  }
  if (i < n) rp[i] = s[tid] - v;     // exclusive within block
  if (tid == 1023) bsum[b] = s[1023];
}

__global__ void scan2_kernel(unsigned int* __restrict__ bsum, int nb){
  __shared__ unsigned int s[256];
  int tid = threadIdx.x;
  unsigned int v = (tid < nb) ? bsum[tid] : 0u;
  s[tid] = v; __syncthreads();
  for (int off = 1; off < 256; off <<= 1){
    unsigned int t = (tid >= off) ? s[tid - off] : 0u;
    __syncthreads();
    s[tid] += t;
    __syncthreads();
  }
  if (tid < nb) bsum[tid] = s[tid] - v;  // exclusive block offsets
}

__global__ void scan3_kernel(unsigned int* __restrict__ rp, const unsigned int* __restrict__ bsum,
                             int n, unsigned int Etot){
  int i = blockIdx.x * 256 + threadIdx.x;
  if (i < n) rp[i] += bsum[i >> 10];
  if (i == 0) rp[n] = Etot;
}

__global__ void scatter_kernel(const int* __restrict__ src, const int* __restrict__ dst,
                               const unsigned int* __restrict__ rp, unsigned int* __restrict__ fill,
                               int* __restrict__ colA, int E){
  int i = blockIdx.x * 256 + threadIdx.x;
  if (i < E){
    int d = dst[i];
    unsigned int pos = rp[d] + atomicAdd(&fill[d], 1u);
    colA[pos] = src[i];
  }
}

__global__ void dinv_kernel(const unsigned int* __restrict__ cnt, float* __restrict__ dinv, int n){
  int i = blockIdx.x * 256 + threadIdx.x;
  if (i < n) dinv[i] = rsqrtf((float)cnt[i] + 1.0f);
}

// ---------------- weight transpose (f32 [128,128] row-major -> bf16 [col][k]) ----------------

struct WSrc { const float* p[18]; };

__global__ void wtrans_kernel(WSrc s, unsigned short* __restrict__ dstAll){
  const float* src = s.p[blockIdx.x];
  unsigned short* dst = dstAll + (size_t)blockIdx.x * 16384;
  __shared__ float st[64][129];
  int tid = threadIdx.x;
  int kb = blockIdx.y * 64;
#pragma unroll
  for (int j = 0; j < 8; ++j){
    int e = tid + 256 * j;          // 0..2047
    int r = e >> 5, c4 = (e & 31) * 4;
    float4 v = *(const float4*)(src + (size_t)(kb + r) * 128 + c4);
    st[r][c4] = v.x; st[r][c4+1] = v.y; st[r][c4+2] = v.z; st[r][c4+3] = v.w;
  }
  __syncthreads();
#pragma unroll
  for (int j = 0; j < 8; ++j){
    int e = tid + 256 * j;          // 0..2047
    int c = e >> 4, k4 = (e & 15) * 4;
    ushort4 o;
    o.x = f2bf(st[k4+0][c]); o.y = f2bf(st[k4+1][c]);
    o.z = f2bf(st[k4+2][c]); o.w = f2bf(st[k4+3][c]);
    *(ushort4*)(dst + (size_t)c * 128 + kb + k4) = o;
  }
}

// ---------------- MFMA GEMM: C[nrows,128] = sum_p A_p[nrows,128] @ W_p[128,128] (+epilogue) ----------------
// W_p given pre-transposed bf16: Wt[col][k].
// EPI: 0 none, 1 +bias, 2 relu(+bias), 3 conv: relu((acc+bias)*bn_g*RSQ + bn_b) + resid

template<int EPI>
__launch_bounds__(256, 2)
__global__ void gemm_kernel(const float* __restrict__ A0, const float* __restrict__ A1, const float* __restrict__ A2,
                            const unsigned short* __restrict__ W0, const unsigned short* __restrict__ W1, const unsigned short* __restrict__ W2,
                            const float* __restrict__ bias, const float* __restrict__ bng, const float* __restrict__ bnb,
                            const float* __restrict__ resid, float* __restrict__ C, int nrows)
{
  __shared__ unsigned short As[64 * LDA];
  __shared__ unsigned short Wt[128 * LDA];
  const int tid = threadIdx.x;
  const int wave = tid >> 6, lane = tid & 63;
  const int row0 = blockIdx.x * 64;
  const float* Aps[3] = {A0, A1, A2};
  const unsigned short* Wps[3] = {W0, W1, W2};
  f32x4 acc[8];
#pragma unroll
  for (int i = 0; i < 8; ++i) acc[i] = (f32x4){0.f, 0.f, 0.f, 0.f};

  for (int p = 0; p < 3; ++p){
    const float* Ap = Aps[p];
    if (Ap == nullptr) break;
    const unsigned short* Wp = Wps[p];
    if (p) __syncthreads();            // LDS reuse guard
    // stage A tile (f32 -> bf16)
#pragma unroll
    for (int j = 0; j < 8; ++j){
      int e = tid + 256 * j;           // 0..2047 (64 rows x 32 float4)
      int r = e >> 5, k4 = (e & 31) * 4;
      int gr = row0 + r;
      float4 v = make_float4(0.f, 0.f, 0.f, 0.f);
      if (gr < nrows) v = *(const float4*)(Ap + (size_t)gr * 128 + k4);
      ushort4 o; o.x = f2bf(v.x); o.y = f2bf(v.y); o.z = f2bf(v.z); o.w = f2bf(v.w);
      *(ushort4*)(As + r * LDA + k4) = o;
    }
    // stage Wt tile (already bf16, transposed)
#pragma unroll
    for (int j = 0; j < 8; ++j){
      int e = tid + 256 * j;           // 0..2047 (128 cols x 16 chunks of 8)
      int colw = e >> 4, k8 = (e & 15) * 8;
      *(s16x8*)(Wt + colw * LDA + k8) = *(const s16x8*)(Wp + (size_t)colw * 128 + k8);
    }
    __syncthreads();
#pragma unroll
    for (int kc = 0; kc < 4; ++kc){
      int ko = kc * 32 + (lane >> 4) * 8;
      s16x8 av = *(const s16x8*)(As + (wave * 16 + (lane & 15)) * LDA + ko);
#pragma unroll
      for (int ct = 0; ct < 8; ++ct){
        s16x8 bv = *(const s16x8*)(Wt + (ct * 16 + (lane & 15)) * LDA + ko);
        acc[ct] = __builtin_amdgcn_mfma_f32_16x16x32_bf16(av, bv, acc[ct], 0, 0, 0);
      }
    }
  }
  const float RSQ = 0.99999500003749969f; // rsqrt(1 + 1e-5)
#pragma unroll
  for (int ct = 0; ct < 8; ++ct){
    int colg = ct * 16 + (lane & 15);
    float bv_ = (EPI >= 1) ? bias[colg] : 0.f;
    float sg = (EPI == 3) ? bng[colg] * RSQ : 0.f;
    float sb = (EPI == 3) ? bnb[colg] : 0.f;
#pragma unroll
    for (int r = 0; r < 4; ++r){
      int rowg = row0 + wave * 16 + (lane >> 4) * 4 + r;
      if (rowg < nrows){
        float v = acc[ct][r];
        if (EPI == 1) v += bv_;
        else if (EPI == 2) v = fmaxf(v + bv_, 0.f);
        else if (EPI == 3){
          v = (v + bv_) * sg + sb;
          v = fmaxf(v, 0.f) + resid[(size_t)rowg * 128 + colg];
        }
        C[(size_t)rowg * 128 + colg] = v;
      }
    }
  }
}

// Dual-output GEMM sharing A: C0 = A@W0, C1 = A@W1 (no epilogue). Stages A once.
__launch_bounds__(256, 2)
__global__ void gemm_dual_kernel(const float* __restrict__ A,
                                 const unsigned short* __restrict__ W0, const unsigned short* __restrict__ W1,
                                 float* __restrict__ C0, float* __restrict__ C1, int nrows)
{
  __shared__ unsigned short As[64 * LDA];
  __shared__ unsigned short Wt[128 * LDA];
  const int tid = threadIdx.x;
  const int wave = tid >> 6, lane = tid & 63;
  const int row0 = blockIdx.x * 64;
  f32x4 acc0[8], acc1[8];
#pragma unroll
  for (int i = 0; i < 8; ++i){ acc0[i] = (f32x4){0.f,0.f,0.f,0.f}; acc1[i] = (f32x4){0.f,0.f,0.f,0.f}; }

  // stage A tile (f32 -> bf16)
#pragma unroll
  for (int j = 0; j < 8; ++j){
    int e = tid + 256 * j;
    int r = e >> 5, k4 = (e & 31) * 4;
    int gr = row0 + r;
    float4 v = make_float4(0.f, 0.f, 0.f, 0.f);
    if (gr < nrows) v = *(const float4*)(A + (size_t)gr * 128 + k4);
    ushort4 o; o.x = f2bf(v.x); o.y = f2bf(v.y); o.z = f2bf(v.z); o.w = f2bf(v.w);
    *(ushort4*)(As + r * LDA + k4) = o;
  }
  // stage W0
#pragma unroll
  for (int j = 0; j < 8; ++j){
    int e = tid + 256 * j;
    int colw = e >> 4, k8 = (e & 15) * 8;
    *(s16x8*)(Wt + colw * LDA + k8) = *(const s16x8*)(W0 + (size_t)colw * 128 + k8);
  }
  __syncthreads();
  // A fragments held in registers, reused for both weight sets
  s16x8 av[4];
#pragma unroll
  for (int kc = 0; kc < 4; ++kc)
    av[kc] = *(const s16x8*)(As + (wave * 16 + (lane & 15)) * LDA + kc * 32 + (lane >> 4) * 8);
#pragma unroll
  for (int kc = 0; kc < 4; ++kc){
    int ko = kc * 32 + (lane >> 4) * 8;
#pragma unroll
    for (int ct = 0; ct < 8; ++ct){
      s16x8 bv = *(const s16x8*)(Wt + (ct * 16 + (lane & 15)) * LDA + ko);
      acc0[ct] = __builtin_amdgcn_mfma_f32_16x16x32_bf16(av[kc], bv, acc0[ct], 0, 0, 0);
    }
  }
  __syncthreads();
  // stage W1
#pragma unroll
  for (int j = 0; j < 8; ++j){
    int e = tid + 256 * j;
    int colw = e >> 4, k8 = (e & 15) * 8;
    *(s16x8*)(Wt + colw * LDA + k8) = *(const s16x8*)(W1 + (size_t)colw * 128 + k8);
  }
  __syncthreads();
#pragma unroll
  for (int kc = 0; kc < 4; ++kc){
    int ko = kc * 32 + (lane >> 4) * 8;
#pragma unroll
    for (int ct = 0; ct < 8; ++ct){
      s16x8 bv = *(const s16x8*)(Wt + (ct * 16 + (lane & 15)) * LDA + ko);
      acc1[ct] = __builtin_amdgcn_mfma_f32_16x16x32_bf16(av[kc], bv, acc1[ct], 0, 0, 0);
    }
  }
#pragma unroll
  for (int ct = 0; ct < 8; ++ct){
    int colg = ct * 16 + (lane & 15);
#pragma unroll
    for (int r = 0; r < 4; ++r){
      int rowg = row0 + wave * 16 + (lane >> 4) * 4 + r;
      if (rowg < nrows){
        C0[(size_t)rowg * 128 + colg] = acc0[ct][r];
        C1[(size_t)rowg * 128 + colg] = acc1[ct][r];
      }
    }
  }
}

// ---------------- aggregation kernels (wave per node, float2 per lane) ----------------

__global__ void gin_agg_kernel(const float* __restrict__ x, const unsigned int* __restrict__ rp,
                               const int* __restrict__ col, float* __restrict__ xs, int n){
  int bid = xcd_swz(blockIdx.x, gridDim.x);
  int node = bid * 4 + (int)(threadIdx.x >> 6);
  if (node >= n) return;
  int lane = threadIdx.x & 63;
  const float2* xin = (const float2*)x;
  float2 acc = xin[(size_t)node * 64 + lane];   // (1+0)*x self term
  unsigned int rs = rp[node], re = rp[node + 1];
  for (unsigned int e = rs; e < re; ++e){
    int s = col[e];
    float2 v = xin[(size_t)s * 64 + lane];
    acc.x += v.x; acc.y += v.y;
  }
  ((float2*)xs)[(size_t)node * 64 + lane] = acc;
}

__global__ void gcn_agg_kernel(const float* __restrict__ h, const float* __restrict__ dinv,
                               const unsigned int* __restrict__ rp, const int* __restrict__ col,
                               const float* __restrict__ b, float* __restrict__ out, int n){
  int bid = xcd_swz(blockIdx.x, gridDim.x);
  int node = bid * 4 + (int)(threadIdx.x >> 6);
  if (node >= n) return;
  int lane = threadIdx.x & 63;
  const float2* hv = (const float2*)h;
  float di = dinv[node];
  float2 a0 = hv[(size_t)node * 64 + lane];
  float2 acc = make_float2(a0.x * di, a0.y * di);   // self loop: h[i]*dinv[i]
  unsigned int rs = rp[node], re = rp[node + 1];
  for (unsigned int e = rs; e < re; ++e){
    int s = col[e];
    float ds = dinv[s];
    float2 v = hv[(size_t)s * 64 + lane];
    acc.x += v.x * ds; acc.y += v.y * ds;
  }
  int f = lane * 2;
  out[(size_t)node * 128 + f]     = fmaxf(acc.x * di + b[f], 0.f);
  out[(size_t)node * 128 + f + 1] = fmaxf(acc.y * di + b[f + 1], 0.f);
}

__global__ void sum_agg_kernel(const float* __restrict__ x, const unsigned int* __restrict__ rp,
                               const int* __restrict__ col, float* __restrict__ out, int n){
  int bid = xcd_swz(blockIdx.x, gridDim.x);
  int node = bid * 4 + (int)(threadIdx.x >> 6);
  if (node >= n) return;
  int lane = threadIdx.x & 63;
  const float2* xin = (const float2*)x;
  float2 acc = make_float2(0.f, 0.f);
  unsigned int rs = rp[node], re = rp[node + 1];
  for (unsigned int e = rs; e < re; ++e){
    int s = col[e];
    float2 v = xin[(size_t)s * 64 + lane];
    acc.x += v.x; acc.y += v.y;
  }
  ((float2*)out)[(size_t)node * 64 + lane] = acc;
}

__global__ void gat_agg_kernel(const float* __restrict__ xp, const float* __restrict__ als,
                               const float* __restrict__ ald, const unsigned int* __restrict__ rp,
                               const int* __restrict__ col, const float* __restrict__ bgat,
                               float* __restrict__ out, int n){
  int bid = xcd_swz(blockIdx.x, gridDim.x);
  int node = bid * 4 + (int)(threadIdx.x >> 6);
  if (node >= n) return;
  int lane = threadIdx.x & 63;
  int h = lane >> 4;
  float ad = ald[(size_t)node * 4 + h];
  unsigned int rs = rp[node], re = rp[node + 1];
  float eself = lrelu02(als[(size_t)node * 4 + h] + ad);
  float m = eself;
  for (unsigned int e = rs; e < re; ++e){
    int s = col[e];
    m = fmaxf(m, lrelu02(als[(size_t)s * 4 + h] + ad));
  }
  const float2* xv = (const float2*)xp;
  float w = __expf(eself - m);
  float2 sv = xv[(size_t)node * 64 + lane];
  float2 acc = make_float2(sv.x * w, sv.y * w);
  float denom = w;
  for (unsigned int e = rs; e < re; ++e){
    int s = col[e];
    float we = __expf(lrelu02(als[(size_t)s * 4 + h] + ad) - m);
    float2 v = xv[(size_t)s * 64 + lane];
    acc.x += v.x * we; acc.y += v.y * we;
    denom += we;
  }
  float inv = 1.0f / denom;
  int f = lane * 2;
  out[(size_t)node * 128 + f]     = fmaxf(acc.x * inv + bgat[f], 0.f);
  out[(size_t)node * 128 + f + 1] = fmaxf(acc.y * inv + bgat[f + 1], 0.f);
}

// ---------------- small per-node kernels ----------------

__global__ void alpair_kernel(const float* __restrict__ xp, const float* __restrict__ a_src,
                              const float* __restrict__ a_dst, float* __restrict__ als,
                              float* __restrict__ ald, int n){
  int node = blockIdx.x * 4 + (int)(threadIdx.x >> 6);
  if (node >= n) return;
  int lane = threadIdx.x & 63;
  int f = lane * 2;
  float2 v = ((const float2*)xp)[(size_t)node * 64 + lane];
  float ps = v.x * a_src[f] + v.y * a_src[f + 1];
  float pd = v.x * a_dst[f] + v.y * a_dst[f + 1];
#pragma unroll
  for (int off = 1; off < 16; off <<= 1){
    ps += __shfl_xor(ps, off, 64);
    pd += __shfl_xor(pd, off, 64);
  }
  if ((lane & 15) == 0){
    int hh = lane >> 4;
    als[(size_t)node * 4 + hh] = ps;
    ald[(size_t)node * 4 + hh] = pd;
  }
}

__global__ void combine_kernel(const float* __restrict__ t, const float* __restrict__ W2,
                               const float* __restrict__ b2, const float* __restrict__ xg,
                               const float* __restrict__ xi, const float* __restrict__ xa,
                               const float* __restrict__ bn0g, const float* __restrict__ bn0b,
                               float* __restrict__ xx, int n){
  int node = blockIdx.x * 4 + (int)(threadIdx.x >> 6);
  if (node >= n) return;
  int lane = threadIdx.x & 63;
  int f = lane * 2;
  float2 tv = ((const float2*)t)[(size_t)node * 64 + lane];
  float p0 = tv.x * W2[f * 3 + 0] + tv.y * W2[(f + 1) * 3 + 0];
  float p1 = tv.x * W2[f * 3 + 1] + tv.y * W2[(f + 1) * 3 + 1];
  float p2 = tv.x * W2[f * 3 + 2] + tv.y * W2[(f + 1) * 3 + 2];
#pragma unroll
  for (int off = 1; off < 64; off <<= 1){
    p0 += __shfl_xor(p0, off, 64);
    p1 += __shfl_xor(p1, off, 64);
    p2 += __shfl_xor(p2, off, 64);
  }
  p0 += b2[0]; p1 += b2[1]; p2 += b2[2];
  float mm = fmaxf(p0, fmaxf(p1, p2));
  float e0 = __expf(p0 - mm), e1 = __expf(p1 - mm), e2 = __expf(p2 - mm);
  float inv = 1.0f / (e0 + e1 + e2);
  e0 *= inv; e1 *= inv; e2 *= inv;
  float2 a = ((const float2*)xg)[(size_t)node * 64 + lane];
  float2 b = ((const float2*)xi)[(size_t)node * 64 + lane];
  float2 c = ((const float2*)xa)[(size_t)node * 64 + lane];
  const float RSQ = 0.99999500003749969f;
  float o0 = fmaxf((e0 * a.x + e1 * b.x + e2 * c.x) * (bn0g[f] * RSQ) + bn0b[f], 0.f);
  float o1 = fmaxf((e0 * a.y + e1 * b.y + e2 * c.y) * (bn0g[f + 1] * RSQ) + bn0b[f + 1], 0.f);
  xx[(size_t)node * 128 + f] = o0;
  xx[(size_t)node * 128 + f + 1] = o1;
}

__global__ void alog_kernel(const float* __restrict__ t, const float* __restrict__ w,
                            const float* __restrict__ b, float* __restrict__ alog, int n){
  int node = blockIdx.x * 4 + (int)(threadIdx.x >> 6);
  if (node >= n) return;
  int lane = threadIdx.x & 63;
  int f = lane * 2;
  float2 tv = ((const float2*)t)[(size_t)node * 64 + lane];
  float p = tv.x * w[f] + tv.y * w[f + 1];
#pragma unroll
  for (int off = 1; off < 64; off <<= 1) p += __shfl_xor(p, off, 64);
  if (lane == 0) alog[node] = p + b[0];
}

// ---------------- pooling + head ----------------

// per-graph attention-softmax stats: gm = max(alog), gz = sum(exp(alog-gm))
__global__ void att_stats_kernel(const float* __restrict__ alog, float* __restrict__ gm,
                                 float* __restrict__ gz, int npg){
  __shared__ float red[256];
  int g = blockIdx.x, tid = threadIdx.x;
  size_t base = (size_t)g * npg;
  float m = -1e30f;
  for (int i = tid; i < npg; i += 256) m = fmaxf(m, alog[base + i]);
  red[tid] = m; __syncthreads();
  for (int off = 128; off > 0; off >>= 1){ if (tid < off) red[tid] = fmaxf(red[tid], red[tid + off]); __syncthreads(); }
  float gmax = red[0]; __syncthreads();
  float z = 0.f;
  for (int i = tid; i < npg; i += 256) z += __expf(alog[base + i] - gmax);
  red[tid] = z; __syncthreads();
  for (int off = 128; off > 0; off >>= 1){ if (tid < off) red[tid] += red[tid + off]; __syncthreads(); }
  if (tid == 0){ gm[g] = gmax; gz[g] = red[0]; }
}

// partial pooling: grid = NG * nparts; each block pools a chunk (<=128 nodes) of one graph
__global__ void pool_partial_kernel(const float* __restrict__ xx, const float* __restrict__ alog,
                                    const float* __restrict__ gm, const float* __restrict__ gz,
                                    float* __restrict__ part, int npg, int nparts){
  __shared__ float wts[128];
  __shared__ float red[256];
  int g = blockIdx.x / nparts, p = blockIdx.x % nparts;
  int chunk = (npg + nparts - 1) / nparts;
  int n0 = p * chunk, n1 = min(npg, n0 + chunk);
  int tid = threadIdx.x;
  float gmax = gm[g], ginv = 1.0f / gz[g];
  size_t base = (size_t)g * npg;
  for (int i = n0 + tid; i < n1; i += 256) wts[i - n0] = __expf(alog[base + i] - gmax) * ginv;
  __syncthreads();
  int f = tid & 127, half = tid >> 7;
  float add = 0.f, mx = -1e30f, att = 0.f;
  for (int n2 = n0 + half; n2 < n1; n2 += 2){
    float v = xx[(base + n2) * 128 + f];
    add += v; mx = fmaxf(mx, v); att += v * wts[n2 - n0];
  }
  red[tid] = add; __syncthreads();
  float addf = add + ((half == 0) ? red[tid + 128] : 0.f);
  __syncthreads(); red[tid] = mx; __syncthreads();
  float mxf = (half == 0) ? fmaxf(mx, red[tid + 128]) : 0.f;
  __syncthreads(); red[tid] = att; __syncthreads();
  float attf = att + ((half == 0) ? red[tid + 128] : 0.f);
  if (half == 0){
    float* o = part + (size_t)(g * nparts + p) * 384;
    o[f] = addf; o[128 + f] = mxf; o[256 + f] = attf;
  }
}

__global__ void pool_final_kernel(const float* __restrict__ part, float* __restrict__ hg,
                                  int npg, int nparts){
  int g = blockIdx.x, f = threadIdx.x;   // 128 threads
  float add = 0.f, mx = -1e30f, att = 0.f;
  for (int p = 0; p < nparts; ++p){
    const float* o = part + (size_t)(g * nparts + p) * 384;
    add += o[f]; mx = fmaxf(mx, o[128 + f]); att += o[256 + f];
  }
  float* o = hg + (size_t)g * 512;
  o[f] = add / (float)npg;    // mean
  o[128 + f] = mx;            // max
  o[256 + f] = add;           // add
  o[384 + f] = att;           // att (already normalized)
}

__global__ void head_kernel(const float* __restrict__ hg, const float* __restrict__ combW,
                            const float* __restrict__ combB, const float* __restrict__ c1W,
                            const float* __restrict__ c1B, const float* __restrict__ c2W,
                            const float* __restrict__ c2B, float* __restrict__ out){
  __shared__ float cat[512];
  __shared__ float h1[128];
  __shared__ float h2[64];
  int g = blockIdx.x, tid = threadIdx.x;   // block 128
#pragma unroll
  for (int j = 0; j < 4; ++j) cat[tid + 128 * j] = hg[(size_t)g * 512 + tid + 128 * j];
  __syncthreads();
  float a = combB[tid];
  for (int k = 0; k < 512; ++k) a += cat[k] * combW[(size_t)k * 128 + tid];
  h1[tid] = a; __syncthreads();
  if (tid < 64){
    float b = c1B[tid];
    for (int k = 0; k < 128; ++k) b += h1[k] * c1W[(size_t)k * 64 + tid];
    h2[tid] = fmaxf(b, 0.f);
  }
  __syncthreads();
  if (tid < 2){
    float o = c2B[tid];
    for (int k = 0; k < 64; ++k) o += h2[k] * c2W[(size_t)k * 2 + tid];
    out[(size_t)g * 2 + tid] = o;
  }
}

// ---------------- host ----------------

static void launch_gemm(int epi, dim3 grid, hipStream_t st,
                        const float* A0, const float* A1, const float* A2,
                        const unsigned short* W0, const unsigned short* W1, const unsigned short* W2,
                        const float* bias, const float* bng, const float* bnb,
                        const float* resid, float* C, int nrows){
  switch (epi){
    case 0: gemm_kernel<0><<<grid, 256, 0, st>>>(A0, A1, A2, W0, W1, W2, bias, bng, bnb, resid, C, nrows); break;
    case 1: gemm_kernel<1><<<grid, 256, 0, st>>>(A0, A1, A2, W0, W1, W2, bias, bng, bnb, resid, C, nrows); break;
    case 2: gemm_kernel<2><<<grid, 256, 0, st>>>(A0, A1, A2, W0, W1, W2, bias, bng, bnb, resid, C, nrows); break;
    default: gemm_kernel<3><<<grid, 256, 0, st>>>(A0, A1, A2, W0, W1, W2, bias, bng, bnb, resid, C, nrows); break;
  }
}

extern "C" void kernel_launch(void* const* d_in, const int* in_sizes, int n_in,
                              void* d_out, int out_size, void* d_ws, size_t ws_size,
                              hipStream_t stream){
  (void)n_in; (void)out_size; (void)ws_size;
  const int N = in_sizes[0] / 128;
  const int E = in_sizes[1] / 2;
  const int NG = 50;
  const int npg = N / NG;

  const float* x       = (const float*)d_in[0];
  const int*   ei      = (const int*)d_in[1];
  const int*   srcI    = ei;
  const int*   dstI    = ei + E;
  const float* W_gcn   = (const float*)d_in[3];
  const float* b_gcn   = (const float*)d_in[4];
  const float* gin_W1  = (const float*)d_in[5];
  const float* gin_b1  = (const float*)d_in[6];
  const float* gin_W2  = (const float*)d_in[7];
  const float* gin_b2  = (const float*)d_in[8];
  const float* W_gat   = (const float*)d_in[9];
  const float* b_gat   = (const float*)d_in[10];
  const float* a_src   = (const float*)d_in[11];
  const float* a_dst   = (const float*)d_in[12];
  const float* gproj_W = (const float*)d_in[13];
  const float* gproj_b = (const float*)d_in[14];
  const float* gate_W1 = (const float*)d_in[15];
  const float* gate_b1 = (const float*)d_in[16];
  const float* gate_W2 = (const float*)d_in[17];
  const float* gate_b2 = (const float*)d_in[18];
  const float* bn0_g   = (const float*)d_in[19];
  const float* bn0_b   = (const float*)d_in[20];
  const float* rel_W   = (const float*)d_in[21];
  const float* rel_b   = (const float*)d_in[22];
  const float* root_W  = (const float*)d_in[23];
  const float* bn_g    = (const float*)d_in[24];
  const float* bn_b    = (const float*)d_in[25];
  const float* jump_W  = (const float*)d_in[26];
  const float* jump_b  = (const float*)d_in[27];
  const float* att_W1  = (const float*)d_in[28];
  const float* att_b1  = (const float*)d_in[29];
  const float* att_W2  = (const float*)d_in[30];
  const float* att_b2  = (const float*)d_in[31];
  const float* comb_W  = (const float*)d_in[32];
  const float* comb_b  = (const float*)d_in[33];
  const float* cls_W1  = (const float*)d_in[34];
  const float* cls_b1  = (const float*)d_in[35];
  const float* cls_W2  = (const float*)d_in[36];
  const float* cls_b2  = (const float*)d_in[37];
  float* out = (float*)d_out;

  char* wp = (char*)d_ws;
  auto alloc = [&](size_t b) -> char* {
    char* p = wp; wp += (b + 511) & ~(size_t)511; return p;
  };
  unsigned int* cnt  = (unsigned int*)alloc((size_t)N * 4);
  unsigned int* fill = (unsigned int*)alloc((size_t)N * 4);
  unsigned int* rp   = (unsigned int*)alloc(((size_t)N + 1) * 4);
  int* colA          = (int*)alloc((size_t)E * 4);
  unsigned int* bsum = (unsigned int*)alloc(256 * 4);
  float* dinv        = (float*)alloc((size_t)N * 4);
  float* als         = (float*)alloc((size_t)N * 16);
  float* ald         = (float*)alloc((size_t)N * 16);
  float* alogv       = (float*)alloc((size_t)N * 4);
  unsigned short* WtAll = (unsigned short*)alloc((size_t)18 * 16384 * 2);
  float* hg          = (float*)alloc((size_t)NG * 512 * 4);
  float* gmv         = (float*)alloc((size_t)NG * 4);
  float* gzv         = (float*)alloc((size_t)NG * 4);
  int nparts = (npg + 99) / 100;                    // chunk <= 100 <= 128
  float* part        = (float*)alloc((size_t)NG * nparts * 384 * 4);
  float* S0 = (float*)alloc((size_t)N * 128 * 4);
  float* S1 = (float*)alloc((size_t)N * 128 * 4);
  float* S2 = (float*)alloc((size_t)N * 128 * 4);
  float* S3 = (float*)alloc((size_t)N * 128 * 4);
  float* S4 = (float*)alloc((size_t)N * 128 * 4);

  // --- CSR build ---
  int zn = (int)(((char*)rp - (char*)cnt) / 4);   // cnt + fill regions (contiguous)
  zero_u32<<<(zn + 255) / 256, 256, 0, stream>>>(cnt, zn);
  hist_kernel<<<(E + 255) / 256, 256, 0, stream>>>(dstI, cnt, E);
  int nbScan = (N + 1023) / 1024;
  scan1_kernel<<<nbScan, 1024, 0, stream>>>(cnt, rp, bsum, N);
  scan2_kernel<<<1, 256, 0, stream>>>(bsum, nbScan);
  scan3_kernel<<<(N + 255) / 256, 256, 0, stream>>>(rp, bsum, N, (unsigned int)E);
  scatter_kernel<<<(E + 255) / 256, 256, 0, stream>>>(srcI, dstI, rp, fill, colA, E);
  dinv_kernel<<<(N + 255) / 256, 256, 0, stream>>>(cnt, dinv, N);

  // --- weight transpose/cast ---
  WSrc wsrc;
  wsrc.p[0] = W_gcn;  wsrc.p[1] = W_gat;  wsrc.p[2] = gin_W1; wsrc.p[3] = gin_W2;
  wsrc.p[4] = gproj_W;
  wsrc.p[5] = gate_W1;      wsrc.p[6] = gate_W1 + 16384; wsrc.p[7] = gate_W1 + 32768;
  wsrc.p[8] = rel_W;        wsrc.p[9] = rel_W + 16384;   wsrc.p[10] = rel_W + 32768;
  wsrc.p[11] = root_W;      wsrc.p[12] = root_W + 16384; wsrc.p[13] = root_W + 32768;
  wsrc.p[14] = jump_W;      wsrc.p[15] = jump_W + 16384; wsrc.p[16] = jump_W + 32768;
  wsrc.p[17] = att_W1;
  wtrans_kernel<<<dim3(18, 2), 256, 0, stream>>>(wsrc, WtAll);

  dim3 gg((N + 63) / 64);
  int nb4 = (N + 3) / 4;
  #define WT(i) (WtAll + (size_t)(i) * 16384)
  const unsigned short* Z = nullptr;
  const float* FZ = nullptr;

  // stems: h_gcn = x@W_gcn, xp = x@W_gat in one pass over x
  gemm_dual_kernel<<<gg, 256, 0, stream>>>(x, WT(0), WT(1), S0, S1, N);
  alpair_kernel<<<nb4, 256, 0, stream>>>(S1, a_src, a_dst, als, ald, N);
  gin_agg_kernel<<<nb4, 256, 0, stream>>>(x, rp, colA, S2, N);                 // xs = x + aggr
  launch_gemm(2, gg, stream, S2, FZ, FZ, WT(2), Z, Z, gin_b1, FZ, FZ, FZ, S3, N); // t_gin
  launch_gemm(2, gg, stream, S3, FZ, FZ, WT(3), Z, Z, gin_b2, FZ, FZ, FZ, S2, N); // x_gin
  gcn_agg_kernel<<<nb4, 256, 0, stream>>>(S0, dinv, rp, colA, b_gcn, S3, N);   // x_gcn
  gat_agg_kernel<<<nb4, 256, 0, stream>>>(S1, als, ald, rp, colA, b_gat, S0, N); // gat_pre
  launch_gemm(1, gg, stream, S0, FZ, FZ, WT(4), Z, Z, gproj_b, FZ, FZ, FZ, S1, N); // x_gat

  // gated fusion
  launch_gemm(2, gg, stream, S3, S2, S1, WT(5), WT(6), WT(7), gate_b1, FZ, FZ, FZ, S4, N); // t_gate
  combine_kernel<<<nb4, 256, 0, stream>>>(S4, gate_W2, gate_b2, S3, S2, S1, bn0_g, bn0_b, S0, N); // xx

  // GraphConv stack
  sum_agg_kernel<<<nb4, 256, 0, stream>>>(S0, rp, colA, S1, N);
  launch_gemm(3, gg, stream, S1, S0, FZ, WT(8), WT(11), Z, rel_b, bn_g, bn_b, S0, S2, N);          // reps0
  sum_agg_kernel<<<nb4, 256, 0, stream>>>(S2, rp, colA, S1, N);
  launch_gemm(3, gg, stream, S1, S2, FZ, WT(9), WT(12), Z, rel_b + 128, bn_g + 128, bn_b + 128, S2, S3, N); // reps1
  sum_agg_kernel<<<nb4, 256, 0, stream>>>(S3, rp, colA, S1, N);
  launch_gemm(3, gg, stream, S1, S3, FZ, WT(10), WT(13), Z, rel_b + 256, bn_g + 256, bn_b + 256, S3, S4, N); // reps2

  // JK cat + attention logits
  launch_gemm(1, gg, stream, S2, S3, S4, WT(14), WT(15), WT(16), jump_b, FZ, FZ, FZ, S0, N); // xx2
  launch_gemm(2, gg, stream, S0, FZ, FZ, WT(17), Z, Z, att_b1, FZ, FZ, FZ, S1, N);           // t_att
  alog_kernel<<<nb4, 256, 0, stream>>>(S1, att_W2, att_b2, alogv, N);

  // pooling + head
  att_stats_kernel<<<NG, 256, 0, stream>>>(alogv, gmv, gzv, npg);
  pool_partial_kernel<<<NG * nparts, 256, 0, stream>>>(S0, alogv, gmv, gzv, part, npg, nparts);
  pool_final_kernel<<<NG, 128, 0, stream>>>(part, hg, npg, nparts);
  head_kernel<<<NG, 128, 0, stream>>>(hg, comb_W, comb_b, cls_W1, cls_b1, cls_W2, cls_b2, out);
}

// Round 3
// 861.729 us; speedup vs baseline: 1.3970x; 1.1604x over previous
//
#include <hip/hip_runtime.h>

typedef float f32x4 __attribute__((ext_vector_type(4)));
typedef short s16x8 __attribute__((ext_vector_type(8)));

#define LDA 136   // padded LDS row length (bf16 elems): 272B rows -> ~2-way bank aliasing (free)

static __device__ __forceinline__ unsigned short f2bf(float f){
  union { float f; unsigned int u; } v; v.f = f;
  unsigned int u = v.u;
  return (unsigned short)((u + 0x7fffu + ((u >> 16) & 1u)) >> 16);
}

static __device__ __forceinline__ float lrelu02(float x){ return x > 0.f ? x : 0.2f * x; }

// bijective XCD swizzle (m204)
static __device__ __forceinline__ int xcd_swz(int bid, int nwg){
  int q = nwg >> 3, r = nwg & 7, x = bid & 7, i = bid >> 3;
  return (x < r ? x * (q + 1) : r * (q + 1) + (x - r) * q) + i;
}

// ---------------- CSR build ----------------

__global__ void zero_u32(unsigned int* p, int n){
  int i = blockIdx.x * 256 + threadIdx.x;
  if (i < n) p[i] = 0u;
}

__global__ void hist_kernel(const int* __restrict__ dst, unsigned int* __restrict__ cnt, int E){
  int i = blockIdx.x * 256 + threadIdx.x;
  if (i < E) atomicAdd(&cnt[dst[i]], 1u);
}

// 3-kernel exclusive scan of cnt[0..n) -> rp, plus rp[n] = E
__global__ void scan1_kernel(const unsigned int* __restrict__ cnt, unsigned int* __restrict__ rp,
                             unsigned int* __restrict__ bsum, int n){
  __shared__ unsigned int s[1024];
  int b = blockIdx.x, tid = threadIdx.x, i = b * 1024 + tid;
  unsigned int v = (i < n) ? cnt[i] : 0u;
  s[tid] = v; __syncthreads();
  for (int off = 1; off < 1024; off <<= 1){
    unsigned int t = (tid >= off) ? s[tid - off] : 0u;
    __syncthreads();
    s[tid] += t;
    __syncthreads();
  }
  if (i < n) rp[i] = s[tid] - v;     // exclusive within block
  if (tid == 1023) bsum[b] = s[1023];
}

__global__ void scan2_kernel(unsigned int* __restrict__ bsum, int nb){
  __shared__ unsigned int s[256];
  int tid = threadIdx.x;
  unsigned int v = (tid < nb) ? bsum[tid] : 0u;
  s[tid] = v; __syncthreads();
  for (int off = 1; off < 256; off <<= 1){
    unsigned int t = (tid >= off) ? s[tid - off] : 0u;
    __syncthreads();
    s[tid] += t;
    __syncthreads();
  }
  if (tid < nb) bsum[tid] = s[tid] - v;  // exclusive block offsets
}

__global__ void scan3_kernel(unsigned int* __restrict__ rp, const unsigned int* __restrict__ bsum,
                             int n, unsigned int Etot){
  int i = blockIdx.x * 256 + threadIdx.x;
  if (i < n) rp[i] += bsum[i >> 10];
  if (i == 0) rp[n] = Etot;
}

__global__ void scatter_kernel(const int* __restrict__ src, const int* __restrict__ dst,
                               const unsigned int* __restrict__ rp, unsigned int* __restrict__ fill,
                               int* __restrict__ colA, int E){
  int i = blockIdx.x * 256 + threadIdx.x;
  if (i < E){
    int d = dst[i];
    unsigned int pos = rp[d] + atomicAdd(&fill[d], 1u);
    colA[pos] = src[i];
  }
}

__global__ void dinv_kernel(const unsigned int* __restrict__ cnt, float* __restrict__ dinv, int n){
  int i = blockIdx.x * 256 + threadIdx.x;
  if (i < n) dinv[i] = rsqrtf((float)cnt[i] + 1.0f);
}

// ---------------- weight transpose (f32 [128,128] row-major -> bf16 [col][k]) ----------------

struct WSrc { const float* p[18]; };

__global__ void wtrans_kernel(WSrc s, unsigned short* __restrict__ dstAll){
  const float* src = s.p[blockIdx.x];
  unsigned short* dst = dstAll + (size_t)blockIdx.x * 16384;
  __shared__ float st[64][129];
  int tid = threadIdx.x;
  int kb = blockIdx.y * 64;
#pragma unroll
  for (int j = 0; j < 8; ++j){
    int e = tid + 256 * j;          // 0..2047
    int r = e >> 5, c4 = (e & 31) * 4;
    float4 v = *(const float4*)(src + (size_t)(kb + r) * 128 + c4);
    st[r][c4] = v.x; st[r][c4+1] = v.y; st[r][c4+2] = v.z; st[r][c4+3] = v.w;
  }
  __syncthreads();
#pragma unroll
  for (int j = 0; j < 8; ++j){
    int e = tid + 256 * j;          // 0..2047
    int c = e >> 4, k4 = (e & 15) * 4;
    ushort4 o;
    o.x = f2bf(st[k4+0][c]); o.y = f2bf(st[k4+1][c]);
    o.z = f2bf(st[k4+2][c]); o.w = f2bf(st[k4+3][c]);
    *(ushort4*)(dst + (size_t)c * 128 + kb + k4) = o;
  }
}

// ---------------- MFMA GEMM: C[nrows,128] = sum_p A_p[nrows,128] @ W_p[128,128] (+epilogue) ----------------
// W_p given pre-transposed bf16: Wt[col][k].
// EPI: 0 none, 1 +bias, 2 relu(+bias), 3 conv: relu((acc+bias)*bn_g*RSQ + bn_b) + resid

template<int EPI>
__launch_bounds__(256, 2)
__global__ void gemm_kernel(const float* __restrict__ A0, const float* __restrict__ A1, const float* __restrict__ A2,
                            const unsigned short* __restrict__ W0, const unsigned short* __restrict__ W1, const unsigned short* __restrict__ W2,
                            const float* __restrict__ bias, const float* __restrict__ bng, const float* __restrict__ bnb,
                            const float* __restrict__ resid, float* __restrict__ C, int nrows)
{
  __shared__ unsigned short As[64 * LDA];
  __shared__ unsigned short Wt[128 * LDA];
  const int tid = threadIdx.x;
  const int wave = tid >> 6, lane = tid & 63;
  const int row0 = blockIdx.x * 64;
  const float* Aps[3] = {A0, A1, A2};
  const unsigned short* Wps[3] = {W0, W1, W2};
  f32x4 acc[8];
#pragma unroll
  for (int i = 0; i < 8; ++i) acc[i] = (f32x4){0.f, 0.f, 0.f, 0.f};

  for (int p = 0; p < 3; ++p){
    const float* Ap = Aps[p];
    if (Ap == nullptr) break;
    const unsigned short* Wp = Wps[p];
    if (p) __syncthreads();            // LDS reuse guard
    // stage A tile (f32 -> bf16)
#pragma unroll
    for (int j = 0; j < 8; ++j){
      int e = tid + 256 * j;           // 0..2047 (64 rows x 32 float4)
      int r = e >> 5, k4 = (e & 31) * 4;
      int gr = row0 + r;
      float4 v = make_float4(0.f, 0.f, 0.f, 0.f);
      if (gr < nrows) v = *(const float4*)(Ap + (size_t)gr * 128 + k4);
      ushort4 o; o.x = f2bf(v.x); o.y = f2bf(v.y); o.z = f2bf(v.z); o.w = f2bf(v.w);
      *(ushort4*)(As + r * LDA + k4) = o;
    }
    // stage Wt tile (already bf16, transposed)
#pragma unroll
    for (int j = 0; j < 8; ++j){
      int e = tid + 256 * j;           // 0..2047 (128 cols x 16 chunks of 8)
      int colw = e >> 4, k8 = (e & 15) * 8;
      *(s16x8*)(Wt + colw * LDA + k8) = *(const s16x8*)(Wp + (size_t)colw * 128 + k8);
    }
    __syncthreads();
#pragma unroll
    for (int kc = 0; kc < 4; ++kc){
      int ko = kc * 32 + (lane >> 4) * 8;
      s16x8 av = *(const s16x8*)(As + (wave * 16 + (lane & 15)) * LDA + ko);
#pragma unroll
      for (int ct = 0; ct < 8; ++ct){
        s16x8 bv = *(const s16x8*)(Wt + (ct * 16 + (lane & 15)) * LDA + ko);
        acc[ct] = __builtin_amdgcn_mfma_f32_16x16x32_bf16(av, bv, acc[ct], 0, 0, 0);
      }
    }
  }
  const float RSQ = 0.99999500003749969f; // rsqrt(1 + 1e-5)
#pragma unroll
  for (int ct = 0; ct < 8; ++ct){
    int colg = ct * 16 + (lane & 15);
    float bv_ = (EPI >= 1) ? bias[colg] : 0.f;
    float sg = (EPI == 3) ? bng[colg] * RSQ : 0.f;
    float sb = (EPI == 3) ? bnb[colg] : 0.f;
#pragma unroll
    for (int r = 0; r < 4; ++r){
      int rowg = row0 + wave * 16 + (lane >> 4) * 4 + r;
      if (rowg < nrows){
        float v = acc[ct][r];
        if (EPI == 1) v += bv_;
        else if (EPI == 2) v = fmaxf(v + bv_, 0.f);
        else if (EPI == 3){
          v = (v + bv_) * sg + sb;
          v = fmaxf(v, 0.f) + resid[(size_t)rowg * 128 + colg];
        }
        C[(size_t)rowg * 128 + colg] = v;
      }
    }
  }
}

// Dual-output GEMM sharing A: C0 = (A@W0)*dscale[row], C1 = A@W1. Stages A once.
__launch_bounds__(256, 2)
__global__ void gemm_dual_kernel(const float* __restrict__ A,
                                 const unsigned short* __restrict__ W0, const unsigned short* __restrict__ W1,
                                 const float* __restrict__ dscale,
                                 float* __restrict__ C0, float* __restrict__ C1, int nrows)
{
  __shared__ unsigned short As[64 * LDA];
  __shared__ unsigned short Wt[128 * LDA];
  const int tid = threadIdx.x;
  const int wave = tid >> 6, lane = tid & 63;
  const int row0 = blockIdx.x * 64;
  f32x4 acc0[8], acc1[8];
#pragma unroll
  for (int i = 0; i < 8; ++i){ acc0[i] = (f32x4){0.f,0.f,0.f,0.f}; acc1[i] = (f32x4){0.f,0.f,0.f,0.f}; }

  // stage A tile (f32 -> bf16)
#pragma unroll
  for (int j = 0; j < 8; ++j){
    int e = tid + 256 * j;
    int r = e >> 5, k4 = (e & 31) * 4;
    int gr = row0 + r;
    float4 v = make_float4(0.f, 0.f, 0.f, 0.f);
    if (gr < nrows) v = *(const float4*)(A + (size_t)gr * 128 + k4);
    ushort4 o; o.x = f2bf(v.x); o.y = f2bf(v.y); o.z = f2bf(v.z); o.w = f2bf(v.w);
    *(ushort4*)(As + r * LDA + k4) = o;
  }
  // stage W0
#pragma unroll
  for (int j = 0; j < 8; ++j){
    int e = tid + 256 * j;
    int colw = e >> 4, k8 = (e & 15) * 8;
    *(s16x8*)(Wt + colw * LDA + k8) = *(const s16x8*)(W0 + (size_t)colw * 128 + k8);
  }
  __syncthreads();
  // A fragments held in registers, reused for both weight sets
  s16x8 av[4];
#pragma unroll
  for (int kc = 0; kc < 4; ++kc)
    av[kc] = *(const s16x8*)(As + (wave * 16 + (lane & 15)) * LDA + kc * 32 + (lane >> 4) * 8);
#pragma unroll
  for (int kc = 0; kc < 4; ++kc){
    int ko = kc * 32 + (lane >> 4) * 8;
#pragma unroll
    for (int ct = 0; ct < 8; ++ct){
      s16x8 bv = *(const s16x8*)(Wt + (ct * 16 + (lane & 15)) * LDA + ko);
      acc0[ct] = __builtin_amdgcn_mfma_f32_16x16x32_bf16(av[kc], bv, acc0[ct], 0, 0, 0);
    }
  }
  __syncthreads();
  // stage W1
#pragma unroll
  for (int j = 0; j < 8; ++j){
    int e = tid + 256 * j;
    int colw = e >> 4, k8 = (e & 15) * 8;
    *(s16x8*)(Wt + colw * LDA + k8) = *(const s16x8*)(W1 + (size_t)colw * 128 + k8);
  }
  __syncthreads();
#pragma unroll
  for (int kc = 0; kc < 4; ++kc){
    int ko = kc * 32 + (lane >> 4) * 8;
#pragma unroll
    for (int ct = 0; ct < 8; ++ct){
      s16x8 bv = *(const s16x8*)(Wt + (ct * 16 + (lane & 15)) * LDA + ko);
      acc1[ct] = __builtin_amdgcn_mfma_f32_16x16x32_bf16(av[kc], bv, acc1[ct], 0, 0, 0);
    }
  }
#pragma unroll
  for (int ct = 0; ct < 8; ++ct){
    int colg = ct * 16 + (lane & 15);
#pragma unroll
    for (int r = 0; r < 4; ++r){
      int rowg = row0 + wave * 16 + (lane >> 4) * 4 + r;
      if (rowg < nrows){
        C0[(size_t)rowg * 128 + colg] = acc0[ct][r] * dscale[rowg];
        C1[(size_t)rowg * 128 + colg] = acc1[ct][r];
      }
    }
  }
}

// ---------------- aggregation kernels (wave per node, float2 per lane, 4x unrolled) ----------------

__global__ void gin_agg_kernel(const float* __restrict__ x, const unsigned int* __restrict__ rp,
                               const int* __restrict__ col, float* __restrict__ xs, int n){
  int bid = xcd_swz(blockIdx.x, gridDim.x);
  int node = bid * 4 + (int)(threadIdx.x >> 6);
  if (node >= n) return;
  int lane = threadIdx.x & 63;
  const float2* xin = (const float2*)x;
  float2 acc = xin[(size_t)node * 64 + lane];   // (1+0)*x self term
  unsigned int rs = rp[node], re = rp[node + 1], e = rs;
  for (; e + 4 <= re; e += 4){
    int s0 = col[e], s1 = col[e+1], s2 = col[e+2], s3 = col[e+3];
    float2 v0 = xin[(size_t)s0 * 64 + lane];
    float2 v1 = xin[(size_t)s1 * 64 + lane];
    float2 v2 = xin[(size_t)s2 * 64 + lane];
    float2 v3 = xin[(size_t)s3 * 64 + lane];
    acc.x += v0.x + v1.x + v2.x + v3.x;
    acc.y += v0.y + v1.y + v2.y + v3.y;
  }
  for (; e < re; ++e){
    int s = col[e];
    float2 v = xin[(size_t)s * 64 + lane];
    acc.x += v.x; acc.y += v.y;
  }
  ((float2*)xs)[(size_t)node * 64 + lane] = acc;
}

// GCN aggregation over pre-scaled hd = (x@W_gcn)*dinv: out = relu(di*(hd[d] + sum_s hd[s]) + b)
__global__ void gcn_agg_kernel(const float* __restrict__ hd, const float* __restrict__ dinv,
                               const unsigned int* __restrict__ rp, const int* __restrict__ col,
                               const float* __restrict__ b, float* __restrict__ out, int n){
  int bid = xcd_swz(blockIdx.x, gridDim.x);
  int node = bid * 4 + (int)(threadIdx.x >> 6);
  if (node >= n) return;
  int lane = threadIdx.x & 63;
  const float2* hv = (const float2*)hd;
  float di = dinv[node];
  float2 acc = hv[(size_t)node * 64 + lane];    // self: hd[d]
  unsigned int rs = rp[node], re = rp[node + 1], e = rs;
  for (; e + 4 <= re; e += 4){
    int s0 = col[e], s1 = col[e+1], s2 = col[e+2], s3 = col[e+3];
    float2 v0 = hv[(size_t)s0 * 64 + lane];
    float2 v1 = hv[(size_t)s1 * 64 + lane];
    float2 v2 = hv[(size_t)s2 * 64 + lane];
    float2 v3 = hv[(size_t)s3 * 64 + lane];
    acc.x += v0.x + v1.x + v2.x + v3.x;
    acc.y += v0.y + v1.y + v2.y + v3.y;
  }
  for (; e < re; ++e){
    int s = col[e];
    float2 v = hv[(size_t)s * 64 + lane];
    acc.x += v.x; acc.y += v.y;
  }
  int f = lane * 2;
  out[(size_t)node * 128 + f]     = fmaxf(acc.x * di + b[f], 0.f);
  out[(size_t)node * 128 + f + 1] = fmaxf(acc.y * di + b[f + 1], 0.f);
}

__global__ void sum_agg_kernel(const float* __restrict__ x, const unsigned int* __restrict__ rp,
                               const int* __restrict__ col, float* __restrict__ out, int n){
  int bid = xcd_swz(blockIdx.x, gridDim.x);
  int node = bid * 4 + (int)(threadIdx.x >> 6);
  if (node >= n) return;
  int lane = threadIdx.x & 63;
  const float2* xin = (const float2*)x;
  float2 acc = make_float2(0.f, 0.f);
  unsigned int rs = rp[node], re = rp[node + 1], e = rs;
  for (; e + 4 <= re; e += 4){
    int s0 = col[e], s1 = col[e+1], s2 = col[e+2], s3 = col[e+3];
    float2 v0 = xin[(size_t)s0 * 64 + lane];
    float2 v1 = xin[(size_t)s1 * 64 + lane];
    float2 v2 = xin[(size_t)s2 * 64 + lane];
    float2 v3 = xin[(size_t)s3 * 64 + lane];
    acc.x += v0.x + v1.x + v2.x + v3.x;
    acc.y += v0.y + v1.y + v2.y + v3.y;
  }
  for (; e < re; ++e){
    int s = col[e];
    float2 v = xin[(size_t)s * 64 + lane];
    acc.x += v.x; acc.y += v.y;
  }
  ((float2*)out)[(size_t)node * 64 + lane] = acc;
}

// One-pass GAT aggregation: softmax max-subtraction dropped (mathematically identity;
// logits are O(1) here, exp arg clamped at 30 for overflow safety).
__global__ void gat_agg_kernel(const float* __restrict__ xp, const float* __restrict__ als,
                               const float* __restrict__ ald, const unsigned int* __restrict__ rp,
                               const int* __restrict__ col, const float* __restrict__ bgat,
                               float* __restrict__ out, int n){
  int bid = xcd_swz(blockIdx.x, gridDim.x);
  int node = bid * 4 + (int)(threadIdx.x >> 6);
  if (node >= n) return;
  int lane = threadIdx.x & 63;
  int h = lane >> 4;
  float ad = ald[(size_t)node * 4 + h];
  const float2* xv = (const float2*)xp;
  // self term
  float w = __expf(fminf(lrelu02(als[(size_t)node * 4 + h] + ad), 30.f));
  float2 sv = xv[(size_t)node * 64 + lane];
  float2 acc = make_float2(sv.x * w, sv.y * w);
  float denom = w;
  unsigned int rs = rp[node], re = rp[node + 1], e = rs;
  for (; e + 4 <= re; e += 4){
    int s0 = col[e], s1 = col[e+1], s2 = col[e+2], s3 = col[e+3];
    float w0 = __expf(fminf(lrelu02(als[(size_t)s0 * 4 + h] + ad), 30.f));
    float w1 = __expf(fminf(lrelu02(als[(size_t)s1 * 4 + h] + ad), 30.f));
    float w2 = __expf(fminf(lrelu02(als[(size_t)s2 * 4 + h] + ad), 30.f));
    float w3 = __expf(fminf(lrelu02(als[(size_t)s3 * 4 + h] + ad), 30.f));
    float2 v0 = xv[(size_t)s0 * 64 + lane];
    float2 v1 = xv[(size_t)s1 * 64 + lane];
    float2 v2 = xv[(size_t)s2 * 64 + lane];
    float2 v3 = xv[(size_t)s3 * 64 + lane];
    acc.x += v0.x * w0 + v1.x * w1 + v2.x * w2 + v3.x * w3;
    acc.y += v0.y * w0 + v1.y * w1 + v2.y * w2 + v3.y * w3;
    denom += w0 + w1 + w2 + w3;
  }
  for (; e < re; ++e){
    int s = col[e];
    float we = __expf(fminf(lrelu02(als[(size_t)s * 4 + h] + ad), 30.f));
    float2 v = xv[(size_t)s * 64 + lane];
    acc.x += v.x * we; acc.y += v.y * we;
    denom += we;
  }
  float inv = 1.0f / denom;
  int f = lane * 2;
  out[(size_t)node * 128 + f]     = fmaxf(acc.x * inv + bgat[f], 0.f);
  out[(size_t)node * 128 + f + 1] = fmaxf(acc.y * inv + bgat[f + 1], 0.f);
}

// ---------------- small per-node kernels ----------------

__global__ void alpair_kernel(const float* __restrict__ xp, const float* __restrict__ a_src,
                              const float* __restrict__ a_dst, float* __restrict__ als,
                              float* __restrict__ ald, int n){
  int node = blockIdx.x * 4 + (int)(threadIdx.x >> 6);
  if (node >= n) return;
  int lane = threadIdx.x & 63;
  int f = lane * 2;
  float2 v = ((const float2*)xp)[(size_t)node * 64 + lane];
  float ps = v.x * a_src[f] + v.y * a_src[f + 1];
  float pd = v.x * a_dst[f] + v.y * a_dst[f + 1];
#pragma unroll
  for (int off = 1; off < 16; off <<= 1){
    ps += __shfl_xor(ps, off, 64);
    pd += __shfl_xor(pd, off, 64);
  }
  if ((lane & 15) == 0){
    int hh = lane >> 4;
    als[(size_t)node * 4 + hh] = ps;
    ald[(size_t)node * 4 + hh] = pd;
  }
}

__global__ void combine_kernel(const float* __restrict__ t, const float* __restrict__ W2,
                               const float* __restrict__ b2, const float* __restrict__ xg,
                               const float* __restrict__ xi, const float* __restrict__ xa,
                               const float* __restrict__ bn0g, const float* __restrict__ bn0b,
                               float* __restrict__ xx, int n){
  int node = blockIdx.x * 4 + (int)(threadIdx.x >> 6);
  if (node >= n) return;
  int lane = threadIdx.x & 63;
  int f = lane * 2;
  float2 tv = ((const float2*)t)[(size_t)node * 64 + lane];
  float p0 = tv.x * W2[f * 3 + 0] + tv.y * W2[(f + 1) * 3 + 0];
  float p1 = tv.x * W2[f * 3 + 1] + tv.y * W2[(f + 1) * 3 + 1];
  float p2 = tv.x * W2[f * 3 + 2] + tv.y * W2[(f + 1) * 3 + 2];
#pragma unroll
  for (int off = 1; off < 64; off <<= 1){
    p0 += __shfl_xor(p0, off, 64);
    p1 += __shfl_xor(p1, off, 64);
    p2 += __shfl_xor(p2, off, 64);
  }
  p0 += b2[0]; p1 += b2[1]; p2 += b2[2];
  float mm = fmaxf(p0, fmaxf(p1, p2));
  float e0 = __expf(p0 - mm), e1 = __expf(p1 - mm), e2 = __expf(p2 - mm);
  float inv = 1.0f / (e0 + e1 + e2);
  e0 *= inv; e1 *= inv; e2 *= inv;
  float2 a = ((const float2*)xg)[(size_t)node * 64 + lane];
  float2 b = ((const float2*)xi)[(size_t)node * 64 + lane];
  float2 c = ((const float2*)xa)[(size_t)node * 64 + lane];
  const float RSQ = 0.99999500003749969f;
  float o0 = fmaxf((e0 * a.x + e1 * b.x + e2 * c.x) * (bn0g[f] * RSQ) + bn0b[f], 0.f);
  float o1 = fmaxf((e0 * a.y + e1 * b.y + e2 * c.y) * (bn0g[f + 1] * RSQ) + bn0b[f + 1], 0.f);
  xx[(size_t)node * 128 + f] = o0;
  xx[(size_t)node * 128 + f + 1] = o1;
}

__global__ void alog_kernel(const float* __restrict__ t, const float* __restrict__ w,
                            const float* __restrict__ b, float* __restrict__ alog, int n){
  int node = blockIdx.x * 4 + (int)(threadIdx.x >> 6);
  if (node >= n) return;
  int lane = threadIdx.x & 63;
  int f = lane * 2;
  float2 tv = ((const float2*)t)[(size_t)node * 64 + lane];
  float p = tv.x * w[f] + tv.y * w[f + 1];
#pragma unroll
  for (int off = 1; off < 64; off <<= 1) p += __shfl_xor(p, off, 64);
  if (lane == 0) alog[node] = p + b[0];
}

// ---------------- pooling + head ----------------

// per-graph attention-softmax stats: gm = max(alog), gz = sum(exp(alog-gm))
__global__ void att_stats_kernel(const float* __restrict__ alog, float* __restrict__ gm,
                                 float* __restrict__ gz, int npg){
  __shared__ float red[256];
  int g = blockIdx.x, tid = threadIdx.x;
  size_t base = (size_t)g * npg;
  float m = -1e30f;
  for (int i = tid; i < npg; i += 256) m = fmaxf(m, alog[base + i]);
  red[tid] = m; __syncthreads();
  for (int off = 128; off > 0; off >>= 1){ if (tid < off) red[tid] = fmaxf(red[tid], red[tid + off]); __syncthreads(); }
  float gmax = red[0]; __syncthreads();
  float z = 0.f;
  for (int i = tid; i < npg; i += 256) z += __expf(alog[base + i] - gmax);
  red[tid] = z; __syncthreads();
  for (int off = 128; off > 0; off >>= 1){ if (tid < off) red[tid] += red[tid + off]; __syncthreads(); }
  if (tid == 0){ gm[g] = gmax; gz[g] = red[0]; }
}

// partial pooling: grid = NG * nparts; each block pools a chunk (<=128 nodes) of one graph
__global__ void pool_partial_kernel(const float* __restrict__ xx, const float* __restrict__ alog,
                                    const float* __restrict__ gm, const float* __restrict__ gz,
                                    float* __restrict__ part, int npg, int nparts){
  __shared__ float wts[128];
  __shared__ float red[256];
  int g = blockIdx.x / nparts, p = blockIdx.x % nparts;
  int chunk = (npg + nparts - 1) / nparts;
  int n0 = p * chunk, n1 = min(npg, n0 + chunk);
  int tid = threadIdx.x;
  float gmax = gm[g], ginv = 1.0f / gz[g];
  size_t base = (size_t)g * npg;
  for (int i = n0 + tid; i < n1; i += 256) wts[i - n0] = __expf(alog[base + i] - gmax) * ginv;
  __syncthreads();
  int f = tid & 127, half = tid >> 7;
  float add = 0.f, mx = -1e30f, att = 0.f;
  for (int n2 = n0 + half; n2 < n1; n2 += 2){
    float v = xx[(base + n2) * 128 + f];
    add += v; mx = fmaxf(mx, v); att += v * wts[n2 - n0];
  }
  red[tid] = add; __syncthreads();
  float addf = add + ((half == 0) ? red[tid + 128] : 0.f);
  __syncthreads(); red[tid] = mx; __syncthreads();
  float mxf = (half == 0) ? fmaxf(mx, red[tid + 128]) : 0.f;
  __syncthreads(); red[tid] = att; __syncthreads();
  float attf = att + ((half == 0) ? red[tid + 128] : 0.f);
  if (half == 0){
    float* o = part + (size_t)(g * nparts + p) * 384;
    o[f] = addf; o[128 + f] = mxf; o[256 + f] = attf;
  }
}

__global__ void pool_final_kernel(const float* __restrict__ part, float* __restrict__ hg,
                                  int npg, int nparts){
  int g = blockIdx.x, f = threadIdx.x;   // 128 threads
  float add = 0.f, mx = -1e30f, att = 0.f;
  for (int p = 0; p < nparts; ++p){
    const float* o = part + (size_t)(g * nparts + p) * 384;
    add += o[f]; mx = fmaxf(mx, o[128 + f]); att += o[256 + f];
  }
  float* o = hg + (size_t)g * 512;
  o[f] = add / (float)npg;    // mean
  o[128 + f] = mx;            // max
  o[256 + f] = add;           // add
  o[384 + f] = att;           // att (already normalized)
}

__global__ void head_kernel(const float* __restrict__ hg, const float* __restrict__ combW,
                            const float* __restrict__ combB, const float* __restrict__ c1W,
                            const float* __restrict__ c1B, const float* __restrict__ c2W,
                            const float* __restrict__ c2B, float* __restrict__ out){
  __shared__ float cat[512];
  __shared__ float h1[128];
  __shared__ float h2[64];
  int g = blockIdx.x, tid = threadIdx.x;   // block 128
#pragma unroll
  for (int j = 0; j < 4; ++j) cat[tid + 128 * j] = hg[(size_t)g * 512 + tid + 128 * j];
  __syncthreads();
  float a = combB[tid];
  for (int k = 0; k < 512; ++k) a += cat[k] * combW[(size_t)k * 128 + tid];
  h1[tid] = a; __syncthreads();
  if (tid < 64){
    float b = c1B[tid];
    for (int k = 0; k < 128; ++k) b += h1[k] * c1W[(size_t)k * 64 + tid];
    h2[tid] = fmaxf(b, 0.f);
  }
  __syncthreads();
  if (tid < 2){
    float o = c2B[tid];
    for (int k = 0; k < 64; ++k) o += h2[k] * c2W[(size_t)k * 2 + tid];
    out[(size_t)g * 2 + tid] = o;
  }
}

// ---------------- host ----------------

static void launch_gemm(int epi, dim3 grid, hipStream_t st,
                        const float* A0, const float* A1, const float* A2,
                        const unsigned short* W0, const unsigned short* W1, const unsigned short* W2,
                        const float* bias, const float* bng, const float* bnb,
                        const float* resid, float* C, int nrows){
  switch (epi){
    case 0: gemm_kernel<0><<<grid, 256, 0, st>>>(A0, A1, A2, W0, W1, W2, bias, bng, bnb, resid, C, nrows); break;
    case 1: gemm_kernel<1><<<grid, 256, 0, st>>>(A0, A1, A2, W0, W1, W2, bias, bng, bnb, resid, C, nrows); break;
    case 2: gemm_kernel<2><<<grid, 256, 0, st>>>(A0, A1, A2, W0, W1, W2, bias, bng, bnb, resid, C, nrows); break;
    default: gemm_kernel<3><<<grid, 256, 0, st>>>(A0, A1, A2, W0, W1, W2, bias, bng, bnb, resid, C, nrows); break;
  }
}

extern "C" void kernel_launch(void* const* d_in, const int* in_sizes, int n_in,
                              void* d_out, int out_size, void* d_ws, size_t ws_size,
                              hipStream_t stream){
  (void)n_in; (void)out_size; (void)ws_size;
  const int N = in_sizes[0] / 128;
  const int E = in_sizes[1] / 2;
  const int NG = 50;
  const int npg = N / NG;

  const float* x       = (const float*)d_in[0];
  const int*   ei      = (const int*)d_in[1];
  const int*   srcI    = ei;
  const int*   dstI    = ei + E;
  const float* W_gcn   = (const float*)d_in[3];
  const float* b_gcn   = (const float*)d_in[4];
  const float* gin_W1  = (const float*)d_in[5];
  const float* gin_b1  = (const float*)d_in[6];
  const float* gin_W2  = (const float*)d_in[7];
  const float* gin_b2  = (const float*)d_in[8];
  const float* W_gat   = (const float*)d_in[9];
  const float* b_gat   = (const float*)d_in[10];
  const float* a_src   = (const float*)d_in[11];
  const float* a_dst   = (const float*)d_in[12];
  const float* gproj_W = (const float*)d_in[13];
  const float* gproj_b = (const float*)d_in[14];
  const float* gate_W1 = (const float*)d_in[15];
  const float* gate_b1 = (const float*)d_in[16];
  const float* gate_W2 = (const float*)d_in[17];
  const float* gate_b2 = (const float*)d_in[18];
  const float* bn0_g   = (const float*)d_in[19];
  const float* bn0_b   = (const float*)d_in[20];
  const float* rel_W   = (const float*)d_in[21];
  const float* rel_b   = (const float*)d_in[22];
  const float* root_W  = (const float*)d_in[23];
  const float* bn_g    = (const float*)d_in[24];
  const float* bn_b    = (const float*)d_in[25];
  const float* jump_W  = (const float*)d_in[26];
  const float* jump_b  = (const float*)d_in[27];
  const float* att_W1  = (const float*)d_in[28];
  const float* att_b1  = (const float*)d_in[29];
  const float* att_W2  = (const float*)d_in[30];
  const float* att_b2  = (const float*)d_in[31];
  const float* comb_W  = (const float*)d_in[32];
  const float* comb_b  = (const float*)d_in[33];
  const float* cls_W1  = (const float*)d_in[34];
  const float* cls_b1  = (const float*)d_in[35];
  const float* cls_W2  = (const float*)d_in[36];
  const float* cls_b2  = (const float*)d_in[37];
  float* out = (float*)d_out;

  char* wp = (char*)d_ws;
  auto alloc = [&](size_t b) -> char* {
    char* p = wp; wp += (b + 511) & ~(size_t)511; return p;
  };
  unsigned int* cnt  = (unsigned int*)alloc((size_t)N * 4);
  unsigned int* fill = (unsigned int*)alloc((size_t)N * 4);
  unsigned int* rp   = (unsigned int*)alloc(((size_t)N + 1) * 4);
  int* colA          = (int*)alloc((size_t)E * 4);
  unsigned int* bsum = (unsigned int*)alloc(256 * 4);
  float* dinv        = (float*)alloc((size_t)N * 4);
  float* als         = (float*)alloc((size_t)N * 16);
  float* ald         = (float*)alloc((size_t)N * 16);
  float* alogv       = (float*)alloc((size_t)N * 4);
  unsigned short* WtAll = (unsigned short*)alloc((size_t)18 * 16384 * 2);
  float* hg          = (float*)alloc((size_t)NG * 512 * 4);
  float* gmv         = (float*)alloc((size_t)NG * 4);
  float* gzv         = (float*)alloc((size_t)NG * 4);
  int nparts = (npg + 99) / 100;                    // chunk <= 100 <= 128
  float* part        = (float*)alloc((size_t)NG * nparts * 384 * 4);
  float* S0 = (float*)alloc((size_t)N * 128 * 4);
  float* S1 = (float*)alloc((size_t)N * 128 * 4);
  float* S2 = (float*)alloc((size_t)N * 128 * 4);
  float* S3 = (float*)alloc((size_t)N * 128 * 4);
  float* S4 = (float*)alloc((size_t)N * 128 * 4);

  // --- CSR build ---
  int zn = (int)(((char*)rp - (char*)cnt) / 4);   // cnt + fill regions (contiguous)
  zero_u32<<<(zn + 255) / 256, 256, 0, stream>>>(cnt, zn);
  hist_kernel<<<(E + 255) / 256, 256, 0, stream>>>(dstI, cnt, E);
  int nbScan = (N + 1023) / 1024;
  scan1_kernel<<<nbScan, 1024, 0, stream>>>(cnt, rp, bsum, N);
  scan2_kernel<<<1, 256, 0, stream>>>(bsum, nbScan);
  scan3_kernel<<<(N + 255) / 256, 256, 0, stream>>>(rp, bsum, N, (unsigned int)E);
  scatter_kernel<<<(E + 255) / 256, 256, 0, stream>>>(srcI, dstI, rp, fill, colA, E);
  dinv_kernel<<<(N + 255) / 256, 256, 0, stream>>>(cnt, dinv, N);

  // --- weight transpose/cast ---
  WSrc wsrc;
  wsrc.p[0] = W_gcn;  wsrc.p[1] = W_gat;  wsrc.p[2] = gin_W1; wsrc.p[3] = gin_W2;
  wsrc.p[4] = gproj_W;
  wsrc.p[5] = gate_W1;      wsrc.p[6] = gate_W1 + 16384; wsrc.p[7] = gate_W1 + 32768;
  wsrc.p[8] = rel_W;        wsrc.p[9] = rel_W + 16384;   wsrc.p[10] = rel_W + 32768;
  wsrc.p[11] = root_W;      wsrc.p[12] = root_W + 16384; wsrc.p[13] = root_W + 32768;
  wsrc.p[14] = jump_W;      wsrc.p[15] = jump_W + 16384; wsrc.p[16] = jump_W + 32768;
  wsrc.p[17] = att_W1;
  wtrans_kernel<<<dim3(18, 2), 256, 0, stream>>>(wsrc, WtAll);

  dim3 gg((N + 63) / 64);
  int nb4 = (N + 3) / 4;
  #define WT(i) (WtAll + (size_t)(i) * 16384)
  const unsigned short* Z = nullptr;
  const float* FZ = nullptr;

  // stems: hd = (x@W_gcn)*dinv, xp = x@W_gat in one pass over x
  gemm_dual_kernel<<<gg, 256, 0, stream>>>(x, WT(0), WT(1), dinv, S0, S1, N);
  alpair_kernel<<<nb4, 256, 0, stream>>>(S1, a_src, a_dst, als, ald, N);
  gin_agg_kernel<<<nb4, 256, 0, stream>>>(x, rp, colA, S2, N);                 // xs = x + aggr
  launch_gemm(2, gg, stream, S2, FZ, FZ, WT(2), Z, Z, gin_b1, FZ, FZ, FZ, S3, N); // t_gin
  launch_gemm(2, gg, stream, S3, FZ, FZ, WT(3), Z, Z, gin_b2, FZ, FZ, FZ, S2, N); // x_gin
  gcn_agg_kernel<<<nb4, 256, 0, stream>>>(S0, dinv, rp, colA, b_gcn, S3, N);   // x_gcn
  gat_agg_kernel<<<nb4, 256, 0, stream>>>(S1, als, ald, rp, colA, b_gat, S0, N); // gat_pre
  launch_gemm(1, gg, stream, S0, FZ, FZ, WT(4), Z, Z, gproj_b, FZ, FZ, FZ, S1, N); // x_gat

  // gated fusion
  launch_gemm(2, gg, stream, S3, S2, S1, WT(5), WT(6), WT(7), gate_b1, FZ, FZ, FZ, S4, N); // t_gate
  combine_kernel<<<nb4, 256, 0, stream>>>(S4, gate_W2, gate_b2, S3, S2, S1, bn0_g, bn0_b, S0, N); // xx

  // GraphConv stack
  sum_agg_kernel<<<nb4, 256, 0, stream>>>(S0, rp, colA, S1, N);
  launch_gemm(3, gg, stream, S1, S0, FZ, WT(8), WT(11), Z, rel_b, bn_g, bn_b, S0, S2, N);          // reps0
  sum_agg_kernel<<<nb4, 256, 0, stream>>>(S2, rp, colA, S1, N);
  launch_gemm(3, gg, stream, S1, S2, FZ, WT(9), WT(12), Z, rel_b + 128, bn_g + 128, bn_b + 128, S2, S3, N); // reps1
  sum_agg_kernel<<<nb4, 256, 0, stream>>>(S3, rp, colA, S1, N);
  launch_gemm(3, gg, stream, S1, S3, FZ, WT(10), WT(13), Z, rel_b + 256, bn_g + 256, bn_b + 256, S3, S4, N); // reps2

  // JK cat + attention logits
  launch_gemm(1, gg, stream, S2, S3, S4, WT(14), WT(15), WT(16), jump_b, FZ, FZ, FZ, S0, N); // xx2
  launch_gemm(2, gg, stream, S0, FZ, FZ, WT(17), Z, Z, att_b1, FZ, FZ, FZ, S1, N);           // t_att
  alog_kernel<<<nb4, 256, 0, stream>>>(S1, att_W2, att_b2, alogv, N);

  // pooling + head
  att_stats_kernel<<<NG, 256, 0, stream>>>(alogv, gmv, gzv, npg);
  pool_partial_kernel<<<NG * nparts, 256, 0, stream>>>(S0, alogv, gmv, gzv, part, npg, nparts);
  pool_final_kernel<<<NG, 128, 0, stream>>>(part, hg, npg, nparts);
  head_kernel<<<NG, 128, 0, stream>>>(hg, comb_W, comb_b, cls_W1, cls_b1, cls_W2, cls_b2, out);
}

// Round 4
// 693.056 us; speedup vs baseline: 1.7370x; 1.2434x over previous
//
#include <hip/hip_runtime.h>

typedef float f32x4 __attribute__((ext_vector_type(4)));
typedef short s16x8 __attribute__((ext_vector_type(8)));

#define LDA 136   // padded LDS row length (bf16 elems): 272B rows -> ~2-way bank aliasing (free)

static __device__ __forceinline__ unsigned short f2bf(float f){
  union { float f; unsigned int u; } v; v.f = f;
  unsigned int u = v.u;
  return (unsigned short)((u + 0x7fffu + ((u >> 16) & 1u)) >> 16);
}
static __device__ __forceinline__ float2 bfp2f(unsigned int p){   // packed 2xbf16 -> 2xf32
  union { unsigned int u; float f; } a, b;
  a.u = (p & 0xffffu) << 16; b.u = p & 0xffff0000u;
  return make_float2(a.f, b.f);
}
static __device__ __forceinline__ unsigned int f2bfp(float x, float y){
  return (unsigned int)f2bf(x) | ((unsigned int)f2bf(y) << 16);
}
static __device__ __forceinline__ float bf2f(unsigned short h){
  union { unsigned int u; float f; } v; v.u = (unsigned int)h << 16; return v.f;
}

static __device__ __forceinline__ float lrelu02(float x){ return x > 0.f ? x : 0.2f * x; }

// bijective XCD swizzle (m204)
static __device__ __forceinline__ int xcd_swz(int bid, int nwg){
  int q = nwg >> 3, r = nwg & 7, x = bid & 7, i = bid >> 3;
  return (x < r ? x * (q + 1) : r * (q + 1) + (x - r) * q) + i;
}

// ---------------- CSR build ----------------

__global__ void zero_u32(unsigned int* p, int n){
  int i = blockIdx.x * 256 + threadIdx.x;
  if (i < n) p[i] = 0u;
}

__global__ void hist_kernel(const int* __restrict__ dst, unsigned int* __restrict__ cnt, int E){
  int i = blockIdx.x * 256 + threadIdx.x;
  if (i < E) atomicAdd(&cnt[dst[i]], 1u);
}

__global__ void scan1_kernel(const unsigned int* __restrict__ cnt, unsigned int* __restrict__ rp,
                             unsigned int* __restrict__ bsum, int n){
  __shared__ unsigned int s[1024];
  int b = blockIdx.x, tid = threadIdx.x, i = b * 1024 + tid;
  unsigned int v = (i < n) ? cnt[i] : 0u;
  s[tid] = v; __syncthreads();
  for (int off = 1; off < 1024; off <<= 1){
    unsigned int t = (tid >= off) ? s[tid - off] : 0u;
    __syncthreads();
    s[tid] += t;
    __syncthreads();
  }
  if (i < n) rp[i] = s[tid] - v;     // exclusive within block
  if (tid == 1023) bsum[b] = s[1023];
}

__global__ void scan2_kernel(unsigned int* __restrict__ bsum, int nb){
  __shared__ unsigned int s[256];
  int tid = threadIdx.x;
  unsigned int v = (tid < nb) ? bsum[tid] : 0u;
  s[tid] = v; __syncthreads();
  for (int off = 1; off < 256; off <<= 1){
    unsigned int t = (tid >= off) ? s[tid - off] : 0u;
    __syncthreads();
    s[tid] += t;
    __syncthreads();
  }
  if (tid < nb) bsum[tid] = s[tid] - v;  // exclusive block offsets
}

__global__ void scan3_kernel(unsigned int* __restrict__ rp, const unsigned int* __restrict__ bsum,
                             int n, unsigned int Etot){
  int i = blockIdx.x * 256 + threadIdx.x;
  if (i < n) rp[i] += bsum[i >> 10];
  if (i == 0) rp[n] = Etot;
}

__global__ void scatter_kernel(const int* __restrict__ src, const int* __restrict__ dst,
                               const unsigned int* __restrict__ rp, unsigned int* __restrict__ fill,
                               int* __restrict__ colA, int* __restrict__ cpos, int E){
  int i = blockIdx.x * 256 + threadIdx.x;
  if (i < E){
    int d = dst[i];
    unsigned int pos = rp[d] + atomicAdd(&fill[d], 1u);
    colA[pos] = src[i];
    cpos[i] = (int)pos;
  }
}

__global__ void dinv_kernel(const unsigned int* __restrict__ cnt, float* __restrict__ dinv, int n){
  int i = blockIdx.x * 256 + threadIdx.x;
  if (i < n) dinv[i] = rsqrtf((float)cnt[i] + 1.0f);
}

// x f32 -> bf16 (one shot)
__global__ void xcast_kernel(const float* __restrict__ x, unsigned short* __restrict__ xb, int n2){
  int i = blockIdx.x * 256 + threadIdx.x;
  if (i < n2){
    float2 v = ((const float2*)x)[i];
    ((unsigned int*)xb)[i] = f2bfp(v.x, v.y);
  }
}

// GAT edge weights in CSR order: wCSR[pos][h] = exp(min(lrelu(als[src][h]+ald[dst][h]),30))
__global__ void ew_kernel(const int* __restrict__ src, const int* __restrict__ dst,
                          const int* __restrict__ cpos, const float* __restrict__ als,
                          const float* __restrict__ ald, float* __restrict__ wCSR, int E){
  int i = blockIdx.x * 256 + threadIdx.x;
  if (i >= E) return;
  int s = src[i], d = dst[i];
  float4 as = ((const float4*)als)[s];
  float4 ad = ((const float4*)ald)[d];
  float4 w;
  w.x = __expf(fminf(lrelu02(as.x + ad.x), 30.f));
  w.y = __expf(fminf(lrelu02(as.y + ad.y), 30.f));
  w.z = __expf(fminf(lrelu02(as.z + ad.z), 30.f));
  w.w = __expf(fminf(lrelu02(as.w + ad.w), 30.f));
  ((float4*)wCSR)[cpos[i]] = w;
}

// ---------------- weight transpose (f32 [128,128] row-major -> bf16 [col][k]) ----------------

struct WSrc { const float* p[18]; };

__global__ void wtrans_kernel(WSrc s, unsigned short* __restrict__ dstAll){
  const float* src = s.p[blockIdx.x];
  unsigned short* dst = dstAll + (size_t)blockIdx.x * 16384;
  __shared__ float st[64][129];
  int tid = threadIdx.x;
  int kb = blockIdx.y * 64;
#pragma unroll
  for (int j = 0; j < 8; ++j){
    int e = tid + 256 * j;          // 0..2047
    int r = e >> 5, c4 = (e & 31) * 4;
    float4 v = *(const float4*)(src + (size_t)(kb + r) * 128 + c4);
    st[r][c4] = v.x; st[r][c4+1] = v.y; st[r][c4+2] = v.z; st[r][c4+3] = v.w;
  }
  __syncthreads();
#pragma unroll
  for (int j = 0; j < 8; ++j){
    int e = tid + 256 * j;          // 0..2047
    int c = e >> 4, k4 = (e & 15) * 4;
    ushort4 o;
    o.x = f2bf(st[k4+0][c]); o.y = f2bf(st[k4+1][c]);
    o.z = f2bf(st[k4+2][c]); o.w = f2bf(st[k4+3][c]);
    *(ushort4*)(dst + (size_t)c * 128 + kb + k4) = o;
  }
}

// ---------------- MFMA GEMM: C[nrows,128] = sum_p A_p[nrows,128] @ W_p[128,128] (+epilogue) ----------------
// A_p bf16 row-major; W_p pre-transposed bf16 Wt[col][k]; C bf16.
// EPI: 0 none, 1 +bias, 2 relu(+bias), 3 conv: relu((acc+bias)*bn_g*RSQ + bn_b) + resid

template<int EPI>
__launch_bounds__(256, 2)
__global__ void gemm_kernel(const unsigned short* __restrict__ A0, const unsigned short* __restrict__ A1,
                            const unsigned short* __restrict__ A2,
                            const unsigned short* __restrict__ W0, const unsigned short* __restrict__ W1,
                            const unsigned short* __restrict__ W2,
                            const float* __restrict__ bias, const float* __restrict__ bng, const float* __restrict__ bnb,
                            const unsigned short* __restrict__ resid, unsigned short* __restrict__ C, int nrows)
{
  __shared__ unsigned short As[64 * LDA];
  __shared__ unsigned short Wt[128 * LDA];
  const int tid = threadIdx.x;
  const int wave = tid >> 6, lane = tid & 63;
  const int row0 = blockIdx.x * 64;
  const unsigned short* Aps[3] = {A0, A1, A2};
  const unsigned short* Wps[3] = {W0, W1, W2};
  f32x4 acc[8];
#pragma unroll
  for (int i = 0; i < 8; ++i) acc[i] = (f32x4){0.f, 0.f, 0.f, 0.f};

  for (int p = 0; p < 3; ++p){
    const unsigned short* Ap = Aps[p];
    if (Ap == nullptr) break;
    const unsigned short* Wp = Wps[p];
    if (p) __syncthreads();            // LDS reuse guard
    // stage A tile (bf16 direct, 16B per lane per iter)
#pragma unroll
    for (int j = 0; j < 4; ++j){
      int e = tid + 256 * j;           // 0..1023 (64 rows x 16 chunks of 8 bf16)
      int r = e >> 4, k8 = (e & 15) * 8;
      int gr = row0 + r;
      s16x8 v = {0,0,0,0,0,0,0,0};
      if (gr < nrows) v = *(const s16x8*)(Ap + (size_t)gr * 128 + k8);
      *(s16x8*)(As + r * LDA + k8) = v;
    }
    // stage Wt tile
#pragma unroll
    for (int j = 0; j < 8; ++j){
      int e = tid + 256 * j;           // 0..2047 (128 cols x 16 chunks of 8)
      int colw = e >> 4, k8 = (e & 15) * 8;
      *(s16x8*)(Wt + colw * LDA + k8) = *(const s16x8*)(Wp + (size_t)colw * 128 + k8);
    }
    __syncthreads();
#pragma unroll
    for (int kc = 0; kc < 4; ++kc){
      int ko = kc * 32 + (lane >> 4) * 8;
      s16x8 av = *(const s16x8*)(As + (wave * 16 + (lane & 15)) * LDA + ko);
#pragma unroll
      for (int ct = 0; ct < 8; ++ct){
        s16x8 bv = *(const s16x8*)(Wt + (ct * 16 + (lane & 15)) * LDA + ko);
        acc[ct] = __builtin_amdgcn_mfma_f32_16x16x32_bf16(av, bv, acc[ct], 0, 0, 0);
      }
    }
  }
  const float RSQ = 0.99999500003749969f; // rsqrt(1 + 1e-5)
#pragma unroll
  for (int ct = 0; ct < 8; ++ct){
    int colg = ct * 16 + (lane & 15);
    float bv_ = (EPI >= 1) ? bias[colg] : 0.f;
    float sg = (EPI == 3) ? bng[colg] * RSQ : 0.f;
    float sb = (EPI == 3) ? bnb[colg] : 0.f;
#pragma unroll
    for (int r = 0; r < 4; ++r){
      int rowg = row0 + wave * 16 + (lane >> 4) * 4 + r;
      if (rowg < nrows){
        float v = acc[ct][r];
        if (EPI == 1) v += bv_;
        else if (EPI == 2) v = fmaxf(v + bv_, 0.f);
        else if (EPI == 3){
          v = (v + bv_) * sg + sb;
          v = fmaxf(v, 0.f) + bf2f(resid[(size_t)rowg * 128 + colg]);
        }
        C[(size_t)rowg * 128 + colg] = f2bf(v);
      }
    }
  }
}

// Dual-output GEMM sharing A(bf16): C0 = (A@W0)*dscale[row], C1 = A@W1 (both bf16 out).
__launch_bounds__(256, 2)
__global__ void gemm_dual_kernel(const unsigned short* __restrict__ A,
                                 const unsigned short* __restrict__ W0, const unsigned short* __restrict__ W1,
                                 const float* __restrict__ dscale,
                                 unsigned short* __restrict__ C0, unsigned short* __restrict__ C1, int nrows)
{
  __shared__ unsigned short As[64 * LDA];
  __shared__ unsigned short Wt[128 * LDA];
  const int tid = threadIdx.x;
  const int wave = tid >> 6, lane = tid & 63;
  const int row0 = blockIdx.x * 64;
  f32x4 acc0[8], acc1[8];
#pragma unroll
  for (int i = 0; i < 8; ++i){ acc0[i] = (f32x4){0.f,0.f,0.f,0.f}; acc1[i] = (f32x4){0.f,0.f,0.f,0.f}; }

#pragma unroll
  for (int j = 0; j < 4; ++j){
    int e = tid + 256 * j;
    int r = e >> 4, k8 = (e & 15) * 8;
    int gr = row0 + r;
    s16x8 v = {0,0,0,0,0,0,0,0};
    if (gr < nrows) v = *(const s16x8*)(A + (size_t)gr * 128 + k8);
    *(s16x8*)(As + r * LDA + k8) = v;
  }
#pragma unroll
  for (int j = 0; j < 8; ++j){
    int e = tid + 256 * j;
    int colw = e >> 4, k8 = (e & 15) * 8;
    *(s16x8*)(Wt + colw * LDA + k8) = *(const s16x8*)(W0 + (size_t)colw * 128 + k8);
  }
  __syncthreads();
  s16x8 av[4];
#pragma unroll
  for (int kc = 0; kc < 4; ++kc)
    av[kc] = *(const s16x8*)(As + (wave * 16 + (lane & 15)) * LDA + kc * 32 + (lane >> 4) * 8);
#pragma unroll
  for (int kc = 0; kc < 4; ++kc){
    int ko = kc * 32 + (lane >> 4) * 8;
#pragma unroll
    for (int ct = 0; ct < 8; ++ct){
      s16x8 bv = *(const s16x8*)(Wt + (ct * 16 + (lane & 15)) * LDA + ko);
      acc0[ct] = __builtin_amdgcn_mfma_f32_16x16x32_bf16(av[kc], bv, acc0[ct], 0, 0, 0);
    }
  }
  __syncthreads();
#pragma unroll
  for (int j = 0; j < 8; ++j){
    int e = tid + 256 * j;
    int colw = e >> 4, k8 = (e & 15) * 8;
    *(s16x8*)(Wt + colw * LDA + k8) = *(const s16x8*)(W1 + (size_t)colw * 128 + k8);
  }
  __syncthreads();
#pragma unroll
  for (int kc = 0; kc < 4; ++kc){
    int ko = kc * 32 + (lane >> 4) * 8;
#pragma unroll
    for (int ct = 0; ct < 8; ++ct){
      s16x8 bv = *(const s16x8*)(Wt + (ct * 16 + (lane & 15)) * LDA + ko);
      acc1[ct] = __builtin_amdgcn_mfma_f32_16x16x32_bf16(av[kc], bv, acc1[ct], 0, 0, 0);
    }
  }
#pragma unroll
  for (int ct = 0; ct < 8; ++ct){
    int colg = ct * 16 + (lane & 15);
#pragma unroll
    for (int r = 0; r < 4; ++r){
      int rowg = row0 + wave * 16 + (lane >> 4) * 4 + r;
      if (rowg < nrows){
        C0[(size_t)rowg * 128 + colg] = f2bf(acc0[ct][r] * dscale[rowg]);
        C1[(size_t)rowg * 128 + colg] = f2bf(acc1[ct][r]);
      }
    }
  }
}

// ---------------- aggregation kernels (wave per node, bf16x2 per lane, 4x unrolled) ----------------

__global__ void gin_agg_kernel(const unsigned short* __restrict__ x, const unsigned int* __restrict__ rp,
                               const int* __restrict__ col, unsigned short* __restrict__ xs, int n){
  int bid = xcd_swz(blockIdx.x, gridDim.x);
  int node = bid * 4 + (int)(threadIdx.x >> 6);
  if (node >= n) return;
  int lane = threadIdx.x & 63;
  const unsigned int* xin = (const unsigned int*)x;
  float2 acc = bfp2f(xin[(size_t)node * 64 + lane]);   // (1+0)*x self term
  unsigned int rs = rp[node], re = rp[node + 1], e = rs;
  for (; e + 4 <= re; e += 4){
    int s0 = col[e], s1 = col[e+1], s2 = col[e+2], s3 = col[e+3];
    float2 v0 = bfp2f(xin[(size_t)s0 * 64 + lane]);
    float2 v1 = bfp2f(xin[(size_t)s1 * 64 + lane]);
    float2 v2 = bfp2f(xin[(size_t)s2 * 64 + lane]);
    float2 v3 = bfp2f(xin[(size_t)s3 * 64 + lane]);
    acc.x += v0.x + v1.x + v2.x + v3.x;
    acc.y += v0.y + v1.y + v2.y + v3.y;
  }
  for (; e < re; ++e){
    float2 v = bfp2f(xin[(size_t)col[e] * 64 + lane]);
    acc.x += v.x; acc.y += v.y;
  }
  ((unsigned int*)xs)[(size_t)node * 64 + lane] = f2bfp(acc.x, acc.y);
}

// GCN aggregation over pre-scaled hd = (x@W_gcn)*dinv: out = relu(di*(hd[d] + sum_s hd[s]) + b)
__global__ void gcn_agg_kernel(const unsigned short* __restrict__ hd, const float* __restrict__ dinv,
                               const unsigned int* __restrict__ rp, const int* __restrict__ col,
                               const float* __restrict__ b, unsigned short* __restrict__ out, int n){
  int bid = xcd_swz(blockIdx.x, gridDim.x);
  int node = bid * 4 + (int)(threadIdx.x >> 6);
  if (node >= n) return;
  int lane = threadIdx.x & 63;
  const unsigned int* hv = (const unsigned int*)hd;
  float di = dinv[node];
  float2 acc = bfp2f(hv[(size_t)node * 64 + lane]);    // self: hd[d]
  unsigned int rs = rp[node], re = rp[node + 1], e = rs;
  for (; e + 4 <= re; e += 4){
    int s0 = col[e], s1 = col[e+1], s2 = col[e+2], s3 = col[e+3];
    float2 v0 = bfp2f(hv[(size_t)s0 * 64 + lane]);
    float2 v1 = bfp2f(hv[(size_t)s1 * 64 + lane]);
    float2 v2 = bfp2f(hv[(size_t)s2 * 64 + lane]);
    float2 v3 = bfp2f(hv[(size_t)s3 * 64 + lane]);
    acc.x += v0.x + v1.x + v2.x + v3.x;
    acc.y += v0.y + v1.y + v2.y + v3.y;
  }
  for (; e < re; ++e){
    float2 v = bfp2f(hv[(size_t)col[e] * 64 + lane]);
    acc.x += v.x; acc.y += v.y;
  }
  int f = lane * 2;
  float o0 = fmaxf(acc.x * di + b[f], 0.f);
  float o1 = fmaxf(acc.y * di + b[f + 1], 0.f);
  ((unsigned int*)out)[(size_t)node * 64 + lane] = f2bfp(o0, o1);
}

__global__ void sum_agg_kernel(const unsigned short* __restrict__ x, const unsigned int* __restrict__ rp,
                               const int* __restrict__ col, unsigned short* __restrict__ out, int n){
  int bid = xcd_swz(blockIdx.x, gridDim.x);
  int node = bid * 4 + (int)(threadIdx.x >> 6);
  if (node >= n) return;
  int lane = threadIdx.x & 63;
  const unsigned int* xin = (const unsigned int*)x;
  float2 acc = make_float2(0.f, 0.f);
  unsigned int rs = rp[node], re = rp[node + 1], e = rs;
  for (; e + 4 <= re; e += 4){
    int s0 = col[e], s1 = col[e+1], s2 = col[e+2], s3 = col[e+3];
    float2 v0 = bfp2f(xin[(size_t)s0 * 64 + lane]);
    float2 v1 = bfp2f(xin[(size_t)s1 * 64 + lane]);
    float2 v2 = bfp2f(xin[(size_t)s2 * 64 + lane]);
    float2 v3 = bfp2f(xin[(size_t)s3 * 64 + lane]);
    acc.x += v0.x + v1.x + v2.x + v3.x;
    acc.y += v0.y + v1.y + v2.y + v3.y;
  }
  for (; e < re; ++e){
    float2 v = bfp2f(xin[(size_t)col[e] * 64 + lane]);
    acc.x += v.x; acc.y += v.y;
  }
  ((unsigned int*)out)[(size_t)node * 64 + lane] = f2bfp(acc.x, acc.y);
}

// GAT aggregation with precomputed CSR-order edge weights (wCSR[pos][h]).
__global__ void gat_agg_kernel(const unsigned short* __restrict__ xp, const float* __restrict__ als,
                               const float* __restrict__ ald, const float* __restrict__ wCSR,
                               const unsigned int* __restrict__ rp, const int* __restrict__ col,
                               const float* __restrict__ bgat, unsigned short* __restrict__ out, int n){
  int bid = xcd_swz(blockIdx.x, gridDim.x);
  int node = bid * 4 + (int)(threadIdx.x >> 6);
  if (node >= n) return;
  int lane = threadIdx.x & 63;
  int h = lane >> 4;
  const unsigned int* xv = (const unsigned int*)xp;
  // self term
  float w = __expf(fminf(lrelu02(als[(size_t)node * 4 + h] + ald[(size_t)node * 4 + h]), 30.f));
  float2 sv = bfp2f(xv[(size_t)node * 64 + lane]);
  float2 acc = make_float2(sv.x * w, sv.y * w);
  float denom = w;
  unsigned int rs = rp[node], re = rp[node + 1], e = rs;
  for (; e + 4 <= re; e += 4){
    int s0 = col[e], s1 = col[e+1], s2 = col[e+2], s3 = col[e+3];
    float w0 = wCSR[(size_t)(e+0) * 4 + h];
    float w1 = wCSR[(size_t)(e+1) * 4 + h];
    float w2 = wCSR[(size_t)(e+2) * 4 + h];
    float w3 = wCSR[(size_t)(e+3) * 4 + h];
    float2 v0 = bfp2f(xv[(size_t)s0 * 64 + lane]);
    float2 v1 = bfp2f(xv[(size_t)s1 * 64 + lane]);
    float2 v2 = bfp2f(xv[(size_t)s2 * 64 + lane]);
    float2 v3 = bfp2f(xv[(size_t)s3 * 64 + lane]);
    acc.x += v0.x * w0 + v1.x * w1 + v2.x * w2 + v3.x * w3;
    acc.y += v0.y * w0 + v1.y * w1 + v2.y * w2 + v3.y * w3;
    denom += w0 + w1 + w2 + w3;
  }
  for (; e < re; ++e){
    float we = wCSR[(size_t)e * 4 + h];
    float2 v = bfp2f(xv[(size_t)col[e] * 64 + lane]);
    acc.x += v.x * we; acc.y += v.y * we;
    denom += we;
  }
  float inv = 1.0f / denom;
  int f = lane * 2;
  float o0 = fmaxf(acc.x * inv + bgat[f], 0.f);
  float o1 = fmaxf(acc.y * inv + bgat[f + 1], 0.f);
  ((unsigned int*)out)[(size_t)node * 64 + lane] = f2bfp(o0, o1);
}

// ---------------- small per-node kernels ----------------

__global__ void alpair_kernel(const unsigned short* __restrict__ xp, const float* __restrict__ a_src,
                              const float* __restrict__ a_dst, float* __restrict__ als,
                              float* __restrict__ ald, int n){
  int node = blockIdx.x * 4 + (int)(threadIdx.x >> 6);
  if (node >= n) return;
  int lane = threadIdx.x & 63;
  int f = lane * 2;
  float2 v = bfp2f(((const unsigned int*)xp)[(size_t)node * 64 + lane]);
  float ps = v.x * a_src[f] + v.y * a_src[f + 1];
  float pd = v.x * a_dst[f] + v.y * a_dst[f + 1];
#pragma unroll
  for (int off = 1; off < 16; off <<= 1){
    ps += __shfl_xor(ps, off, 64);
    pd += __shfl_xor(pd, off, 64);
  }
  if ((lane & 15) == 0){
    int hh = lane >> 4;
    als[(size_t)node * 4 + hh] = ps;
    ald[(size_t)node * 4 + hh] = pd;
  }
}

__global__ void combine_kernel(const unsigned short* __restrict__ t, const float* __restrict__ W2,
                               const float* __restrict__ b2, const unsigned short* __restrict__ xg,
                               const unsigned short* __restrict__ xi, const unsigned short* __restrict__ xa,
                               const float* __restrict__ bn0g, const float* __restrict__ bn0b,
                               unsigned short* __restrict__ xx, int n){
  int node = blockIdx.x * 4 + (int)(threadIdx.x >> 6);
  if (node >= n) return;
  int lane = threadIdx.x & 63;
  int f = lane * 2;
  float2 tv = bfp2f(((const unsigned int*)t)[(size_t)node * 64 + lane]);
  float p0 = tv.x * W2[f * 3 + 0] + tv.y * W2[(f + 1) * 3 + 0];
  float p1 = tv.x * W2[f * 3 + 1] + tv.y * W2[(f + 1) * 3 + 1];
  float p2 = tv.x * W2[f * 3 + 2] + tv.y * W2[(f + 1) * 3 + 2];
#pragma unroll
  for (int off = 1; off < 64; off <<= 1){
    p0 += __shfl_xor(p0, off, 64);
    p1 += __shfl_xor(p1, off, 64);
    p2 += __shfl_xor(p2, off, 64);
  }
  p0 += b2[0]; p1 += b2[1]; p2 += b2[2];
  float mm = fmaxf(p0, fmaxf(p1, p2));
  float e0 = __expf(p0 - mm), e1 = __expf(p1 - mm), e2 = __expf(p2 - mm);
  float inv = 1.0f / (e0 + e1 + e2);
  e0 *= inv; e1 *= inv; e2 *= inv;
  float2 a = bfp2f(((const unsigned int*)xg)[(size_t)node * 64 + lane]);
  float2 b = bfp2f(((const unsigned int*)xi)[(size_t)node * 64 + lane]);
  float2 c = bfp2f(((const unsigned int*)xa)[(size_t)node * 64 + lane]);
  const float RSQ = 0.99999500003749969f;
  float o0 = fmaxf((e0 * a.x + e1 * b.x + e2 * c.x) * (bn0g[f] * RSQ) + bn0b[f], 0.f);
  float o1 = fmaxf((e0 * a.y + e1 * b.y + e2 * c.y) * (bn0g[f + 1] * RSQ) + bn0b[f + 1], 0.f);
  ((unsigned int*)xx)[(size_t)node * 64 + lane] = f2bfp(o0, o1);
}

__global__ void alog_kernel(const unsigned short* __restrict__ t, const float* __restrict__ w,
                            const float* __restrict__ b, float* __restrict__ alog, int n){
  int node = blockIdx.x * 4 + (int)(threadIdx.x >> 6);
  if (node >= n) return;
  int lane = threadIdx.x & 63;
  int f = lane * 2;
  float2 tv = bfp2f(((const unsigned int*)t)[(size_t)node * 64 + lane]);
  float p = tv.x * w[f] + tv.y * w[f + 1];
#pragma unroll
  for (int off = 1; off < 64; off <<= 1) p += __shfl_xor(p, off, 64);
  if (lane == 0) alog[node] = p + b[0];
}

// ---------------- pooling + head ----------------

__global__ void att_stats_kernel(const float* __restrict__ alog, float* __restrict__ gm,
                                 float* __restrict__ gz, int npg){
  __shared__ float red[256];
  int g = blockIdx.x, tid = threadIdx.x;
  size_t base = (size_t)g * npg;
  float m = -1e30f;
  for (int i = tid; i < npg; i += 256) m = fmaxf(m, alog[base + i]);
  red[tid] = m; __syncthreads();
  for (int off = 128; off > 0; off >>= 1){ if (tid < off) red[tid] = fmaxf(red[tid], red[tid + off]); __syncthreads(); }
  float gmax = red[0]; __syncthreads();
  float z = 0.f;
  for (int i = tid; i < npg; i += 256) z += __expf(alog[base + i] - gmax);
  red[tid] = z; __syncthreads();
  for (int off = 128; off > 0; off >>= 1){ if (tid < off) red[tid] += red[tid + off]; __syncthreads(); }
  if (tid == 0){ gm[g] = gmax; gz[g] = red[0]; }
}

__global__ void pool_partial_kernel(const unsigned short* __restrict__ xx, const float* __restrict__ alog,
                                    const float* __restrict__ gm, const float* __restrict__ gz,
                                    float* __restrict__ part, int npg, int nparts){
  __shared__ float wts[128];
  __shared__ float red[256];
  int g = blockIdx.x / nparts, p = blockIdx.x % nparts;
  int chunk = (npg + nparts - 1) / nparts;
  int n0 = p * chunk, n1 = min(npg, n0 + chunk);
  int tid = threadIdx.x;
  float gmax = gm[g], ginv = 1.0f / gz[g];
  size_t base = (size_t)g * npg;
  for (int i = n0 + tid; i < n1; i += 256) wts[i - n0] = __expf(alog[base + i] - gmax) * ginv;
  __syncthreads();
  int f = tid & 127, half = tid >> 7;
  float add = 0.f, mx = -1e30f, att = 0.f;
  for (int n2 = n0 + half; n2 < n1; n2 += 2){
    float v = bf2f(xx[(base + n2) * 128 + f]);
    add += v; mx = fmaxf(mx, v); att += v * wts[n2 - n0];
  }
  red[tid] = add; __syncthreads();
  float addf = add + ((half == 0) ? red[tid + 128] : 0.f);
  __syncthreads(); red[tid] = mx; __syncthreads();
  float mxf = (half == 0) ? fmaxf(mx, red[tid + 128]) : 0.f;
  __syncthreads(); red[tid] = att; __syncthreads();
  float attf = att + ((half == 0) ? red[tid + 128] : 0.f);
  if (half == 0){
    float* o = part + (size_t)(g * nparts + p) * 384;
    o[f] = addf; o[128 + f] = mxf; o[256 + f] = attf;
  }
}

__global__ void pool_final_kernel(const float* __restrict__ part, float* __restrict__ hg,
                                  int npg, int nparts){
  int g = blockIdx.x, f = threadIdx.x;   // 128 threads
  float add = 0.f, mx = -1e30f, att = 0.f;
  for (int p = 0; p < nparts; ++p){
    const float* o = part + (size_t)(g * nparts + p) * 384;
    add += o[f]; mx = fmaxf(mx, o[128 + f]); att += o[256 + f];
  }
  float* o = hg + (size_t)g * 512;
  o[f] = add / (float)npg;    // mean
  o[128 + f] = mx;            // max
  o[256 + f] = add;           // add
  o[384 + f] = att;           // att (already normalized)
}

__global__ void head_kernel(const float* __restrict__ hg, const float* __restrict__ combW,
                            const float* __restrict__ combB, const float* __restrict__ c1W,
                            const float* __restrict__ c1B, const float* __restrict__ c2W,
                            const float* __restrict__ c2B, float* __restrict__ out){
  __shared__ float cat[512];
  __shared__ float h1[128];
  __shared__ float h2[64];
  int g = blockIdx.x, tid = threadIdx.x;   // block 128
#pragma unroll
  for (int j = 0; j < 4; ++j) cat[tid + 128 * j] = hg[(size_t)g * 512 + tid + 128 * j];
  __syncthreads();
  float a = combB[tid];
  for (int k = 0; k < 512; ++k) a += cat[k] * combW[(size_t)k * 128 + tid];
  h1[tid] = a; __syncthreads();
  if (tid < 64){
    float b = c1B[tid];
    for (int k = 0; k < 128; ++k) b += h1[k] * c1W[(size_t)k * 64 + tid];
    h2[tid] = fmaxf(b, 0.f);
  }
  __syncthreads();
  if (tid < 2){
    float o = c2B[tid];
    for (int k = 0; k < 64; ++k) o += h2[k] * c2W[(size_t)k * 2 + tid];
    out[(size_t)g * 2 + tid] = o;
  }
}

// ---------------- host ----------------

static void launch_gemm(int epi, dim3 grid, hipStream_t st,
                        const unsigned short* A0, const unsigned short* A1, const unsigned short* A2,
                        const unsigned short* W0, const unsigned short* W1, const unsigned short* W2,
                        const float* bias, const float* bng, const float* bnb,
                        const unsigned short* resid, unsigned short* C, int nrows){
  switch (epi){
    case 0: gemm_kernel<0><<<grid, 256, 0, st>>>(A0, A1, A2, W0, W1, W2, bias, bng, bnb, resid, C, nrows); break;
    case 1: gemm_kernel<1><<<grid, 256, 0, st>>>(A0, A1, A2, W0, W1, W2, bias, bng, bnb, resid, C, nrows); break;
    case 2: gemm_kernel<2><<<grid, 256, 0, st>>>(A0, A1, A2, W0, W1, W2, bias, bng, bnb, resid, C, nrows); break;
    default: gemm_kernel<3><<<grid, 256, 0, st>>>(A0, A1, A2, W0, W1, W2, bias, bng, bnb, resid, C, nrows); break;
  }
}

extern "C" void kernel_launch(void* const* d_in, const int* in_sizes, int n_in,
                              void* d_out, int out_size, void* d_ws, size_t ws_size,
                              hipStream_t stream){
  (void)n_in; (void)out_size; (void)ws_size;
  const int N = in_sizes[0] / 128;
  const int E = in_sizes[1] / 2;
  const int NG = 50;
  const int npg = N / NG;

  const float* x       = (const float*)d_in[0];
  const int*   ei      = (const int*)d_in[1];
  const int*   srcI    = ei;
  const int*   dstI    = ei + E;
  const float* W_gcn   = (const float*)d_in[3];
  const float* b_gcn   = (const float*)d_in[4];
  const float* gin_W1  = (const float*)d_in[5];
  const float* gin_b1  = (const float*)d_in[6];
  const float* gin_W2  = (const float*)d_in[7];
  const float* gin_b2  = (const float*)d_in[8];
  const float* W_gat   = (const float*)d_in[9];
  const float* b_gat   = (const float*)d_in[10];
  const float* a_src   = (const float*)d_in[11];
  const float* a_dst   = (const float*)d_in[12];
  const float* gproj_W = (const float*)d_in[13];
  const float* gproj_b = (const float*)d_in[14];
  const float* gate_W1 = (const float*)d_in[15];
  const float* gate_b1 = (const float*)d_in[16];
  const float* gate_W2 = (const float*)d_in[17];
  const float* gate_b2 = (const float*)d_in[18];
  const float* bn0_g   = (const float*)d_in[19];
  const float* bn0_b   = (const float*)d_in[20];
  const float* rel_W   = (const float*)d_in[21];
  const float* rel_b   = (const float*)d_in[22];
  const float* root_W  = (const float*)d_in[23];
  const float* bn_g    = (const float*)d_in[24];
  const float* bn_b    = (const float*)d_in[25];
  const float* jump_W  = (const float*)d_in[26];
  const float* jump_b  = (const float*)d_in[27];
  const float* att_W1  = (const float*)d_in[28];
  const float* att_b1  = (const float*)d_in[29];
  const float* att_W2  = (const float*)d_in[30];
  const float* att_b2  = (const float*)d_in[31];
  const float* comb_W  = (const float*)d_in[32];
  const float* comb_b  = (const float*)d_in[33];
  const float* cls_W1  = (const float*)d_in[34];
  const float* cls_b1  = (const float*)d_in[35];
  const float* cls_W2  = (const float*)d_in[36];
  const float* cls_b2  = (const float*)d_in[37];
  float* out = (float*)d_out;

  char* wp = (char*)d_ws;
  auto alloc = [&](size_t b) -> char* {
    char* p = wp; wp += (b + 511) & ~(size_t)511; return p;
  };
  unsigned int* cnt  = (unsigned int*)alloc((size_t)N * 4);
  unsigned int* fill = (unsigned int*)alloc((size_t)N * 4);
  unsigned int* rp   = (unsigned int*)alloc(((size_t)N + 1) * 4);
  int* colA          = (int*)alloc((size_t)E * 4);
  int* cpos          = (int*)alloc((size_t)E * 4);
  float* wCSR        = (float*)alloc((size_t)E * 16);
  unsigned int* bsum = (unsigned int*)alloc(256 * 4);
  float* dinv        = (float*)alloc((size_t)N * 4);
  float* als         = (float*)alloc((size_t)N * 16);
  float* ald         = (float*)alloc((size_t)N * 16);
  float* alogv       = (float*)alloc((size_t)N * 4);
  unsigned short* WtAll = (unsigned short*)alloc((size_t)18 * 16384 * 2);
  float* hg          = (float*)alloc((size_t)NG * 512 * 4);
  float* gmv         = (float*)alloc((size_t)NG * 4);
  float* gzv         = (float*)alloc((size_t)NG * 4);
  int nparts = (npg + 99) / 100;                    // chunk <= 100 <= 128
  float* part        = (float*)alloc((size_t)NG * nparts * 384 * 4);
  unsigned short* xbf = (unsigned short*)alloc((size_t)N * 128 * 2);
  unsigned short* S0 = (unsigned short*)alloc((size_t)N * 128 * 2);
  unsigned short* S1 = (unsigned short*)alloc((size_t)N * 128 * 2);
  unsigned short* S2 = (unsigned short*)alloc((size_t)N * 128 * 2);
  unsigned short* S3 = (unsigned short*)alloc((size_t)N * 128 * 2);
  unsigned short* S4 = (unsigned short*)alloc((size_t)N * 128 * 2);

  // --- CSR build ---
  int zn = (int)(((char*)rp - (char*)cnt) / 4);   // cnt + fill regions (contiguous)
  zero_u32<<<(zn + 255) / 256, 256, 0, stream>>>(cnt, zn);
  hist_kernel<<<(E + 255) / 256, 256, 0, stream>>>(dstI, cnt, E);
  int nbScan = (N + 1023) / 1024;
  scan1_kernel<<<nbScan, 1024, 0, stream>>>(cnt, rp, bsum, N);
  scan2_kernel<<<1, 256, 0, stream>>>(bsum, nbScan);
  scan3_kernel<<<(N + 255) / 256, 256, 0, stream>>>(rp, bsum, N, (unsigned int)E);
  scatter_kernel<<<(E + 255) / 256, 256, 0, stream>>>(srcI, dstI, rp, fill, colA, cpos, E);
  dinv_kernel<<<(N + 255) / 256, 256, 0, stream>>>(cnt, dinv, N);

  // --- weight transpose/cast + x cast ---
  WSrc wsrc;
  wsrc.p[0] = W_gcn;  wsrc.p[1] = W_gat;  wsrc.p[2] = gin_W1; wsrc.p[3] = gin_W2;
  wsrc.p[4] = gproj_W;
  wsrc.p[5] = gate_W1;      wsrc.p[6] = gate_W1 + 16384; wsrc.p[7] = gate_W1 + 32768;
  wsrc.p[8] = rel_W;        wsrc.p[9] = rel_W + 16384;   wsrc.p[10] = rel_W + 32768;
  wsrc.p[11] = root_W;      wsrc.p[12] = root_W + 16384; wsrc.p[13] = root_W + 32768;
  wsrc.p[14] = jump_W;      wsrc.p[15] = jump_W + 16384; wsrc.p[16] = jump_W + 32768;
  wsrc.p[17] = att_W1;
  wtrans_kernel<<<dim3(18, 2), 256, 0, stream>>>(wsrc, WtAll);
  xcast_kernel<<<(N * 64 + 255) / 256, 256, 0, stream>>>(x, xbf, N * 64);

  dim3 gg((N + 63) / 64);
  int nb4 = (N + 3) / 4;
  #define WT(i) (WtAll + (size_t)(i) * 16384)
  const unsigned short* Z = nullptr;
  const unsigned short* BZ = nullptr;

  // stems: hd = (x@W_gcn)*dinv, xp = x@W_gat in one pass over x
  gemm_dual_kernel<<<gg, 256, 0, stream>>>(xbf, WT(0), WT(1), dinv, S0, S1, N);
  alpair_kernel<<<nb4, 256, 0, stream>>>(S1, a_src, a_dst, als, ald, N);
  ew_kernel<<<(E + 255) / 256, 256, 0, stream>>>(srcI, dstI, cpos, als, ald, wCSR, E);
  gin_agg_kernel<<<nb4, 256, 0, stream>>>(xbf, rp, colA, S2, N);               // xs = x + aggr
  launch_gemm(2, gg, stream, S2, BZ, BZ, WT(2), Z, Z, gin_b1, nullptr, nullptr, BZ, S3, N); // t_gin
  launch_gemm(2, gg, stream, S3, BZ, BZ, WT(3), Z, Z, gin_b2, nullptr, nullptr, BZ, S2, N); // x_gin
  gcn_agg_kernel<<<nb4, 256, 0, stream>>>(S0, dinv, rp, colA, b_gcn, S3, N);   // x_gcn
  gat_agg_kernel<<<nb4, 256, 0, stream>>>(S1, als, ald, wCSR, rp, colA, b_gat, S0, N); // gat_pre
  launch_gemm(1, gg, stream, S0, BZ, BZ, WT(4), Z, Z, gproj_b, nullptr, nullptr, BZ, S1, N); // x_gat

  // gated fusion
  launch_gemm(2, gg, stream, S3, S2, S1, WT(5), WT(6), WT(7), gate_b1, nullptr, nullptr, BZ, S4, N); // t_gate
  combine_kernel<<<nb4, 256, 0, stream>>>(S4, gate_W2, gate_b2, S3, S2, S1, bn0_g, bn0_b, S0, N); // xx

  // GraphConv stack
  sum_agg_kernel<<<nb4, 256, 0, stream>>>(S0, rp, colA, S1, N);
  launch_gemm(3, gg, stream, S1, S0, BZ, WT(8), WT(11), Z, rel_b, bn_g, bn_b, S0, S2, N);          // reps0
  sum_agg_kernel<<<nb4, 256, 0, stream>>>(S2, rp, colA, S1, N);
  launch_gemm(3, gg, stream, S1, S2, BZ, WT(9), WT(12), Z, rel_b + 128, bn_g + 128, bn_b + 128, S2, S3, N); // reps1
  sum_agg_kernel<<<nb4, 256, 0, stream>>>(S3, rp, colA, S1, N);
  launch_gemm(3, gg, stream, S1, S3, BZ, WT(10), WT(13), Z, rel_b + 256, bn_g + 256, bn_b + 256, S3, S4, N); // reps2

  // JK cat + attention logits
  launch_gemm(1, gg, stream, S2, S3, S4, WT(14), WT(15), WT(16), jump_b, nullptr, nullptr, BZ, S0, N); // xx2
  launch_gemm(2, gg, stream, S0, BZ, BZ, WT(17), Z, Z, att_b1, nullptr, nullptr, BZ, S1, N);           // t_att
  alog_kernel<<<nb4, 256, 0, stream>>>(S1, att_W2, att_b2, alogv, N);

  // pooling + head
  att_stats_kernel<<<NG, 256, 0, stream>>>(alogv, gmv, gzv, npg);
  pool_partial_kernel<<<NG * nparts, 256, 0, stream>>>(S0, alogv, gmv, gzv, part, npg, nparts);
  pool_final_kernel<<<NG, 128, 0, stream>>>(part, hg, npg, nparts);
  head_kernel<<<NG, 128, 0, stream>>>(hg, comb_W, comb_b, cls_W1, cls_b1, cls_W2, cls_b2, out);
}

// Round 6
// 653.905 us; speedup vs baseline: 1.8410x; 1.0599x over previous
//
#include <hip/hip_runtime.h>

typedef float f32x4 __attribute__((ext_vector_type(4)));
typedef short s16x8 __attribute__((ext_vector_type(8)));

#define LDA 136   // padded LDS row length (bf16 elems)

static __device__ __forceinline__ unsigned short f2bf(float f){
  union { float f; unsigned int u; } v; v.f = f;
  unsigned int u = v.u;
  return (unsigned short)((u + 0x7fffu + ((u >> 16) & 1u)) >> 16);
}
static __device__ __forceinline__ float2 bfp2f(unsigned int p){   // packed 2xbf16 -> 2xf32
  union { unsigned int u; float f; } a, b;
  a.u = (p & 0xffffu) << 16; b.u = p & 0xffff0000u;
  return make_float2(a.f, b.f);
}
static __device__ __forceinline__ unsigned int f2bfp(float x, float y){
  return (unsigned int)f2bf(x) | ((unsigned int)f2bf(y) << 16);
}
static __device__ __forceinline__ float bf2f(unsigned short h){
  union { unsigned int u; float f; } v; v.u = (unsigned int)h << 16; return v.f;
}

static __device__ __forceinline__ float lrelu02(float x){ return x > 0.f ? x : 0.2f * x; }

// bijective XCD swizzle (m204)
static __device__ __forceinline__ int xcd_swz(int bid, int nwg){
  int q = nwg >> 3, r = nwg & 7, x = bid & 7, i = bid >> 3;
  return (x < r ? x * (q + 1) : r * (q + 1) + (x - r) * q) + i;
}

// ---------------- two-level CSR build (graph buckets -> per-graph CSR) ----------------

__global__ void zero_u32(unsigned int* p, int n){
  int i = blockIdx.x * 256 + threadIdx.x;
  if (i < n) p[i] = 0u;
}

// count edges per graph (LDS hist, then 50 global atomics per block)
__global__ void gcount_kernel(const int* __restrict__ dst, unsigned int* __restrict__ gcnt,
                              int E, int npg, int ng){
  __shared__ unsigned int h[64];
  int tid = threadIdx.x;
  if (tid < 64) h[tid] = 0u;
  __syncthreads();
  for (int i = blockIdx.x * 256 + tid; i < E; i += gridDim.x * 256)
    atomicAdd(&h[dst[i] / npg], 1u);
  __syncthreads();
  if (tid < ng) atomicAdd(&gcnt[tid], h[tid]);
}

__global__ void gscan_kernel(const unsigned int* __restrict__ gcnt, unsigned int* __restrict__ goff, int ng){
  if (threadIdx.x == 0){
    unsigned int run = 0;
    for (int i = 0; i < ng; ++i){ goff[i] = run; run += gcnt[i]; }
    goff[ng] = run;
  }
}

// bucket edges by graph; per-block contiguous runs -> coalesced-ish writes
__global__ void gbucket_kernel(const int* __restrict__ src, const int* __restrict__ dst,
                               const unsigned int* __restrict__ goff, unsigned int* __restrict__ gfill,
                               int2* __restrict__ ebuf, int E, int npg, int ng){
  __shared__ unsigned int h[64];
  __shared__ unsigned int base[64];
  __shared__ unsigned int fl[64];
  int tid = threadIdx.x;
  if (tid < 64){ h[tid] = 0u; fl[tid] = 0u; }
  __syncthreads();
  int per = (E + gridDim.x - 1) / gridDim.x;
  int i0 = blockIdx.x * per, i1 = min(E, i0 + per);
  for (int i = i0 + tid; i < i1; i += 256)
    atomicAdd(&h[dst[i] / npg], 1u);
  __syncthreads();
  if (tid < ng) base[tid] = goff[tid] + atomicAdd(&gfill[tid], h[tid]);
  __syncthreads();
  for (int i = i0 + tid; i < i1; i += 256){
    int d = dst[i];
    int g = d / npg;
    unsigned int p = base[g] + atomicAdd(&fl[g], 1u);
    ebuf[p] = make_int2(src[i], d);
  }
}

// per-graph CSR: block g builds rp/colA/dstA/dinv for its 1000 nodes (single-XCD write locality)
__global__ void csr_graph_kernel(const int2* __restrict__ ebuf, const unsigned int* __restrict__ goff,
                                 unsigned int* __restrict__ rp, int* __restrict__ colA,
                                 int* __restrict__ dstA, float* __restrict__ dinv,
                                 int npg, int N, int Etot){
  __shared__ unsigned int hist[1024];
  __shared__ unsigned int fill[1024];
  int g = blockIdx.x, tid = threadIdx.x;
  unsigned int e0 = goff[g], e1 = goff[g + 1];
  int nbase = g * npg;
  hist[tid] = 0u; fill[tid] = 0u;
  __syncthreads();
  for (unsigned int e = e0 + tid; e < e1; e += 1024)
    atomicAdd(&hist[ebuf[e].y - nbase], 1u);
  __syncthreads();
  unsigned int cnt = hist[tid];
  // inclusive Hillis-Steele scan in place
  for (int off = 1; off < 1024; off <<= 1){
    unsigned int t = (tid >= off) ? hist[tid - off] : 0u;
    __syncthreads();
    hist[tid] += t;
    __syncthreads();
  }
  unsigned int basev = e0 + hist[tid] - cnt;   // exclusive + graph offset
  __syncthreads();
  hist[tid] = basev;                            // hist now holds per-node base
  if (tid < npg){
    int node = nbase + tid;
    rp[node] = basev;
    dinv[node] = rsqrtf((float)cnt + 1.0f);
  }
  if (g == 0 && tid == 0) rp[N] = (unsigned int)Etot;
  __syncthreads();
  for (unsigned int e = e0 + tid; e < e1; e += 1024){
    int2 sd = ebuf[e];
    int ld = sd.y - nbase;
    unsigned int pos = hist[ld] + atomicAdd(&fill[ld], 1u);
    colA[pos] = sd.x;
    dstA[pos] = sd.y;
  }
}

// x f32 -> bf16 (one shot)
__global__ void xcast_kernel(const float* __restrict__ x, unsigned short* __restrict__ xb, int n2){
  int i = blockIdx.x * 256 + threadIdx.x;
  if (i < n2){
    float2 v = ((const float2*)x)[i];
    ((unsigned int*)xb)[i] = f2bfp(v.x, v.y);
  }
}

// GAT edge weights, CSR order, fully coalesced; bf16x4 packed per edge (8B)
__global__ void ew_kernel(const int* __restrict__ colA, const int* __restrict__ dstA,
                          const float* __restrict__ als, const float* __restrict__ ald,
                          unsigned int* __restrict__ wb, int E){
  int i = blockIdx.x * 256 + threadIdx.x;
  if (i >= E) return;
  int s = colA[i], d = dstA[i];
  float4 as = ((const float4*)als)[s];
  float4 ad = ((const float4*)ald)[d];
  float w0 = __expf(fminf(lrelu02(as.x + ad.x), 30.f));
  float w1 = __expf(fminf(lrelu02(as.y + ad.y), 30.f));
  float w2 = __expf(fminf(lrelu02(as.z + ad.z), 30.f));
  float w3 = __expf(fminf(lrelu02(as.w + ad.w), 30.f));
  wb[(size_t)i * 2 + 0] = f2bfp(w0, w1);
  wb[(size_t)i * 2 + 1] = f2bfp(w2, w3);
}

// ---------------- weight transpose (f32 [128,128] row-major -> bf16 [col][k]) ----------------

struct WSrc { const float* p[18]; };

__global__ void wtrans_kernel(WSrc s, unsigned short* __restrict__ dstAll){
  const float* src = s.p[blockIdx.x];
  unsigned short* dst = dstAll + (size_t)blockIdx.x * 16384;
  __shared__ float st[64][129];
  int tid = threadIdx.x;
  int kb = blockIdx.y * 64;
#pragma unroll
  for (int j = 0; j < 8; ++j){
    int e = tid + 256 * j;          // 0..2047
    int r = e >> 5, c4 = (e & 31) * 4;
    float4 v = *(const float4*)(src + (size_t)(kb + r) * 128 + c4);
    st[r][c4] = v.x; st[r][c4+1] = v.y; st[r][c4+2] = v.z; st[r][c4+3] = v.w;
  }
  __syncthreads();
#pragma unroll
  for (int j = 0; j < 8; ++j){
    int e = tid + 256 * j;          // 0..2047
    int c = e >> 4, k4 = (e & 15) * 4;
    ushort4 o;
    o.x = f2bf(st[k4+0][c]); o.y = f2bf(st[k4+1][c]);
    o.z = f2bf(st[k4+2][c]); o.w = f2bf(st[k4+3][c]);
    *(ushort4*)(dst + (size_t)c * 128 + kb + k4) = o;
  }
}

// ---------------- MFMA GEMM: C[nrows,128] = sum_p A_p[nrows,128] @ W_p[128,128] (+epilogue) ----------------
// A_p bf16 row-major; W_p pre-transposed bf16 Wt[col][k]; C bf16.
// EPI: 0 none, 1 +bias, 2 relu(+bias), 3 conv: relu((acc+bias)*bn_g*RSQ + bn_b) + resid

template<int EPI>
__launch_bounds__(256, 2)
__global__ void gemm_kernel(const unsigned short* __restrict__ A0, const unsigned short* __restrict__ A1,
                            const unsigned short* __restrict__ A2,
                            const unsigned short* __restrict__ W0, const unsigned short* __restrict__ W1,
                            const unsigned short* __restrict__ W2,
                            const float* __restrict__ bias, const float* __restrict__ bng, const float* __restrict__ bnb,
                            const unsigned short* __restrict__ resid, unsigned short* __restrict__ C, int nrows)
{
  __shared__ unsigned short As[64 * LDA];
  __shared__ unsigned short Wt[128 * LDA];
  const int tid = threadIdx.x;
  const int wave = tid >> 6, lane = tid & 63;
  const int row0 = blockIdx.x * 64;
  const unsigned short* Aps[3] = {A0, A1, A2};
  const unsigned short* Wps[3] = {W0, W1, W2};
  f32x4 acc[8];
#pragma unroll
  for (int i = 0; i < 8; ++i) acc[i] = (f32x4){0.f, 0.f, 0.f, 0.f};

  for (int p = 0; p < 3; ++p){
    const unsigned short* Ap = Aps[p];
    if (Ap == nullptr) break;
    const unsigned short* Wp = Wps[p];
    if (p) __syncthreads();            // LDS reuse guard
#pragma unroll
    for (int j = 0; j < 4; ++j){
      int e = tid + 256 * j;           // 0..1023 (64 rows x 16 chunks of 8 bf16)
      int r = e >> 4, k8 = (e & 15) * 8;
      int gr = row0 + r;
      s16x8 v = {0,0,0,0,0,0,0,0};
      if (gr < nrows) v = *(const s16x8*)(Ap + (size_t)gr * 128 + k8);
      *(s16x8*)(As + r * LDA + k8) = v;
    }
#pragma unroll
    for (int j = 0; j < 8; ++j){
      int e = tid + 256 * j;           // 0..2047 (128 cols x 16 chunks of 8)
      int colw = e >> 4, k8 = (e & 15) * 8;
      *(s16x8*)(Wt + colw * LDA + k8) = *(const s16x8*)(Wp + (size_t)colw * 128 + k8);
    }
    __syncthreads();
#pragma unroll
    for (int kc = 0; kc < 4; ++kc){
      int ko = kc * 32 + (lane >> 4) * 8;
      s16x8 av = *(const s16x8*)(As + (wave * 16 + (lane & 15)) * LDA + ko);
#pragma unroll
      for (int ct = 0; ct < 8; ++ct){
        s16x8 bv = *(const s16x8*)(Wt + (ct * 16 + (lane & 15)) * LDA + ko);
        acc[ct] = __builtin_amdgcn_mfma_f32_16x16x32_bf16(av, bv, acc[ct], 0, 0, 0);
      }
    }
  }
  const float RSQ = 0.99999500003749969f; // rsqrt(1 + 1e-5)
#pragma unroll
  for (int ct = 0; ct < 8; ++ct){
    int colg = ct * 16 + (lane & 15);
    float bv_ = (EPI >= 1) ? bias[colg] : 0.f;
    float sg = (EPI == 3) ? bng[colg] * RSQ : 0.f;
    float sb = (EPI == 3) ? bnb[colg] : 0.f;
#pragma unroll
    for (int r = 0; r < 4; ++r){
      int rowg = row0 + wave * 16 + (lane >> 4) * 4 + r;
      if (rowg < nrows){
        float v = acc[ct][r];
        if (EPI == 1) v += bv_;
        else if (EPI == 2) v = fmaxf(v + bv_, 0.f);
        else if (EPI == 3){
          v = (v + bv_) * sg + sb;
          v = fmaxf(v, 0.f) + bf2f(resid[(size_t)rowg * 128 + colg]);
        }
        C[(size_t)rowg * 128 + colg] = f2bf(v);
      }
    }
  }
}

// Dual-output GEMM sharing A(bf16): C0 = (A@W0)*dscale[row], C1 = A@W1 (both bf16 out).
__launch_bounds__(256, 2)
__global__ void gemm_dual_kernel(const unsigned short* __restrict__ A,
                                 const unsigned short* __restrict__ W0, const unsigned short* __restrict__ W1,
                                 const float* __restrict__ dscale,
                                 unsigned short* __restrict__ C0, unsigned short* __restrict__ C1, int nrows)
{
  __shared__ unsigned short As[64 * LDA];
  __shared__ unsigned short Wt[128 * LDA];
  const int tid = threadIdx.x;
  const int wave = tid >> 6, lane = tid & 63;
  const int row0 = blockIdx.x * 64;
  f32x4 acc0[8], acc1[8];
#pragma unroll
  for (int i = 0; i < 8; ++i){ acc0[i] = (f32x4){0.f,0.f,0.f,0.f}; acc1[i] = (f32x4){0.f,0.f,0.f,0.f}; }

#pragma unroll
  for (int j = 0; j < 4; ++j){
    int e = tid + 256 * j;
    int r = e >> 4, k8 = (e & 15) * 8;
    int gr = row0 + r;
    s16x8 v = {0,0,0,0,0,0,0,0};
    if (gr < nrows) v = *(const s16x8*)(A + (size_t)gr * 128 + k8);
    *(s16x8*)(As + r * LDA + k8) = v;
  }
#pragma unroll
  for (int j = 0; j < 8; ++j){
    int e = tid + 256 * j;
    int colw = e >> 4, k8 = (e & 15) * 8;
    *(s16x8*)(Wt + colw * LDA + k8) = *(const s16x8*)(W0 + (size_t)colw * 128 + k8);
  }
  __syncthreads();
  s16x8 av[4];
#pragma unroll
  for (int kc = 0; kc < 4; ++kc)
    av[kc] = *(const s16x8*)(As + (wave * 16 + (lane & 15)) * LDA + kc * 32 + (lane >> 4) * 8);
#pragma unroll
  for (int kc = 0; kc < 4; ++kc){
    int ko = kc * 32 + (lane >> 4) * 8;
#pragma unroll
    for (int ct = 0; ct < 8; ++ct){
      s16x8 bv = *(const s16x8*)(Wt + (ct * 16 + (lane & 15)) * LDA + ko);
      acc0[ct] = __builtin_amdgcn_mfma_f32_16x16x32_bf16(av[kc], bv, acc0[ct], 0, 0, 0);
    }
  }
  __syncthreads();
#pragma unroll
  for (int j = 0; j < 8; ++j){
    int e = tid + 256 * j;
    int colw = e >> 4, k8 = (e & 15) * 8;
    *(s16x8*)(Wt + colw * LDA + k8) = *(const s16x8*)(W1 + (size_t)colw * 128 + k8);
  }
  __syncthreads();
#pragma unroll
  for (int kc = 0; kc < 4; ++kc){
    int ko = kc * 32 + (lane >> 4) * 8;
#pragma unroll
    for (int ct = 0; ct < 8; ++ct){
      s16x8 bv = *(const s16x8*)(Wt + (ct * 16 + (lane & 15)) * LDA + ko);
      acc1[ct] = __builtin_amdgcn_mfma_f32_16x16x32_bf16(av[kc], bv, acc1[ct], 0, 0, 0);
    }
  }
#pragma unroll
  for (int ct = 0; ct < 8; ++ct){
    int colg = ct * 16 + (lane & 15);
#pragma unroll
    for (int r = 0; r < 4; ++r){
      int rowg = row0 + wave * 16 + (lane >> 4) * 4 + r;
      if (rowg < nrows){
        C0[(size_t)rowg * 128 + colg] = f2bf(acc0[ct][r] * dscale[rowg]);
        C1[(size_t)rowg * 128 + colg] = f2bf(acc1[ct][r]);
      }
    }
  }
}

// ---------------- aggregation kernels (wave per node, bf16x2 per lane, 4x unrolled) ----------------

__global__ void gin_agg_kernel(const unsigned short* __restrict__ x, const unsigned int* __restrict__ rp,
                               const int* __restrict__ col, unsigned short* __restrict__ xs, int n){
  int bid = xcd_swz(blockIdx.x, gridDim.x);
  int node = bid * 4 + (int)(threadIdx.x >> 6);
  if (node >= n) return;
  int lane = threadIdx.x & 63;
  const unsigned int* xin = (const unsigned int*)x;
  float2 acc = bfp2f(xin[(size_t)node * 64 + lane]);   // (1+0)*x self term
  unsigned int rs = rp[node], re = rp[node + 1], e = rs;
  for (; e + 4 <= re; e += 4){
    int s0 = col[e], s1 = col[e+1], s2 = col[e+2], s3 = col[e+3];
    float2 v0 = bfp2f(xin[(size_t)s0 * 64 + lane]);
    float2 v1 = bfp2f(xin[(size_t)s1 * 64 + lane]);
    float2 v2 = bfp2f(xin[(size_t)s2 * 64 + lane]);
    float2 v3 = bfp2f(xin[(size_t)s3 * 64 + lane]);
    acc.x += v0.x + v1.x + v2.x + v3.x;
    acc.y += v0.y + v1.y + v2.y + v3.y;
  }
  for (; e < re; ++e){
    float2 v = bfp2f(xin[(size_t)col[e] * 64 + lane]);
    acc.x += v.x; acc.y += v.y;
  }
  ((unsigned int*)xs)[(size_t)node * 64 + lane] = f2bfp(acc.x, acc.y);
}

// GCN aggregation over pre-scaled hd = (x@W_gcn)*dinv: out = relu(di*(hd[d] + sum_s hd[s]) + b)
__global__ void gcn_agg_kernel(const unsigned short* __restrict__ hd, const float* __restrict__ dinv,
                               const unsigned int* __restrict__ rp, const int* __restrict__ col,
                               const float* __restrict__ b, unsigned short* __restrict__ out, int n){
  int bid = xcd_swz(blockIdx.x, gridDim.x);
  int node = bid * 4 + (int)(threadIdx.x >> 6);
  if (node >= n) return;
  int lane = threadIdx.x & 63;
  const unsigned int* hv = (const unsigned int*)hd;
  float di = dinv[node];
  float2 acc = bfp2f(hv[(size_t)node * 64 + lane]);    // self: hd[d]
  unsigned int rs = rp[node], re = rp[node + 1], e = rs;
  for (; e + 4 <= re; e += 4){
    int s0 = col[e], s1 = col[e+1], s2 = col[e+2], s3 = col[e+3];
    float2 v0 = bfp2f(hv[(size_t)s0 * 64 + lane]);
    float2 v1 = bfp2f(hv[(size_t)s1 * 64 + lane]);
    float2 v2 = bfp2f(hv[(size_t)s2 * 64 + lane]);
    float2 v3 = bfp2f(hv[(size_t)s3 * 64 + lane]);
    acc.x += v0.x + v1.x + v2.x + v3.x;
    acc.y += v0.y + v1.y + v2.y + v3.y;
  }
  for (; e < re; ++e){
    float2 v = bfp2f(hv[(size_t)col[e] * 64 + lane]);
    acc.x += v.x; acc.y += v.y;
  }
  int f = lane * 2;
  float o0 = fmaxf(acc.x * di + b[f], 0.f);
  float o1 = fmaxf(acc.y * di + b[f + 1], 0.f);
  ((unsigned int*)out)[(size_t)node * 64 + lane] = f2bfp(o0, o1);
}

__global__ void sum_agg_kernel(const unsigned short* __restrict__ x, const unsigned int* __restrict__ rp,
                               const int* __restrict__ col, unsigned short* __restrict__ out, int n){
  int bid = xcd_swz(blockIdx.x, gridDim.x);
  int node = bid * 4 + (int)(threadIdx.x >> 6);
  if (node >= n) return;
  int lane = threadIdx.x & 63;
  const unsigned int* xin = (const unsigned int*)x;
  float2 acc = make_float2(0.f, 0.f);
  unsigned int rs = rp[node], re = rp[node + 1], e = rs;
  for (; e + 4 <= re; e += 4){
    int s0 = col[e], s1 = col[e+1], s2 = col[e+2], s3 = col[e+3];
    float2 v0 = bfp2f(xin[(size_t)s0 * 64 + lane]);
    float2 v1 = bfp2f(xin[(size_t)s1 * 64 + lane]);
    float2 v2 = bfp2f(xin[(size_t)s2 * 64 + lane]);
    float2 v3 = bfp2f(xin[(size_t)s3 * 64 + lane]);
    acc.x += v0.x + v1.x + v2.x + v3.x;
    acc.y += v0.y + v1.y + v2.y + v3.y;
  }
  for (; e < re; ++e){
    float2 v = bfp2f(xin[(size_t)col[e] * 64 + lane]);
    acc.x += v.x; acc.y += v.y;
  }
  ((unsigned int*)out)[(size_t)node * 64 + lane] = f2bfp(acc.x, acc.y);
}

// GAT aggregation with precomputed CSR-order bf16x4 edge weights.
__global__ void gat_agg_kernel(const unsigned short* __restrict__ xp, const float* __restrict__ als,
                               const float* __restrict__ ald, const unsigned int* __restrict__ wb,
                               const unsigned int* __restrict__ rp, const int* __restrict__ col,
                               const float* __restrict__ bgat, unsigned short* __restrict__ out, int n){
  int bid = xcd_swz(blockIdx.x, gridDim.x);
  int node = bid * 4 + (int)(threadIdx.x >> 6);
  if (node >= n) return;
  int lane = threadIdx.x & 63;
  int h = lane >> 4;
  int wword = h >> 1, wsh = (h & 1) * 16;
  const unsigned int* xv = (const unsigned int*)xp;
  // self term
  float w = __expf(fminf(lrelu02(als[(size_t)node * 4 + h] + ald[(size_t)node * 4 + h]), 30.f));
  float2 sv = bfp2f(xv[(size_t)node * 64 + lane]);
  float2 acc = make_float2(sv.x * w, sv.y * w);
  float denom = w;
  unsigned int rs = rp[node], re = rp[node + 1], e = rs;
  for (; e + 4 <= re; e += 4){
    int s0 = col[e], s1 = col[e+1], s2 = col[e+2], s3 = col[e+3];
    float w0 = bf2f((unsigned short)(wb[(size_t)(e+0) * 2 + wword] >> wsh));
    float w1 = bf2f((unsigned short)(wb[(size_t)(e+1) * 2 + wword] >> wsh));
    float w2 = bf2f((unsigned short)(wb[(size_t)(e+2) * 2 + wword] >> wsh));
    float w3 = bf2f((unsigned short)(wb[(size_t)(e+3) * 2 + wword] >> wsh));
    float2 v0 = bfp2f(xv[(size_t)s0 * 64 + lane]);
    float2 v1 = bfp2f(xv[(size_t)s1 * 64 + lane]);
    float2 v2 = bfp2f(xv[(size_t)s2 * 64 + lane]);
    float2 v3 = bfp2f(xv[(size_t)s3 * 64 + lane]);
    acc.x += v0.x * w0 + v1.x * w1 + v2.x * w2 + v3.x * w3;
    acc.y += v0.y * w0 + v1.y * w1 + v2.y * w2 + v3.y * w3;
    denom += w0 + w1 + w2 + w3;
  }
  for (; e < re; ++e){
    float we = bf2f((unsigned short)(wb[(size_t)e * 2 + wword] >> wsh));
    float2 v = bfp2f(xv[(size_t)col[e] * 64 + lane]);
    acc.x += v.x * we; acc.y += v.y * we;
    denom += we;
  }
  float inv = 1.0f / denom;
  int f = lane * 2;
  float o0 = fmaxf(acc.x * inv + bgat[f], 0.f);
  float o1 = fmaxf(acc.y * inv + bgat[f + 1], 0.f);
  ((unsigned int*)out)[(size_t)node * 64 + lane] = f2bfp(o0, o1);
}

// ---------------- small per-node kernels ----------------

__global__ void alpair_kernel(const unsigned short* __restrict__ xp, const float* __restrict__ a_src,
                              const float* __restrict__ a_dst, float* __restrict__ als,
                              float* __restrict__ ald, int n){
  int node = blockIdx.x * 4 + (int)(threadIdx.x >> 6);
  if (node >= n) return;
  int lane = threadIdx.x & 63;
  int f = lane * 2;
  float2 v = bfp2f(((const unsigned int*)xp)[(size_t)node * 64 + lane]);
  float ps = v.x * a_src[f] + v.y * a_src[f + 1];
  float pd = v.x * a_dst[f] + v.y * a_dst[f + 1];
#pragma unroll
  for (int off = 1; off < 16; off <<= 1){
    ps += __shfl_xor(ps, off, 64);
    pd += __shfl_xor(pd, off, 64);
  }
  if ((lane & 15) == 0){
    int hh = lane >> 4;
    als[(size_t)node * 4 + hh] = ps;
    ald[(size_t)node * 4 + hh] = pd;
  }
}

__global__ void combine_kernel(const unsigned short* __restrict__ t, const float* __restrict__ W2,
                               const float* __restrict__ b2, const unsigned short* __restrict__ xg,
                               const unsigned short* __restrict__ xi, const unsigned short* __restrict__ xa,
                               const float* __restrict__ bn0g, const float* __restrict__ bn0b,
                               unsigned short* __restrict__ xx, int n){
  int node = blockIdx.x * 4 + (int)(threadIdx.x >> 6);
  if (node >= n) return;
  int lane = threadIdx.x & 63;
  int f = lane * 2;
  float2 tv = bfp2f(((const unsigned int*)t)[(size_t)node * 64 + lane]);
  float p0 = tv.x * W2[f * 3 + 0] + tv.y * W2[(f + 1) * 3 + 0];
  float p1 = tv.x * W2[f * 3 + 1] + tv.y * W2[(f + 1) * 3 + 1];
  float p2 = tv.x * W2[f * 3 + 2] + tv.y * W2[(f + 1) * 3 + 2];
#pragma unroll
  for (int off = 1; off < 64; off <<= 1){
    p0 += __shfl_xor(p0, off, 64);
    p1 += __shfl_xor(p1, off, 64);
    p2 += __shfl_xor(p2, off, 64);
  }
  p0 += b2[0]; p1 += b2[1]; p2 += b2[2];
  float mm = fmaxf(p0, fmaxf(p1, p2));
  float e0 = __expf(p0 - mm), e1 = __expf(p1 - mm), e2 = __expf(p2 - mm);
  float inv = 1.0f / (e0 + e1 + e2);
  e0 *= inv; e1 *= inv; e2 *= inv;
  float2 a = bfp2f(((const unsigned int*)xg)[(size_t)node * 64 + lane]);
  float2 b = bfp2f(((const unsigned int*)xi)[(size_t)node * 64 + lane]);
  float2 c = bfp2f(((const unsigned int*)xa)[(size_t)node * 64 + lane]);
  const float RSQ = 0.99999500003749969f;
  float o0 = fmaxf((e0 * a.x + e1 * b.x + e2 * c.x) * (bn0g[f] * RSQ) + bn0b[f], 0.f);
  float o1 = fmaxf((e0 * a.y + e1 * b.y + e2 * c.y) * (bn0g[f + 1] * RSQ) + bn0b[f + 1], 0.f);
  ((unsigned int*)xx)[(size_t)node * 64 + lane] = f2bfp(o0, o1);
}

__global__ void alog_kernel(const unsigned short* __restrict__ t, const float* __restrict__ w,
                            const float* __restrict__ b, float* __restrict__ alog, int n){
  int node = blockIdx.x * 4 + (int)(threadIdx.x >> 6);
  if (node >= n) return;
  int lane = threadIdx.x & 63;
  int f = lane * 2;
  float2 tv = bfp2f(((const unsigned int*)t)[(size_t)node * 64 + lane]);
  float p = tv.x * w[f] + tv.y * w[f + 1];
#pragma unroll
  for (int off = 1; off < 64; off <<= 1) p += __shfl_xor(p, off, 64);
  if (lane == 0) alog[node] = p + b[0];
}

// ---------------- pooling + head ----------------

__global__ void att_stats_kernel(const float* __restrict__ alog, float* __restrict__ gm,
                                 float* __restrict__ gz, int npg){
  __shared__ float red[256];
  int g = blockIdx.x, tid = threadIdx.x;
  size_t base = (size_t)g * npg;
  float m = -1e30f;
  for (int i = tid; i < npg; i += 256) m = fmaxf(m, alog[base + i]);
  red[tid] = m; __syncthreads();
  for (int off = 128; off > 0; off >>= 1){ if (tid < off) red[tid] = fmaxf(red[tid], red[tid + off]); __syncthreads(); }
  float gmax = red[0]; __syncthreads();
  float z = 0.f;
  for (int i = tid; i < npg; i += 256) z += __expf(alog[base + i] - gmax);
  red[tid] = z; __syncthreads();
  for (int off = 128; off > 0; off >>= 1){ if (tid < off) red[tid] += red[tid + off]; __syncthreads(); }
  if (tid == 0){ gm[g] = gmax; gz[g] = red[0]; }
}

__global__ void pool_partial_kernel(const unsigned short* __restrict__ xx, const float* __restrict__ alog,
                                    const float* __restrict__ gm, const float* __restrict__ gz,
                                    float* __restrict__ part, int npg, int nparts){
  __shared__ float wts[128];
  __shared__ float red[256];
  int g = blockIdx.x / nparts, p = blockIdx.x % nparts;
  int chunk = (npg + nparts - 1) / nparts;
  int n0 = p * chunk, n1 = min(npg, n0 + chunk);
  int tid = threadIdx.x;
  float gmax = gm[g], ginv = 1.0f / gz[g];
  size_t base = (size_t)g * npg;
  for (int i = n0 + tid; i < n1; i += 256) wts[i - n0] = __expf(alog[base + i] - gmax) * ginv;
  __syncthreads();
  int f = tid & 127, half = tid >> 7;
  float add = 0.f, mx = -1e30f, att = 0.f;
  for (int n2 = n0 + half; n2 < n1; n2 += 2){
    float v = bf2f(xx[(base + n2) * 128 + f]);
    add += v; mx = fmaxf(mx, v); att += v * wts[n2 - n0];
  }
  red[tid] = add; __syncthreads();
  float addf = add + ((half == 0) ? red[tid + 128] : 0.f);
  __syncthreads(); red[tid] = mx; __syncthreads();
  float mxf = (half == 0) ? fmaxf(mx, red[tid + 128]) : 0.f;
  __syncthreads(); red[tid] = att; __syncthreads();
  float attf = att + ((half == 0) ? red[tid + 128] : 0.f);
  if (half == 0){
    float* o = part + (size_t)(g * nparts + p) * 384;
    o[f] = addf; o[128 + f] = mxf; o[256 + f] = attf;
  }
}

__global__ void pool_final_kernel(const float* __restrict__ part, float* __restrict__ hg,
                                  int npg, int nparts){
  int g = blockIdx.x, f = threadIdx.x;   // 128 threads
  float add = 0.f, mx = -1e30f, att = 0.f;
  for (int p = 0; p < nparts; ++p){
    const float* o = part + (size_t)(g * nparts + p) * 384;
    add += o[f]; mx = fmaxf(mx, o[128 + f]); att += o[256 + f];
  }
  float* o = hg + (size_t)g * 512;
  o[f] = add / (float)npg;    // mean
  o[128 + f] = mx;            // max
  o[256 + f] = add;           // add
  o[384 + f] = att;           // att (already normalized)
}

__global__ void head_kernel(const float* __restrict__ hg, const float* __restrict__ combW,
                            const float* __restrict__ combB, const float* __restrict__ c1W,
                            const float* __restrict__ c1B, const float* __restrict__ c2W,
                            const float* __restrict__ c2B, float* __restrict__ out){
  __shared__ float cat[512];
  __shared__ float h1[128];
  __shared__ float h2[64];
  int g = blockIdx.x, tid = threadIdx.x;   // block 128
#pragma unroll
  for (int j = 0; j < 4; ++j) cat[tid + 128 * j] = hg[(size_t)g * 512 + tid + 128 * j];
  __syncthreads();
  float a = combB[tid];
  for (int k = 0; k < 512; ++k) a += cat[k] * combW[(size_t)k * 128 + tid];
  h1[tid] = a; __syncthreads();
  if (tid < 64){
    float b = c1B[tid];
    for (int k = 0; k < 128; ++k) b += h1[k] * c1W[(size_t)k * 64 + tid];
    h2[tid] = fmaxf(b, 0.f);
  }
  __syncthreads();
  if (tid < 2){
    float o = c2B[tid];
    for (int k = 0; k < 64; ++k) o += h2[k] * c2W[(size_t)k * 2 + tid];
    out[(size_t)g * 2 + tid] = o;
  }
}

// ---------------- host ----------------

static void launch_gemm(int epi, dim3 grid, hipStream_t st,
                        const unsigned short* A0, const unsigned short* A1, const unsigned short* A2,
                        const unsigned short* W0, const unsigned short* W1, const unsigned short* W2,
                        const float* bias, const float* bng, const float* bnb,
                        const unsigned short* resid, unsigned short* C, int nrows){
  switch (epi){
    case 0: gemm_kernel<0><<<grid, 256, 0, st>>>(A0, A1, A2, W0, W1, W2, bias, bng, bnb, resid, C, nrows); break;
    case 1: gemm_kernel<1><<<grid, 256, 0, st>>>(A0, A1, A2, W0, W1, W2, bias, bng, bnb, resid, C, nrows); break;
    case 2: gemm_kernel<2><<<grid, 256, 0, st>>>(A0, A1, A2, W0, W1, W2, bias, bng, bnb, resid, C, nrows); break;
    default: gemm_kernel<3><<<grid, 256, 0, st>>>(A0, A1, A2, W0, W1, W2, bias, bng, bnb, resid, C, nrows); break;
  }
}

extern "C" void kernel_launch(void* const* d_in, const int* in_sizes, int n_in,
                              void* d_out, int out_size, void* d_ws, size_t ws_size,
                              hipStream_t stream){
  (void)n_in; (void)out_size; (void)ws_size;
  const int N = in_sizes[0] / 128;
  const int E = in_sizes[1] / 2;
  const int NG = 50;
  const int npg = N / NG;

  const float* x       = (const float*)d_in[0];
  const int*   ei      = (const int*)d_in[1];
  const int*   srcI    = ei;
  const int*   dstI    = ei + E;
  const float* W_gcn   = (const float*)d_in[3];
  const float* b_gcn   = (const float*)d_in[4];
  const float* gin_W1  = (const float*)d_in[5];
  const float* gin_b1  = (const float*)d_in[6];
  const float* gin_W2  = (const float*)d_in[7];
  const float* gin_b2  = (const float*)d_in[8];
  const float* W_gat   = (const float*)d_in[9];
  const float* b_gat   = (const float*)d_in[10];
  const float* a_src   = (const float*)d_in[11];
  const float* a_dst   = (const float*)d_in[12];
  const float* gproj_W = (const float*)d_in[13];
  const float* gproj_b = (const float*)d_in[14];
  const float* gate_W1 = (const float*)d_in[15];
  const float* gate_b1 = (const float*)d_in[16];
  const float* gate_W2 = (const float*)d_in[17];
  const float* gate_b2 = (const float*)d_in[18];
  const float* bn0_g   = (const float*)d_in[19];
  const float* bn0_b   = (const float*)d_in[20];
  const float* rel_W   = (const float*)d_in[21];
  const float* rel_b   = (const float*)d_in[22];
  const float* root_W  = (const float*)d_in[23];
  const float* bn_g    = (const float*)d_in[24];
  const float* bn_b    = (const float*)d_in[25];
  const float* jump_W  = (const float*)d_in[26];
  const float* jump_b  = (const float*)d_in[27];
  const float* att_W1  = (const float*)d_in[28];
  const float* att_b1  = (const float*)d_in[29];
  const float* att_W2  = (const float*)d_in[30];
  const float* att_b2  = (const float*)d_in[31];
  const float* comb_W  = (const float*)d_in[32];
  const float* comb_b  = (const float*)d_in[33];
  const float* cls_W1  = (const float*)d_in[34];
  const float* cls_b1  = (const float*)d_in[35];
  const float* cls_W2  = (const float*)d_in[36];
  const float* cls_b2  = (const float*)d_in[37];
  float* out = (float*)d_out;

  char* wp = (char*)d_ws;
  auto alloc = [&](size_t b) -> char* {
    char* p = wp; wp += (b + 511) & ~(size_t)511; return p;
  };
  unsigned int* rp   = (unsigned int*)alloc(((size_t)N + 1) * 4);
  int* colA          = (int*)alloc((size_t)E * 4);
  int* dstA          = (int*)alloc((size_t)E * 4);
  int2* ebuf         = (int2*)alloc((size_t)E * 8);
  unsigned int* wb   = (unsigned int*)alloc((size_t)E * 8);
  unsigned int* gcnt = (unsigned int*)alloc(192 * 4);   // gcnt[64] | gfill[64] | goff[64] in ONE block
  unsigned int* gfill= gcnt + 64;
  unsigned int* goff = gcnt + 128;
  float* dinv        = (float*)alloc((size_t)N * 4);
  float* als         = (float*)alloc((size_t)N * 16);
  float* ald         = (float*)alloc((size_t)N * 16);
  float* alogv       = (float*)alloc((size_t)N * 4);
  unsigned short* WtAll = (unsigned short*)alloc((size_t)18 * 16384 * 2);
  float* hg          = (float*)alloc((size_t)NG * 512 * 4);
  float* gmv         = (float*)alloc((size_t)NG * 4);
  float* gzv         = (float*)alloc((size_t)NG * 4);
  int nparts = (npg + 99) / 100;                    // chunk <= 100 <= 128
  float* part        = (float*)alloc((size_t)NG * nparts * 384 * 4);
  unsigned short* xbf = (unsigned short*)alloc((size_t)N * 128 * 2);
  unsigned short* S0 = (unsigned short*)alloc((size_t)N * 128 * 2);
  unsigned short* S1 = (unsigned short*)alloc((size_t)N * 128 * 2);
  unsigned short* S2 = (unsigned short*)alloc((size_t)N * 128 * 2);
  unsigned short* S3 = (unsigned short*)alloc((size_t)N * 128 * 2);
  unsigned short* S4 = (unsigned short*)alloc((size_t)N * 128 * 2);

  // --- two-level CSR build ---
  zero_u32<<<1, 256, 0, stream>>>(gcnt, 128);                 // zeroes gcnt AND gfill (contiguous now)
  gcount_kernel<<<256, 256, 0, stream>>>(dstI, gcnt, E, npg, NG);
  gscan_kernel<<<1, 64, 0, stream>>>(gcnt, goff, NG);
  gbucket_kernel<<<256, 256, 0, stream>>>(srcI, dstI, goff, gfill, ebuf, E, npg, NG);
  csr_graph_kernel<<<NG, 1024, 0, stream>>>(ebuf, goff, rp, colA, dstA, dinv, npg, N, E);

  // --- weight transpose/cast + x cast ---
  WSrc wsrc;
  wsrc.p[0] = W_gcn;  wsrc.p[1] = W_gat;  wsrc.p[2] = gin_W1; wsrc.p[3] = gin_W2;
  wsrc.p[4] = gproj_W;
  wsrc.p[5] = gate_W1;      wsrc.p[6] = gate_W1 + 16384; wsrc.p[7] = gate_W1 + 32768;
  wsrc.p[8] = rel_W;        wsrc.p[9] = rel_W + 16384;   wsrc.p[10] = rel_W + 32768;
  wsrc.p[11] = root_W;      wsrc.p[12] = root_W + 16384; wsrc.p[13] = root_W + 32768;
  wsrc.p[14] = jump_W;      wsrc.p[15] = jump_W + 16384; wsrc.p[16] = jump_W + 32768;
  wsrc.p[17] = att_W1;
  wtrans_kernel<<<dim3(18, 2), 256, 0, stream>>>(wsrc, WtAll);
  xcast_kernel<<<(N * 64 + 255) / 256, 256, 0, stream>>>(x, xbf, N * 64);

  dim3 gg((N + 63) / 64);
  int nb4 = (N + 3) / 4;
  #define WT(i) (WtAll + (size_t)(i) * 16384)
  const unsigned short* Z = nullptr;
  const unsigned short* BZ = nullptr;

  // stems: hd = (x@W_gcn)*dinv, xp = x@W_gat in one pass over x
  gemm_dual_kernel<<<gg, 256, 0, stream>>>(xbf, WT(0), WT(1), dinv, S0, S1, N);
  alpair_kernel<<<nb4, 256, 0, stream>>>(S1, a_src, a_dst, als, ald, N);
  ew_kernel<<<(E + 255) / 256, 256, 0, stream>>>(colA, dstA, als, ald, wb, E);
  gin_agg_kernel<<<nb4, 256, 0, stream>>>(xbf, rp, colA, S2, N);               // xs = x + aggr
  launch_gemm(2, gg, stream, S2, BZ, BZ, WT(2), Z, Z, gin_b1, nullptr, nullptr, BZ, S3, N); // t_gin
  launch_gemm(2, gg, stream, S3, BZ, BZ, WT(3), Z, Z, gin_b2, nullptr, nullptr, BZ, S2, N); // x_gin
  gcn_agg_kernel<<<nb4, 256, 0, stream>>>(S0, dinv, rp, colA, b_gcn, S3, N);   // x_gcn
  gat_agg_kernel<<<nb4, 256, 0, stream>>>(S1, als, ald, wb, rp, colA, b_gat, S0, N); // gat_pre
  launch_gemm(1, gg, stream, S0, BZ, BZ, WT(4), Z, Z, gproj_b, nullptr, nullptr, BZ, S1, N); // x_gat

  // gated fusion
  launch_gemm(2, gg, stream, S3, S2, S1, WT(5), WT(6), WT(7), gate_b1, nullptr, nullptr, BZ, S4, N); // t_gate
  combine_kernel<<<nb4, 256, 0, stream>>>(S4, gate_W2, gate_b2, S3, S2, S1, bn0_g, bn0_b, S0, N); // xx

  // GraphConv stack
  sum_agg_kernel<<<nb4, 256, 0, stream>>>(S0, rp, colA, S1, N);
  launch_gemm(3, gg, stream, S1, S0, BZ, WT(8), WT(11), Z, rel_b, bn_g, bn_b, S0, S2, N);          // reps0
  sum_agg_kernel<<<nb4, 256, 0, stream>>>(S2, rp, colA, S1, N);
  launch_gemm(3, gg, stream, S1, S2, BZ, WT(9), WT(12), Z, rel_b + 128, bn_g + 128, bn_b + 128, S2, S3, N); // reps1
  sum_agg_kernel<<<nb4, 256, 0, stream>>>(S3, rp, colA, S1, N);
  launch_gemm(3, gg, stream, S1, S3, BZ, WT(10), WT(13), Z, rel_b + 256, bn_g + 256, bn_b + 256, S3, S4, N); // reps2

  // JK cat + attention logits
  launch_gemm(1, gg, stream, S2, S3, S4, WT(14), WT(15), WT(16), jump_b, nullptr, nullptr, BZ, S0, N); // xx2
  launch_gemm(2, gg, stream, S0, BZ, BZ, WT(17), Z, Z, att_b1, nullptr, nullptr, BZ, S1, N);           // t_att
  alog_kernel<<<nb4, 256, 0, stream>>>(S1, att_W2, att_b2, alogv, N);

  // pooling + head
  att_stats_kernel<<<NG, 256, 0, stream>>>(alogv, gmv, gzv, npg);
  pool_partial_kernel<<<NG * nparts, 256, 0, stream>>>(S0, alogv, gmv, gzv, part, npg, nparts);
  pool_final_kernel<<<NG, 128, 0, stream>>>(part, hg, npg, nparts);
  head_kernel<<<NG, 128, 0, stream>>>(hg, comb_W, comb_b, cls_W1, cls_b1, cls_W2, cls_b2, out);
}

// Round 12
// 625.634 us; speedup vs baseline: 1.9242x; 1.0452x over previous
//
#include <hip/hip_runtime.h>

typedef float f32x4 __attribute__((ext_vector_type(4)));
typedef short s16x8 __attribute__((ext_vector_type(8)));

#define LDA 136   // padded LDS row length (bf16 elems)

static __device__ __forceinline__ unsigned short f2bf(float f){
  union { float f; unsigned int u; } v; v.f = f;
  unsigned int u = v.u;
  return (unsigned short)((u + 0x7fffu + ((u >> 16) & 1u)) >> 16);
}
static __device__ __forceinline__ float2 bfp2f(unsigned int p){   // packed 2xbf16 -> 2xf32
  union { unsigned int u; float f; } a, b;
  a.u = (p & 0xffffu) << 16; b.u = p & 0xffff0000u;
  return make_float2(a.f, b.f);
}
static __device__ __forceinline__ unsigned int f2bfp(float x, float y){
  return (unsigned int)f2bf(x) | ((unsigned int)f2bf(y) << 16);
}
static __device__ __forceinline__ float bf2f(unsigned short h){
  union { unsigned int u; float f; } v; v.u = (unsigned int)h << 16; return v.f;
}

static __device__ __forceinline__ float lrelu02(float x){ return x > 0.f ? x : 0.2f * x; }

// bijective XCD swizzle (m204)
static __device__ __forceinline__ int xcd_swz(int bid, int nwg){
  int q = nwg >> 3, r = nwg & 7, x = bid & 7, i = bid >> 3;
  return (x < r ? x * (q + 1) : r * (q + 1) + (x - r) * q) + i;
}

// ---------------- two-level CSR build (graph buckets -> per-graph CSR) ----------------

__global__ void zero_u32(unsigned int* p, int n){
  int i = blockIdx.x * 256 + threadIdx.x;
  if (i < n) p[i] = 0u;
}

__global__ void gcount_kernel(const int* __restrict__ dst, unsigned int* __restrict__ gcnt,
                              int E, int npg, int ng){
  __shared__ unsigned int h[64];
  int tid = threadIdx.x;
  if (tid < 64) h[tid] = 0u;
  __syncthreads();
  for (int i = blockIdx.x * 256 + tid; i < E; i += gridDim.x * 256)
    atomicAdd(&h[dst[i] / npg], 1u);
  __syncthreads();
  if (tid < ng) atomicAdd(&gcnt[tid], h[tid]);
}

__global__ void gscan_kernel(const unsigned int* __restrict__ gcnt, unsigned int* __restrict__ goff, int ng){
  if (threadIdx.x == 0){
    unsigned int run = 0;
    for (int i = 0; i < ng; ++i){ goff[i] = run; run += gcnt[i]; }
    goff[ng] = run;
  }
}

__global__ void gbucket_kernel(const int* __restrict__ src, const int* __restrict__ dst,
                               const unsigned int* __restrict__ goff, unsigned int* __restrict__ gfill,
                               int2* __restrict__ ebuf, int E, int npg, int ng){
  __shared__ unsigned int h[64];
  __shared__ unsigned int base[64];
  __shared__ unsigned int fl[64];
  int tid = threadIdx.x;
  if (tid < 64){ h[tid] = 0u; fl[tid] = 0u; }
  __syncthreads();
  int per = (E + gridDim.x - 1) / gridDim.x;
  int i0 = blockIdx.x * per, i1 = min(E, i0 + per);
  for (int i = i0 + tid; i < i1; i += 256)
    atomicAdd(&h[dst[i] / npg], 1u);
  __syncthreads();
  if (tid < ng) base[tid] = goff[tid] + atomicAdd(&gfill[tid], h[tid]);
  __syncthreads();
  for (int i = i0 + tid; i < i1; i += 256){
    int d = dst[i];
    int g = d / npg;
    unsigned int p = base[g] + atomicAdd(&fl[g], 1u);
    ebuf[p] = make_int2(src[i], d);
  }
}

__global__ void csr_graph_kernel(const int2* __restrict__ ebuf, const unsigned int* __restrict__ goff,
                                 unsigned int* __restrict__ rp, int* __restrict__ colA,
                                 int* __restrict__ dstA, float* __restrict__ dinv,
                                 int npg, int N, int Etot){
  __shared__ unsigned int hist[1024];
  __shared__ unsigned int fill[1024];
  int g = blockIdx.x, tid = threadIdx.x;
  unsigned int e0 = goff[g], e1 = goff[g + 1];
  int nbase = g * npg;
  hist[tid] = 0u; fill[tid] = 0u;
  __syncthreads();
  for (unsigned int e = e0 + tid; e < e1; e += 1024)
    atomicAdd(&hist[ebuf[e].y - nbase], 1u);
  __syncthreads();
  unsigned int cnt = hist[tid];
  for (int off = 1; off < 1024; off <<= 1){
    unsigned int t = (tid >= off) ? hist[tid - off] : 0u;
    __syncthreads();
    hist[tid] += t;
    __syncthreads();
  }
  unsigned int basev = e0 + hist[tid] - cnt;   // exclusive + graph offset
  __syncthreads();
  hist[tid] = basev;
  if (tid < npg){
    int node = nbase + tid;
    rp[node] = basev;
    dinv[node] = rsqrtf((float)cnt + 1.0f);
  }
  if (g == 0 && tid == 0) rp[N] = (unsigned int)Etot;
  __syncthreads();
  for (unsigned int e = e0 + tid; e < e1; e += 1024){
    int2 sd = ebuf[e];
    int ld = sd.y - nbase;
    unsigned int pos = hist[ld] + atomicAdd(&fill[ld], 1u);
    colA[pos] = sd.x;
    dstA[pos] = sd.y;
  }
}

__global__ void xcast_kernel(const float* __restrict__ x, unsigned short* __restrict__ xb, int n2){
  int i = blockIdx.x * 256 + threadIdx.x;
  if (i < n2){
    float2 v = ((const float2*)x)[i];
    ((unsigned int*)xb)[i] = f2bfp(v.x, v.y);
  }
}

__global__ void ew_kernel(const int* __restrict__ colA, const int* __restrict__ dstA,
                          const float* __restrict__ als, const float* __restrict__ ald,
                          unsigned int* __restrict__ wb, int E){
  int i = blockIdx.x * 256 + threadIdx.x;
  if (i >= E) return;
  int s = colA[i], d = dstA[i];
  float4 as = ((const float4*)als)[s];
  float4 ad = ((const float4*)ald)[d];
  float w0 = __expf(fminf(lrelu02(as.x + ad.x), 30.f));
  float w1 = __expf(fminf(lrelu02(as.y + ad.y), 30.f));
  float w2 = __expf(fminf(lrelu02(as.z + ad.z), 30.f));
  float w3 = __expf(fminf(lrelu02(as.w + ad.w), 30.f));
  wb[(size_t)i * 2 + 0] = f2bfp(w0, w1);
  wb[(size_t)i * 2 + 1] = f2bfp(w2, w3);
}

// ---------------- weight transpose (f32 [128,128] row-major -> bf16 [col][k]) ----------------

struct WSrc { const float* p[18]; };

__global__ void wtrans_kernel(WSrc s, unsigned short* __restrict__ dstAll){
  const float* src = s.p[blockIdx.x];
  unsigned short* dst = dstAll + (size_t)blockIdx.x * 16384;
  __shared__ float st[64][129];
  int tid = threadIdx.x;
  int kb = blockIdx.y * 64;
#pragma unroll
  for (int j = 0; j < 8; ++j){
    int e = tid + 256 * j;
    int r = e >> 5, c4 = (e & 31) * 4;
    float4 v = *(const float4*)(src + (size_t)(kb + r) * 128 + c4);
    st[r][c4] = v.x; st[r][c4+1] = v.y; st[r][c4+2] = v.z; st[r][c4+3] = v.w;
  }
  __syncthreads();
#pragma unroll
  for (int j = 0; j < 8; ++j){
    int e = tid + 256 * j;
    int c = e >> 4, k4 = (e & 15) * 4;
    ushort4 o;
    o.x = f2bf(st[k4+0][c]); o.y = f2bf(st[k4+1][c]);
    o.z = f2bf(st[k4+2][c]); o.w = f2bf(st[k4+3][c]);
    *(ushort4*)(dst + (size_t)c * 128 + kb + k4) = o;
  }
}

// ---------------- MFMA GEMM helpers ----------------
// Common staging macros (A bf16 row-major [nrows,128]; W pre-transposed bf16 [col][k])

#define STAGE_A(Ap)                                            \
  _Pragma("unroll")                                            \
  for (int j = 0; j < 4; ++j){                                 \
    int e = tid + 256 * j;                                     \
    int r = e >> 4, k8 = (e & 15) * 8;                         \
    int gr = row0 + r;                                         \
    s16x8 v = {0,0,0,0,0,0,0,0};                               \
    if (gr < nrows) v = *(const s16x8*)((Ap) + (size_t)gr * 128 + k8); \
    *(s16x8*)(As + r * LDA + k8) = v;                          \
  }

#define STAGE_W(Wp)                                            \
  _Pragma("unroll")                                            \
  for (int j = 0; j < 8; ++j){                                 \
    int e = tid + 256 * j;                                     \
    int colw = e >> 4, k8 = (e & 15) * 8;                      \
    *(s16x8*)(Wt + colw * LDA + k8) = *(const s16x8*)((Wp) + (size_t)colw * 128 + k8); \
  }

#define MFMA_LOOP(accv)                                        \
  _Pragma("unroll")                                            \
  for (int kc = 0; kc < 4; ++kc){                              \
    int ko = kc * 32 + (lane >> 4) * 8;                        \
    s16x8 av = *(const s16x8*)(As + (wave * 16 + (lane & 15)) * LDA + ko); \
    _Pragma("unroll")                                          \
    for (int ct = 0; ct < 8; ++ct){                            \
      s16x8 bv = *(const s16x8*)(Wt + (ct * 16 + (lane & 15)) * LDA + ko); \
      accv[ct] = __builtin_amdgcn_mfma_f32_16x16x32_bf16(av, bv, accv[ct], 0, 0, 0); \
    }                                                          \
  }

// EPI: 1 +bias, 3 conv: relu((acc+bias)*bn_g*RSQ + bn_b) + resid
template<int EPI>
__launch_bounds__(256, 2)
__global__ void gemm_kernel(const unsigned short* __restrict__ A0, const unsigned short* __restrict__ A1,
                            const unsigned short* __restrict__ A2,
                            const unsigned short* __restrict__ W0, const unsigned short* __restrict__ W1,
                            const unsigned short* __restrict__ W2,
                            const float* __restrict__ bias, const float* __restrict__ bng, const float* __restrict__ bnb,
                            const unsigned short* __restrict__ resid, unsigned short* __restrict__ C, int nrows)
{
  __shared__ unsigned short As[64 * LDA];
  __shared__ unsigned short Wt[128 * LDA];
  const int tid = threadIdx.x;
  const int wave = tid >> 6, lane = tid & 63;
  const int row0 = blockIdx.x * 64;
  const unsigned short* Aps[3] = {A0, A1, A2};
  const unsigned short* Wps[3] = {W0, W1, W2};
  f32x4 acc[8];
#pragma unroll
  for (int i = 0; i < 8; ++i) acc[i] = (f32x4){0.f, 0.f, 0.f, 0.f};

  for (int p = 0; p < 3; ++p){
    const unsigned short* Ap = Aps[p];
    if (Ap == nullptr) break;
    const unsigned short* Wp = Wps[p];
    if (p) __syncthreads();
    STAGE_A(Ap)
    STAGE_W(Wp)
    __syncthreads();
    MFMA_LOOP(acc)
  }
  const float RSQ = 0.99999500003749969f;
#pragma unroll
  for (int ct = 0; ct < 8; ++ct){
    int colg = ct * 16 + (lane & 15);
    float bv_ = bias[colg];
    float sg = (EPI == 3) ? bng[colg] * RSQ : 0.f;
    float sb = (EPI == 3) ? bnb[colg] : 0.f;
#pragma unroll
    for (int r = 0; r < 4; ++r){
      int rowg = row0 + wave * 16 + (lane >> 4) * 4 + r;
      if (rowg < nrows){
        float v = acc[ct][r];
        if (EPI == 1) v += bv_;
        else {
          v = (v + bv_) * sg + sb;
          v = fmaxf(v, 0.f) + bf2f(resid[(size_t)rowg * 128 + colg]);
        }
        C[(size_t)rowg * 128 + colg] = f2bf(v);
      }
    }
  }
}

// Dual-output GEMM sharing A(bf16): C0 = (A@W0)*dscale[row], C1 = A@W1 (both bf16 out).
__launch_bounds__(256, 2)
__global__ void gemm_dual_kernel(const unsigned short* __restrict__ A,
                                 const unsigned short* __restrict__ W0, const unsigned short* __restrict__ W1,
                                 const float* __restrict__ dscale,
                                 unsigned short* __restrict__ C0, unsigned short* __restrict__ C1, int nrows)
{
  __shared__ unsigned short As[64 * LDA];
  __shared__ unsigned short Wt[128 * LDA];
  const int tid = threadIdx.x;
  const int wave = tid >> 6, lane = tid & 63;
  const int row0 = blockIdx.x * 64;
  f32x4 acc0[8], acc1[8];
#pragma unroll
  for (int i = 0; i < 8; ++i){ acc0[i] = (f32x4){0.f,0.f,0.f,0.f}; acc1[i] = (f32x4){0.f,0.f,0.f,0.f}; }

  STAGE_A(A)
  STAGE_W(W0)
  __syncthreads();
  s16x8 av[4];
#pragma unroll
  for (int kc = 0; kc < 4; ++kc)
    av[kc] = *(const s16x8*)(As + (wave * 16 + (lane & 15)) * LDA + kc * 32 + (lane >> 4) * 8);
#pragma unroll
  for (int kc = 0; kc < 4; ++kc){
    int ko = kc * 32 + (lane >> 4) * 8;
#pragma unroll
    for (int ct = 0; ct < 8; ++ct){
      s16x8 bv = *(const s16x8*)(Wt + (ct * 16 + (lane & 15)) * LDA + ko);
      acc0[ct] = __builtin_amdgcn_mfma_f32_16x16x32_bf16(av[kc], bv, acc0[ct], 0, 0, 0);
    }
  }
  __syncthreads();
  STAGE_W(W1)
  __syncthreads();
#pragma unroll
  for (int kc = 0; kc < 4; ++kc){
    int ko = kc * 32 + (lane >> 4) * 8;
#pragma unroll
    for (int ct = 0; ct < 8; ++ct){
      s16x8 bv = *(const s16x8*)(Wt + (ct * 16 + (lane & 15)) * LDA + ko);
      acc1[ct] = __builtin_amdgcn_mfma_f32_16x16x32_bf16(av[kc], bv, acc1[ct], 0, 0, 0);
    }
  }
#pragma unroll
  for (int ct = 0; ct < 8; ++ct){
    int colg = ct * 16 + (lane & 15);
#pragma unroll
    for (int r = 0; r < 4; ++r){
      int rowg = row0 + wave * 16 + (lane >> 4) * 4 + r;
      if (rowg < nrows){
        C0[(size_t)rowg * 128 + colg] = f2bf(acc0[ct][r] * dscale[rowg]);
        C1[(size_t)rowg * 128 + colg] = f2bf(acc1[ct][r]);
      }
    }
  }
}

// GIN fused chain: C = relu(relu(A@W1+b1)@W2+b2)
__launch_bounds__(256, 2)
__global__ void gemm_gin_kernel(const unsigned short* __restrict__ A,
                                const unsigned short* __restrict__ W1, const unsigned short* __restrict__ W2,
                                const float* __restrict__ b1, const float* __restrict__ b2,
                                unsigned short* __restrict__ C, int nrows)
{
  __shared__ unsigned short As[64 * LDA];
  __shared__ unsigned short Wt[128 * LDA];
  const int tid = threadIdx.x;
  const int wave = tid >> 6, lane = tid & 63;
  const int row0 = blockIdx.x * 64;
  f32x4 acc[8];
#pragma unroll
  for (int i = 0; i < 8; ++i) acc[i] = (f32x4){0.f,0.f,0.f,0.f};
  STAGE_A(A)
  STAGE_W(W1)
  __syncthreads();
  MFMA_LOOP(acc)
  __syncthreads();                   // all waves done with As/Wt
  // h1 = relu(acc+b1) -> As (per-wave row stripe)
#pragma unroll
  for (int ct = 0; ct < 8; ++ct){
    int colg = ct * 16 + (lane & 15);
    float bb = b1[colg];
#pragma unroll
    for (int r = 0; r < 4; ++r){
      int rl = wave * 16 + (lane >> 4) * 4 + r;
      As[rl * LDA + colg] = f2bf(fmaxf(acc[ct][r] + bb, 0.f));
    }
  }
  STAGE_W(W2)
#pragma unroll
  for (int i = 0; i < 8; ++i) acc[i] = (f32x4){0.f,0.f,0.f,0.f};
  __syncthreads();
  MFMA_LOOP(acc)
#pragma unroll
  for (int ct = 0; ct < 8; ++ct){
    int colg = ct * 16 + (lane & 15);
    float bb = b2[colg];
#pragma unroll
    for (int r = 0; r < 4; ++r){
      int rowg = row0 + wave * 16 + (lane >> 4) * 4 + r;
      if (rowg < nrows)
        C[(size_t)rowg * 128 + colg] = f2bf(fmaxf(acc[ct][r] + bb, 0.f));
    }
  }
}

// Gate GEMM fused with gating+BN: t=relu(cat@W1+b1); g=softmax(t@W2+b2);
// xx = relu((g0*A0 + g1*A1 + g2*A2)*bn_g*RSQ + bn_b)
__launch_bounds__(256, 2)
__global__ void gemm_gate_kernel(const unsigned short* __restrict__ A0, const unsigned short* __restrict__ A1,
                                 const unsigned short* __restrict__ A2,
                                 const unsigned short* __restrict__ W0, const unsigned short* __restrict__ W1,
                                 const unsigned short* __restrict__ W2w,
                                 const float* __restrict__ b1, const float* __restrict__ gW2,
                                 const float* __restrict__ gb2,
                                 const float* __restrict__ bn0g, const float* __restrict__ bn0b,
                                 unsigned short* __restrict__ XX, int nrows)
{
  __shared__ unsigned short As[64 * LDA];
  __shared__ unsigned short Wt[128 * LDA];
  const int tid = threadIdx.x;
  const int wave = tid >> 6, lane = tid & 63;
  const int row0 = blockIdx.x * 64;
  const unsigned short* Aps[3] = {A0, A1, A2};
  const unsigned short* Wps[3] = {W0, W1, W2w};
  f32x4 acc[8];
#pragma unroll
  for (int i = 0; i < 8; ++i) acc[i] = (f32x4){0.f,0.f,0.f,0.f};
  for (int p = 0; p < 3; ++p){
    if (p) __syncthreads();
    STAGE_A(Aps[p])
    STAGE_W(Wps[p])
    __syncthreads();
    MFMA_LOOP(acc)
  }
  // per-row 3-gate projection
  float p0[4] = {0,0,0,0}, p1[4] = {0,0,0,0}, p2[4] = {0,0,0,0};
#pragma unroll
  for (int ct = 0; ct < 8; ++ct){
    int colg = ct * 16 + (lane & 15);
    float bb = b1[colg];
    float w0 = gW2[colg * 3 + 0], w1 = gW2[colg * 3 + 1], w2 = gW2[colg * 3 + 2];
#pragma unroll
    for (int r = 0; r < 4; ++r){
      float t = fmaxf(acc[ct][r] + bb, 0.f);
      p0[r] += t * w0; p1[r] += t * w1; p2[r] += t * w2;
    }
  }
#pragma unroll
  for (int off = 1; off < 16; off <<= 1){
#pragma unroll
    for (int r = 0; r < 4; ++r){
      p0[r] += __shfl_xor(p0[r], off, 64);
      p1[r] += __shfl_xor(p1[r], off, 64);
      p2[r] += __shfl_xor(p2[r], off, 64);
    }
  }
  float e0[4], e1[4], e2[4];
#pragma unroll
  for (int r = 0; r < 4; ++r){
    float q0 = p0[r] + gb2[0], q1 = p1[r] + gb2[1], q2 = p2[r] + gb2[2];
    float mm = fmaxf(q0, fmaxf(q1, q2));
    float x0 = __expf(q0 - mm), x1 = __expf(q1 - mm), x2 = __expf(q2 - mm);
    float inv = 1.0f / (x0 + x1 + x2);
    e0[r] = x0 * inv; e1[r] = x1 * inv; e2[r] = x2 * inv;
  }
  const float RSQ = 0.99999500003749969f;
#pragma unroll
  for (int ct = 0; ct < 8; ++ct){
    int colg = ct * 16 + (lane & 15);
    float sg = bn0g[colg] * RSQ, sb = bn0b[colg];
#pragma unroll
    for (int r = 0; r < 4; ++r){
      int rowg = row0 + wave * 16 + (lane >> 4) * 4 + r;
      if (rowg < nrows){
        float a = bf2f(A0[(size_t)rowg * 128 + colg]);
        float b = bf2f(A1[(size_t)rowg * 128 + colg]);
        float c = bf2f(A2[(size_t)rowg * 128 + colg]);
        float o = fmaxf((e0[r] * a + e1[r] * b + e2[r] * c) * sg + sb, 0.f);
        XX[(size_t)rowg * 128 + colg] = f2bf(o);
      }
    }
  }
}

// Jump(3-part)+bias -> XX2 (global + LDS) ; t=relu(XX2@Wa+ab1) ; alog=t@aw2+ab2
__launch_bounds__(256, 2)
__global__ void gemm_jump_att_kernel(const unsigned short* __restrict__ A0, const unsigned short* __restrict__ A1,
                                     const unsigned short* __restrict__ A2,
                                     const unsigned short* __restrict__ W0, const unsigned short* __restrict__ W1,
                                     const unsigned short* __restrict__ W2w,
                                     const float* __restrict__ jb,
                                     const unsigned short* __restrict__ Wa, const float* __restrict__ ab1,
                                     const float* __restrict__ aw2, const float* __restrict__ ab2,
                                     unsigned short* __restrict__ XX2, float* __restrict__ alog, int nrows)
{
  __shared__ unsigned short As[64 * LDA];
  __shared__ unsigned short Wt[128 * LDA];
  const int tid = threadIdx.x;
  const int wave = tid >> 6, lane = tid & 63;
  const int row0 = blockIdx.x * 64;
  const unsigned short* Aps[3] = {A0, A1, A2};
  const unsigned short* Wps[3] = {W0, W1, W2w};
  f32x4 acc[8];
#pragma unroll
  for (int i = 0; i < 8; ++i) acc[i] = (f32x4){0.f,0.f,0.f,0.f};
  for (int p = 0; p < 3; ++p){
    if (p) __syncthreads();
    STAGE_A(Aps[p])
    STAGE_W(Wps[p])
    __syncthreads();
    MFMA_LOOP(acc)
  }
  __syncthreads();                   // all waves done reading As/Wt
  // xx2 = acc + jb -> global + LDS
#pragma unroll
  for (int ct = 0; ct < 8; ++ct){
    int colg = ct * 16 + (lane & 15);
    float bb = jb[colg];
#pragma unroll
    for (int r = 0; r < 4; ++r){
      int rl = wave * 16 + (lane >> 4) * 4 + r;
      unsigned short h = f2bf(acc[ct][r] + bb);
      As[rl * LDA + colg] = h;
      int rowg = row0 + rl;
      if (rowg < nrows) XX2[(size_t)rowg * 128 + colg] = h;
    }
  }
  STAGE_W(Wa)
#pragma unroll
  for (int i = 0; i < 8; ++i) acc[i] = (f32x4){0.f,0.f,0.f,0.f};
  __syncthreads();
  MFMA_LOOP(acc)
  float pl[4] = {0,0,0,0};
#pragma unroll
  for (int ct = 0; ct < 8; ++ct){
    int colg = ct * 16 + (lane & 15);
    float bb = ab1[colg];
    float w = aw2[colg];
#pragma unroll
    for (int r = 0; r < 4; ++r)
      pl[r] += fmaxf(acc[ct][r] + bb, 0.f) * w;
  }
#pragma unroll
  for (int off = 1; off < 16; off <<= 1){
#pragma unroll
    for (int r = 0; r < 4; ++r) pl[r] += __shfl_xor(pl[r], off, 64);
  }
  if ((lane & 15) == 0){
#pragma unroll
    for (int r = 0; r < 4; ++r){
      int rowg = row0 + wave * 16 + (lane >> 4) * 4 + r;
      if (rowg < nrows) alog[rowg] = pl[r] + ab2[0];
    }
  }
}

// ---------------- aggregation kernels (wave per node, bf16x2 per lane, 4x unrolled) ----------------

__global__ void gin_agg_kernel(const unsigned short* __restrict__ x, const unsigned int* __restrict__ rp,
                               const int* __restrict__ col, unsigned short* __restrict__ xs, int n){
  int bid = xcd_swz(blockIdx.x, gridDim.x);
  int node = bid * 4 + (int)(threadIdx.x >> 6);
  if (node >= n) return;
  int lane = threadIdx.x & 63;
  const unsigned int* xin = (const unsigned int*)x;
  float2 acc = bfp2f(xin[(size_t)node * 64 + lane]);
  unsigned int rs = rp[node], re = rp[node + 1], e = rs;
  for (; e + 4 <= re; e += 4){
    int s0 = col[e], s1 = col[e+1], s2 = col[e+2], s3 = col[e+3];
    float2 v0 = bfp2f(xin[(size_t)s0 * 64 + lane]);
    float2 v1 = bfp2f(xin[(size_t)s1 * 64 + lane]);
    float2 v2 = bfp2f(xin[(size_t)s2 * 64 + lane]);
    float2 v3 = bfp2f(xin[(size_t)s3 * 64 + lane]);
    acc.x += v0.x + v1.x + v2.x + v3.x;
    acc.y += v0.y + v1.y + v2.y + v3.y;
  }
  for (; e < re; ++e){
    float2 v = bfp2f(xin[(size_t)col[e] * 64 + lane]);
    acc.x += v.x; acc.y += v.y;
  }
  ((unsigned int*)xs)[(size_t)node * 64 + lane] = f2bfp(acc.x, acc.y);
}

__global__ void gcn_agg_kernel(const unsigned short* __restrict__ hd, const float* __restrict__ dinv,
                               const unsigned int* __restrict__ rp, const int* __restrict__ col,
                               const float* __restrict__ b, unsigned short* __restrict__ out, int n){
  int bid = xcd_swz(blockIdx.x, gridDim.x);
  int node = bid * 4 + (int)(threadIdx.x >> 6);
  if (node >= n) return;
  int lane = threadIdx.x & 63;
  const unsigned int* hv = (const unsigned int*)hd;
  float di = dinv[node];
  float2 acc = bfp2f(hv[(size_t)node * 64 + lane]);
  unsigned int rs = rp[node], re = rp[node + 1], e = rs;
  for (; e + 4 <= re; e += 4){
    int s0 = col[e], s1 = col[e+1], s2 = col[e+2], s3 = col[e+3];
    float2 v0 = bfp2f(hv[(size_t)s0 * 64 + lane]);
    float2 v1 = bfp2f(hv[(size_t)s1 * 64 + lane]);
    float2 v2 = bfp2f(hv[(size_t)s2 * 64 + lane]);
    float2 v3 = bfp2f(hv[(size_t)s3 * 64 + lane]);
    acc.x += v0.x + v1.x + v2.x + v3.x;
    acc.y += v0.y + v1.y + v2.y + v3.y;
  }
  for (; e < re; ++e){
    float2 v = bfp2f(hv[(size_t)col[e] * 64 + lane]);
    acc.x += v.x; acc.y += v.y;
  }
  int f = lane * 2;
  float o0 = fmaxf(acc.x * di + b[f], 0.f);
  float o1 = fmaxf(acc.y * di + b[f + 1], 0.f);
  ((unsigned int*)out)[(size_t)node * 64 + lane] = f2bfp(o0, o1);
}

__global__ void sum_agg_kernel(const unsigned short* __restrict__ x, const unsigned int* __restrict__ rp,
                               const int* __restrict__ col, unsigned short* __restrict__ out, int n){
  int bid = xcd_swz(blockIdx.x, gridDim.x);
  int node = bid * 4 + (int)(threadIdx.x >> 6);
  if (node >= n) return;
  int lane = threadIdx.x & 63;
  const unsigned int* xin = (const unsigned int*)x;
  float2 acc = make_float2(0.f, 0.f);
  unsigned int rs = rp[node], re = rp[node + 1], e = rs;
  for (; e + 4 <= re; e += 4){
    int s0 = col[e], s1 = col[e+1], s2 = col[e+2], s3 = col[e+3];
    float2 v0 = bfp2f(xin[(size_t)s0 * 64 + lane]);
    float2 v1 = bfp2f(xin[(size_t)s1 * 64 + lane]);
    float2 v2 = bfp2f(xin[(size_t)s2 * 64 + lane]);
    float2 v3 = bfp2f(xin[(size_t)s3 * 64 + lane]);
    acc.x += v0.x + v1.x + v2.x + v3.x;
    acc.y += v0.y + v1.y + v2.y + v3.y;
  }
  for (; e < re; ++e){
    float2 v = bfp2f(xin[(size_t)col[e] * 64 + lane]);
    acc.x += v.x; acc.y += v.y;
  }
  ((unsigned int*)out)[(size_t)node * 64 + lane] = f2bfp(acc.x, acc.y);
}

__global__ void gat_agg_kernel(const unsigned short* __restrict__ xp, const float* __restrict__ als,
                               const float* __restrict__ ald, const unsigned int* __restrict__ wb,
                               const unsigned int* __restrict__ rp, const int* __restrict__ col,
                               const float* __restrict__ bgat, unsigned short* __restrict__ out, int n){
  int bid = xcd_swz(blockIdx.x, gridDim.x);
  int node = bid * 4 + (int)(threadIdx.x >> 6);
  if (node >= n) return;
  int lane = threadIdx.x & 63;
  int h = lane >> 4;
  int wword = h >> 1, wsh = (h & 1) * 16;
  const unsigned int* xv = (const unsigned int*)xp;
  float w = __expf(fminf(lrelu02(als[(size_t)node * 4 + h] + ald[(size_t)node * 4 + h]), 30.f));
  float2 sv = bfp2f(xv[(size_t)node * 64 + lane]);
  float2 acc = make_float2(sv.x * w, sv.y * w);
  float denom = w;
  unsigned int rs = rp[node], re = rp[node + 1], e = rs;
  for (; e + 4 <= re; e += 4){
    int s0 = col[e], s1 = col[e+1], s2 = col[e+2], s3 = col[e+3];
    float w0 = bf2f((unsigned short)(wb[(size_t)(e+0) * 2 + wword] >> wsh));
    float w1 = bf2f((unsigned short)(wb[(size_t)(e+1) * 2 + wword] >> wsh));
    float w2 = bf2f((unsigned short)(wb[(size_t)(e+2) * 2 + wword] >> wsh));
    float w3 = bf2f((unsigned short)(wb[(size_t)(e+3) * 2 + wword] >> wsh));
    float2 v0 = bfp2f(xv[(size_t)s0 * 64 + lane]);
    float2 v1 = bfp2f(xv[(size_t)s1 * 64 + lane]);
    float2 v2 = bfp2f(xv[(size_t)s2 * 64 + lane]);
    float2 v3 = bfp2f(xv[(size_t)s3 * 64 + lane]);
    acc.x += v0.x * w0 + v1.x * w1 + v2.x * w2 + v3.x * w3;
    acc.y += v0.y * w0 + v1.y * w1 + v2.y * w2 + v3.y * w3;
    denom += w0 + w1 + w2 + w3;
  }
  for (; e < re; ++e){
    float we = bf2f((unsigned short)(wb[(size_t)e * 2 + wword] >> wsh));
    float2 v = bfp2f(xv[(size_t)col[e] * 64 + lane]);
    acc.x += v.x * we; acc.y += v.y * we;
    denom += we;
  }
  float inv = 1.0f / denom;
  int f = lane * 2;
  float o0 = fmaxf(acc.x * inv + bgat[f], 0.f);
  float o1 = fmaxf(acc.y * inv + bgat[f + 1], 0.f);
  ((unsigned int*)out)[(size_t)node * 64 + lane] = f2bfp(o0, o1);
}

// ---------------- small per-node kernels ----------------

__global__ void alpair_kernel(const unsigned short* __restrict__ xp, const float* __restrict__ a_src,
                              const float* __restrict__ a_dst, float* __restrict__ als,
                              float* __restrict__ ald, int n){
  int node = blockIdx.x * 4 + (int)(threadIdx.x >> 6);
  if (node >= n) return;
  int lane = threadIdx.x & 63;
  int f = lane * 2;
  float2 v = bfp2f(((const unsigned int*)xp)[(size_t)node * 64 + lane]);
  float ps = v.x * a_src[f] + v.y * a_src[f + 1];
  float pd = v.x * a_dst[f] + v.y * a_dst[f + 1];
#pragma unroll
  for (int off = 1; off < 16; off <<= 1){
    ps += __shfl_xor(ps, off, 64);
    pd += __shfl_xor(pd, off, 64);
  }
  if ((lane & 15) == 0){
    int hh = lane >> 4;
    als[(size_t)node * 4 + hh] = ps;
    ald[(size_t)node * 4 + hh] = pd;
  }
}

// ---------------- pooling + head ----------------

__global__ void att_stats_kernel(const float* __restrict__ alog, float* __restrict__ gm,
                                 float* __restrict__ gz, int npg){
  __shared__ float red[256];
  int g = blockIdx.x, tid = threadIdx.x;
  size_t base = (size_t)g * npg;
  float m = -1e30f;
  for (int i = tid; i < npg; i += 256) m = fmaxf(m, alog[base + i]);
  red[tid] = m; __syncthreads();
  for (int off = 128; off > 0; off >>= 1){ if (tid < off) red[tid] = fmaxf(red[tid], red[tid + off]); __syncthreads(); }
  float gmax = red[0]; __syncthreads();
  float z = 0.f;
  for (int i = tid; i < npg; i += 256) z += __expf(alog[base + i] - gmax);
  red[tid] = z; __syncthreads();
  for (int off = 128; off > 0; off >>= 1){ if (tid < off) red[tid] += red[tid + off]; __syncthreads(); }
  if (tid == 0){ gm[g] = gmax; gz[g] = red[0]; }
}

__global__ void pool_partial_kernel(const unsigned short* __restrict__ xx, const float* __restrict__ alog,
                                    const float* __restrict__ gm, const float* __restrict__ gz,
                                    float* __restrict__ part, int npg, int nparts){
  __shared__ float wts[128];
  __shared__ float red[256];
  int g = blockIdx.x / nparts, p = blockIdx.x % nparts;
  int chunk = (npg + nparts - 1) / nparts;
  int n0 = p * chunk, n1 = min(npg, n0 + chunk);
  int tid = threadIdx.x;
  float gmax = gm[g], ginv = 1.0f / gz[g];
  size_t base = (size_t)g * npg;
  for (int i = n0 + tid; i < n1; i += 256) wts[i - n0] = __expf(alog[base + i] - gmax) * ginv;
  __syncthreads();
  int f = tid & 127, half = tid >> 7;
  float add = 0.f, mx = -1e30f, att = 0.f;
  for (int n2 = n0 + half; n2 < n1; n2 += 2){
    float v = bf2f(xx[(base + n2) * 128 + f]);
    add += v; mx = fmaxf(mx, v); att += v * wts[n2 - n0];
  }
  red[tid] = add; __syncthreads();
  float addf = add + ((half == 0) ? red[tid + 128] : 0.f);
  __syncthreads(); red[tid] = mx; __syncthreads();
  float mxf = (half == 0) ? fmaxf(mx, red[tid + 128]) : 0.f;
  __syncthreads(); red[tid] = att; __syncthreads();
  float attf = att + ((half == 0) ? red[tid + 128] : 0.f);
  if (half == 0){
    float* o = part + (size_t)(g * nparts + p) * 384;
    o[f] = addf; o[128 + f] = mxf; o[256 + f] = attf;
  }
}

__global__ void pool_final_kernel(const float* __restrict__ part, float* __restrict__ hg,
                                  int npg, int nparts){
  int g = blockIdx.x, f = threadIdx.x;
  float add = 0.f, mx = -1e30f, att = 0.f;
  for (int p = 0; p < nparts; ++p){
    const float* o = part + (size_t)(g * nparts + p) * 384;
    add += o[f]; mx = fmaxf(mx, o[128 + f]); att += o[256 + f];
  }
  float* o = hg + (size_t)g * 512;
  o[f] = add / (float)npg;
  o[128 + f] = mx;
  o[256 + f] = add;
  o[384 + f] = att;
}

__global__ void head_kernel(const float* __restrict__ hg, const float* __restrict__ combW,
                            const float* __restrict__ combB, const float* __restrict__ c1W,
                            const float* __restrict__ c1B, const float* __restrict__ c2W,
                            const float* __restrict__ c2B, float* __restrict__ out){
  __shared__ float cat[512];
  __shared__ float h1[128];
  __shared__ float h2[64];
  int g = blockIdx.x, tid = threadIdx.x;
#pragma unroll
  for (int j = 0; j < 4; ++j) cat[tid + 128 * j] = hg[(size_t)g * 512 + tid + 128 * j];
  __syncthreads();
  float a = combB[tid];
  for (int k = 0; k < 512; ++k) a += cat[k] * combW[(size_t)k * 128 + tid];
  h1[tid] = a; __syncthreads();
  if (tid < 64){
    float b = c1B[tid];
    for (int k = 0; k < 128; ++k) b += h1[k] * c1W[(size_t)k * 64 + tid];
    h2[tid] = fmaxf(b, 0.f);
  }
  __syncthreads();
  if (tid < 2){
    float o = c2B[tid];
    for (int k = 0; k < 64; ++k) o += h2[k] * c2W[(size_t)k * 2 + tid];
    out[(size_t)g * 2 + tid] = o;
  }
}

// ---------------- host ----------------

extern "C" void kernel_launch(void* const* d_in, const int* in_sizes, int n_in,
                              void* d_out, int out_size, void* d_ws, size_t ws_size,
                              hipStream_t stream){
  (void)n_in; (void)out_size; (void)ws_size;
  const int N = in_sizes[0] / 128;
  const int E = in_sizes[1] / 2;
  const int NG = 50;
  const int npg = N / NG;

  const float* x       = (const float*)d_in[0];
  const int*   ei      = (const int*)d_in[1];
  const int*   srcI    = ei;
  const int*   dstI    = ei + E;
  const float* W_gcn   = (const float*)d_in[3];
  const float* b_gcn   = (const float*)d_in[4];
  const float* gin_W1  = (const float*)d_in[5];
  const float* gin_b1  = (const float*)d_in[6];
  const float* gin_W2  = (const float*)d_in[7];
  const float* gin_b2  = (const float*)d_in[8];
  const float* W_gat   = (const float*)d_in[9];
  const float* b_gat   = (const float*)d_in[10];
  const float* a_src   = (const float*)d_in[11];
  const float* a_dst   = (const float*)d_in[12];
  const float* gproj_W = (const float*)d_in[13];
  const float* gproj_b = (const float*)d_in[14];
  const float* gate_W1 = (const float*)d_in[15];
  const float* gate_b1 = (const float*)d_in[16];
  const float* gate_W2 = (const float*)d_in[17];
  const float* gate_b2 = (const float*)d_in[18];
  const float* bn0_g   = (const float*)d_in[19];
  const float* bn0_b   = (const float*)d_in[20];
  const float* rel_W   = (const float*)d_in[21];
  const float* rel_b   = (const float*)d_in[22];
  const float* root_W  = (const float*)d_in[23];
  const float* bn_g    = (const float*)d_in[24];
  const float* bn_b    = (const float*)d_in[25];
  const float* jump_W  = (const float*)d_in[26];
  const float* jump_b  = (const float*)d_in[27];
  const float* att_W1  = (const float*)d_in[28];
  const float* att_b1  = (const float*)d_in[29];
  const float* att_W2  = (const float*)d_in[30];
  const float* att_b2  = (const float*)d_in[31];
  const float* comb_W  = (const float*)d_in[32];
  const float* comb_b  = (const float*)d_in[33];
  const float* cls_W1  = (const float*)d_in[34];
  const float* cls_b1  = (const float*)d_in[35];
  const float* cls_W2  = (const float*)d_in[36];
  const float* cls_b2  = (const float*)d_in[37];
  float* out = (float*)d_out;

  char* wp = (char*)d_ws;
  auto alloc = [&](size_t b) -> char* {
    char* p = wp; wp += (b + 511) & ~(size_t)511; return p;
  };
  unsigned int* rp   = (unsigned int*)alloc(((size_t)N + 1) * 4);
  int* colA          = (int*)alloc((size_t)E * 4);
  int* dstA          = (int*)alloc((size_t)E * 4);
  int2* ebuf         = (int2*)alloc((size_t)E * 8);
  unsigned int* wb   = (unsigned int*)alloc((size_t)E * 8);
  unsigned int* gcnt = (unsigned int*)alloc(192 * 4);   // gcnt[64] | gfill[64] | goff[64]
  unsigned int* gfill= gcnt + 64;
  unsigned int* goff = gcnt + 128;
  float* dinv        = (float*)alloc((size_t)N * 4);
  float* als         = (float*)alloc((size_t)N * 16);
  float* ald         = (float*)alloc((size_t)N * 16);
  float* alogv       = (float*)alloc((size_t)N * 4);
  unsigned short* WtAll = (unsigned short*)alloc((size_t)18 * 16384 * 2);
  float* hg          = (float*)alloc((size_t)NG * 512 * 4);
  float* gmv         = (float*)alloc((size_t)NG * 4);
  float* gzv         = (float*)alloc((size_t)NG * 4);
  int nparts = (npg + 99) / 100;
  float* part        = (float*)alloc((size_t)NG * nparts * 384 * 4);
  unsigned short* xbf = (unsigned short*)alloc((size_t)N * 128 * 2);
  unsigned short* S0 = (unsigned short*)alloc((size_t)N * 128 * 2);
  unsigned short* S1 = (unsigned short*)alloc((size_t)N * 128 * 2);
  unsigned short* S2 = (unsigned short*)alloc((size_t)N * 128 * 2);
  unsigned short* S3 = (unsigned short*)alloc((size_t)N * 128 * 2);
  unsigned short* S4 = (unsigned short*)alloc((size_t)N * 128 * 2);

  // --- two-level CSR build ---
  zero_u32<<<1, 256, 0, stream>>>(gcnt, 128);
  gcount_kernel<<<256, 256, 0, stream>>>(dstI, gcnt, E, npg, NG);
  gscan_kernel<<<1, 64, 0, stream>>>(gcnt, goff, NG);
  gbucket_kernel<<<256, 256, 0, stream>>>(srcI, dstI, goff, gfill, ebuf, E, npg, NG);
  csr_graph_kernel<<<NG, 1024, 0, stream>>>(ebuf, goff, rp, colA, dstA, dinv, npg, N, E);

  // --- weight transpose/cast + x cast ---
  WSrc wsrc;
  wsrc.p[0] = W_gcn;  wsrc.p[1] = W_gat;  wsrc.p[2] = gin_W1; wsrc.p[3] = gin_W2;
  wsrc.p[4] = gproj_W;
  wsrc.p[5] = gate_W1;      wsrc.p[6] = gate_W1 + 16384; wsrc.p[7] = gate_W1 + 32768;
  wsrc.p[8] = rel_W;        wsrc.p[9] = rel_W + 16384;   wsrc.p[10] = rel_W + 32768;
  wsrc.p[11] = root_W;      wsrc.p[12] = root_W + 16384; wsrc.p[13] = root_W + 32768;
  wsrc.p[14] = jump_W;      wsrc.p[15] = jump_W + 16384; wsrc.p[16] = jump_W + 32768;
  wsrc.p[17] = att_W1;
  wtrans_kernel<<<dim3(18, 2), 256, 0, stream>>>(wsrc, WtAll);
  xcast_kernel<<<(N * 64 + 255) / 256, 256, 0, stream>>>(x, xbf, N * 64);

  dim3 gg((N + 63) / 64);
  int nb4 = (N + 3) / 4;
  #define WT(i) (WtAll + (size_t)(i) * 16384)
  const unsigned short* Z = nullptr;
  const unsigned short* BZ = nullptr;

  // stems: S0 = hd = (x@W_gcn)*dinv, S1 = xp = x@W_gat
  gemm_dual_kernel<<<gg, 256, 0, stream>>>(xbf, WT(0), WT(1), dinv, S0, S1, N);
  alpair_kernel<<<nb4, 256, 0, stream>>>(S1, a_src, a_dst, als, ald, N);
  ew_kernel<<<(E + 255) / 256, 256, 0, stream>>>(colA, dstA, als, ald, wb, E);
  gin_agg_kernel<<<nb4, 256, 0, stream>>>(xbf, rp, colA, S2, N);                    // S2 = xs
  gemm_gin_kernel<<<gg, 256, 0, stream>>>(S2, WT(2), WT(3), gin_b1, gin_b2, S3, N); // S3 = x_gin
  gcn_agg_kernel<<<nb4, 256, 0, stream>>>(S0, dinv, rp, colA, b_gcn, S4, N);        // S4 = x_gcn
  gat_agg_kernel<<<nb4, 256, 0, stream>>>(S1, als, ald, wb, rp, colA, b_gat, S0, N); // S0 = gat_pre
  gemm_kernel<1><<<gg, 256, 0, stream>>>(S0, BZ, BZ, WT(4), Z, Z, gproj_b, nullptr, nullptr, BZ, S1, N); // S1 = x_gat

  // gated fusion (fused): S2 = xx
  gemm_gate_kernel<<<gg, 256, 0, stream>>>(S4, S3, S1, WT(5), WT(6), WT(7),
                                           gate_b1, gate_W2, gate_b2, bn0_g, bn0_b, S2, N);

  // GraphConv stack
  sum_agg_kernel<<<nb4, 256, 0, stream>>>(S2, rp, colA, S0, N);
  gemm_kernel<3><<<gg, 256, 0, stream>>>(S0, S2, BZ, WT(8), WT(11), Z, rel_b, bn_g, bn_b, S2, S1, N);          // S1 = x1
  sum_agg_kernel<<<nb4, 256, 0, stream>>>(S1, rp, colA, S0, N);
  gemm_kernel<3><<<gg, 256, 0, stream>>>(S0, S1, BZ, WT(9), WT(12), Z, rel_b + 128, bn_g + 128, bn_b + 128, S1, S4, N); // S4 = x2
  sum_agg_kernel<<<nb4, 256, 0, stream>>>(S4, rp, colA, S0, N);
  gemm_kernel<3><<<gg, 256, 0, stream>>>(S0, S4, BZ, WT(10), WT(13), Z, rel_b + 256, bn_g + 256, bn_b + 256, S4, S2, N); // S2 = x3

  // JK cat + attention logits (fused): S0 = xx2, alogv
  gemm_jump_att_kernel<<<gg, 256, 0, stream>>>(S1, S4, S2, WT(14), WT(15), WT(16), jump_b,
                                               WT(17), att_b1, att_W2, att_b2, S0, alogv, N);

  // pooling + head
  att_stats_kernel<<<NG, 256, 0, stream>>>(alogv, gmv, gzv, npg);
  pool_partial_kernel<<<NG * nparts, 256, 0, stream>>>(S0, alogv, gmv, gzv, part, npg, nparts);
  pool_final_kernel<<<NG, 128, 0, stream>>>(part, hg, npg, nparts);
  head_kernel<<<NG, 128, 0, stream>>>(hg, comb_W, comb_b, cls_W1, cls_b1, cls_W2, cls_b2, out);
}